// Round 4
// baseline (872.273 us; speedup 1.0000x reference)
//
#include <hip/hip_runtime.h>
#include <cstdint>
#include <cstddef>

#define BATCH 256
#define DIM   512
#define HIDN  2048
#define SLOTS 32768
#define NCHUNK 4
#define CHSZ  (SLOTS/NCHUNK)    // 8192

typedef __attribute__((ext_vector_type(8))) _Float16 half8;
typedef __attribute__((ext_vector_type(4))) float f32x4;

__device__ __forceinline__ unsigned int pack2(unsigned short a, unsigned short b) {
  return (unsigned int)a | ((unsigned int)b << 16);
}

// ---------------------------------------------------------------------------
// fp16 split helpers (RNE) — 11+11 significand bits, fp32-class when paired
// ---------------------------------------------------------------------------
__device__ __forceinline__ unsigned short h_rne(float x) {
  _Float16 h = (_Float16)x;
  union { _Float16 f; unsigned short u; } cv; cv.f = h;
  return cv.u;
}
__device__ __forceinline__ unsigned short h_split(float x, float& rem) {
  _Float16 h = (_Float16)x;
  rem = x - (float)h;
  union { _Float16 f; unsigned short u; } cv; cv.f = h;
  return cv.u;
}

// ---------------------------------------------------------------------------
// Generic MFMA BT-GEMM with on-the-fly fp16 hi/lo compensation:
// C[M,N] = act(A @ B^T + bias), fp32 in/out, ~22-bit effective significand.
// Tile 128x128, 256 threads, K-step 32. Replaces ALL fp32 VALU GEMMs and the
// bf16 score GEMM (fp16-hilo proven at K=32768 in seq_plus_gemm; here K<=2048
// for MLP and K=512 for scores — strictly tighter than the old bf16 path).
// M, N must be multiples of 128; K of 32 (all call sites satisfy this).
// ---------------------------------------------------------------------------
#define LSTR 40
__global__ __launch_bounds__(256) void hgemm_bt(
    const float* __restrict__ A, const float* __restrict__ B,
    const float* __restrict__ bias, float* __restrict__ C,
    int M, int N, int K, int relu)
{
  __shared__ __align__(16) unsigned short sAhi[128*LSTR];
  __shared__ __align__(16) unsigned short sAlo[128*LSTR];
  __shared__ __align__(16) unsigned short sBhi[128*LSTR];
  __shared__ __align__(16) unsigned short sBlo[128*LSTR];
  const int m0 = blockIdx.x * 128, n0 = blockIdx.y * 128;
  const int t = threadIdx.x;
  const int wave = t >> 6, lane = t & 63;
  const int wr = (wave >> 1) * 64, wc = (wave & 1) * 64;
  const int lrow = lane & 15, quad = lane >> 4;
  const int sr = t >> 1;           // staging row (0..127), 2 threads/row
  const int sc = (t & 1) * 16;     // staging k-offset

  f32x4 acc[4][4];
  #pragma unroll
  for (int a = 0; a < 4; ++a)
    #pragma unroll
    for (int b = 0; b < 4; ++b)
      acc[a][b] = (f32x4){0.f, 0.f, 0.f, 0.f};

  for (int k0 = 0; k0 < K; k0 += 32) {
    const float* ap = A + (size_t)(m0 + sr) * K + k0 + sc;
    float4 a0 = *(const float4*)(ap);
    float4 a1 = *(const float4*)(ap + 4);
    float4 a2 = *(const float4*)(ap + 8);
    float4 a3 = *(const float4*)(ap + 12);
    const float* bp = B + (size_t)(n0 + sr) * K + k0 + sc;
    float4 b0 = *(const float4*)(bp);
    float4 b1 = *(const float4*)(bp + 4);
    float4 b2 = *(const float4*)(bp + 8);
    float4 b3 = *(const float4*)(bp + 12);

    float ax[16] = {a0.x,a0.y,a0.z,a0.w, a1.x,a1.y,a1.z,a1.w,
                    a2.x,a2.y,a2.z,a2.w, a3.x,a3.y,a3.z,a3.w};
    float bx[16] = {b0.x,b0.y,b0.z,b0.w, b1.x,b1.y,b1.z,b1.w,
                    b2.x,b2.y,b2.z,b2.w, b3.x,b3.y,b3.z,b3.w};
    unsigned short ah[16], al[16], bh[16], bl[16];
    #pragma unroll
    for (int e = 0; e < 16; ++e) {
      float rm;
      ah[e] = h_split(ax[e], rm); al[e] = h_rne(rm);
      bh[e] = h_split(bx[e], rm); bl[e] = h_rne(rm);
    }

    __syncthreads();
    *(uint4*)&sAhi[sr*LSTR + sc] =
        make_uint4(pack2(ah[0],ah[1]), pack2(ah[2],ah[3]),
                   pack2(ah[4],ah[5]), pack2(ah[6],ah[7]));
    *(uint4*)&sAhi[sr*LSTR + sc + 8] =
        make_uint4(pack2(ah[8],ah[9]), pack2(ah[10],ah[11]),
                   pack2(ah[12],ah[13]), pack2(ah[14],ah[15]));
    *(uint4*)&sAlo[sr*LSTR + sc] =
        make_uint4(pack2(al[0],al[1]), pack2(al[2],al[3]),
                   pack2(al[4],al[5]), pack2(al[6],al[7]));
    *(uint4*)&sAlo[sr*LSTR + sc + 8] =
        make_uint4(pack2(al[8],al[9]), pack2(al[10],al[11]),
                   pack2(al[12],al[13]), pack2(al[14],al[15]));
    *(uint4*)&sBhi[sr*LSTR + sc] =
        make_uint4(pack2(bh[0],bh[1]), pack2(bh[2],bh[3]),
                   pack2(bh[4],bh[5]), pack2(bh[6],bh[7]));
    *(uint4*)&sBhi[sr*LSTR + sc + 8] =
        make_uint4(pack2(bh[8],bh[9]), pack2(bh[10],bh[11]),
                   pack2(bh[12],bh[13]), pack2(bh[14],bh[15]));
    *(uint4*)&sBlo[sr*LSTR + sc] =
        make_uint4(pack2(bl[0],bl[1]), pack2(bl[2],bl[3]),
                   pack2(bl[4],bl[5]), pack2(bl[6],bl[7]));
    *(uint4*)&sBlo[sr*LSTR + sc + 8] =
        make_uint4(pack2(bl[8],bl[9]), pack2(bl[10],bl[11]),
                   pack2(bl[12],bl[13]), pack2(bl[14],bl[15]));
    __syncthreads();

    half8 afh[4], afl[4], bfh[4], bfl[4];
    #pragma unroll
    for (int mt = 0; mt < 4; ++mt) {
      const int ar = wr + mt*16 + lrow;
      afh[mt] = *(const half8*)&sAhi[ar*LSTR + quad*8];
      afl[mt] = *(const half8*)&sAlo[ar*LSTR + quad*8];
    }
    #pragma unroll
    for (int nt = 0; nt < 4; ++nt) {
      const int br = wc + nt*16 + lrow;
      bfh[nt] = *(const half8*)&sBhi[br*LSTR + quad*8];
      bfl[nt] = *(const half8*)&sBlo[br*LSTR + quad*8];
    }
    #pragma unroll
    for (int mt = 0; mt < 4; ++mt)
      #pragma unroll
      for (int nt = 0; nt < 4; ++nt) {
        acc[mt][nt] = __builtin_amdgcn_mfma_f32_16x16x32_f16(afh[mt], bfh[nt], acc[mt][nt], 0, 0, 0);
        acc[mt][nt] = __builtin_amdgcn_mfma_f32_16x16x32_f16(afl[mt], bfh[nt], acc[mt][nt], 0, 0, 0);
        acc[mt][nt] = __builtin_amdgcn_mfma_f32_16x16x32_f16(afh[mt], bfl[nt], acc[mt][nt], 0, 0, 0);
      }
  }
  #pragma unroll
  for (int mt = 0; mt < 4; ++mt)
    #pragma unroll
    for (int nt = 0; nt < 4; ++nt)
      #pragma unroll
      for (int reg = 0; reg < 4; ++reg) {
        const int m = m0 + wr + mt*16 + quad*4 + reg;
        const int n = n0 + wc + nt*16 + lrow;
        float c = acc[mt][nt][reg];
        if (bias) c += bias[n];
        if (relu) c = fmaxf(c, 0.0f);
        C[(size_t)m * N + n] = c;
      }
}

// ---------------------------------------------------------------------------
// FUSED: sequential slot assignment (block 0) + split-K NN exp-GEMM
// (blocks 1..256). GEMM uses m_base (available before the sequential phase);
// the exp(m_base-mOut) factor is folded into ksum, so the roles are fully
// independent and the ~93 us of GEMM hides under the ~152 us single-wave
// sequential critical path. Blocks are independent (no dispatch-order or
// co-residency assumption). LDS: one 70656-B arena aliased per role.
// ---------------------------------------------------------------------------
#define LSB 34
#define EXP_SCALE 16384.0f
#define KCHUNK 1024
__global__ __launch_bounds__(256) void seq_plus_gemm(
    const float* __restrict__ S0T, const float* __restrict__ G,
    const float* __restrict__ t16v, const int* __restrict__ t16i,
    const float* __restrict__ gv16, const int* __restrict__ gj16,
    int* __restrict__ slots,
    const float* __restrict__ B, const float* __restrict__ mArr,
    float* __restrict__ part)
{
  __shared__ __align__(16) unsigned char smem[70656];

  if (blockIdx.x == 0) {
    // ======================= sequential phase =======================
    unsigned int* bitmap = (unsigned int*)smem;            //  4096 B
    float* sv       = (float*)(smem + 4096);               // 16384 B
    int*   si       = (int*)  (smem + 20480);              // 16384 B
    float* gv       = (float*)(smem + 36864);              // 16384 B
    int*   gj       = (int*)  (smem + 53248);              // 16384 B
    int*   slots_sh = (int*)  (smem + 69632);              //  1024 B
    volatile unsigned int* vbm = bitmap;
    const int tt = threadIdx.x;
    for (int q = tt; q < SLOTS/32; q += 256) bitmap[q] = 0u;
    for (int q = tt; q < BATCH*16; q += 256) {
      sv[q] = t16v[q]; si[q] = t16i[q]; gv[q] = gv16[q]; gj[q] = gj16[q];
    }
    __syncthreads();
    if (tt < 64) {
      const int lane = tt;
      unsigned long long alive[4] = {0ull,0ull,0ull,0ull};
      int slotr0 = -1, slotr1 = -1, slotr2 = -1, slotr3 = -1;

      for (int i = 0; i < BATCH; ++i) {
        float myv = -1e30f; int myslot = 0; bool bvalid = false;
        if (lane < 16) {
          myv = sv[i*16 + lane]; myslot = si[i*16 + lane];
          bvalid = (((vbm[myslot >> 5] >> (myslot & 31)) & 1u) == 0u);
        }
        unsigned long long bb = __ballot(bvalid);
        float ov = -1e30f; int oj = 0; bool ovalid = false;
        if (lane < 16) {
          ov = gv[i*16 + lane]; oj = gj[i*16 + lane];
          unsigned long long am = (oj < 64) ? alive[0] : (oj < 128) ? alive[1]
                                 : (oj < 192) ? alive[2] : alive[3];
          ovalid = (ov > -1e29f) && (((am >> (oj & 63)) & 1ull) != 0ull);
        }
        unsigned long long ob = __ballot(ovalid);

        float bval; int bslot;
        if (bb != 0ull) {
          int bl = __ffsll((unsigned long long)bb) - 1;
          bval = __shfl(myv, bl); bslot = __shfl(myslot, bl);
        } else {
          float fv = -1e30f; int fi = 0x7fffffff;
          for (int s = lane; s < SLOTS; s += 64) {
            if (((vbm[s >> 5] >> (s & 31)) & 1u) == 0u) {
              float x = S0T[(size_t)i*SLOTS + s];
              if (x > fv || (x == fv && s < fi)) { fv = x; fi = s; }
            }
          }
          #pragma unroll
          for (int off = 32; off; off >>= 1) {
            float ovv = __shfl_xor(fv, off); int oii = __shfl_xor(fi, off);
            if (ovv > fv || (ovv == fv && oii < fi)) { fv = ovv; fi = oii; }
          }
          bval = fv; bslot = fi;
        }

        float oval = -1e30f; int oslot = 0x7fffffff;
        if (ob != 0ull) {
          int ol = __ffsll((unsigned long long)ob) - 1;
          oval = __shfl(ov, ol);
          int ojw = __shfl(oj, ol);
          int r = ojw >> 6;
          int srg = (r == 0) ? slotr0 : (r == 1) ? slotr1 : (r == 2) ? slotr2 : slotr3;
          oslot = __shfl(srg, ojw & 63);
        } else if ((alive[0] | alive[1] | alive[2] | alive[3]) != 0ull) {
          float fv = -1e30f; int fj = 0x7fffffff;
          #pragma unroll
          for (int r = 0; r < 4; ++r) {
            int j = lane + 64*r;
            if (j < i && ((alive[r] >> lane) & 1ull)) {
              float x = G[(size_t)i*BATCH + j];
              if (x > fv || (x == fv && j < fj)) { fv = x; fj = j; }
            }
          }
          #pragma unroll
          for (int off = 32; off; off >>= 1) {
            float ovv = __shfl_xor(fv, off); int ojj = __shfl_xor(fj, off);
            if (ovv > fv || (ovv == fv && ojj < fj)) { fv = ovv; fj = ojj; }
          }
          if (fj != 0x7fffffff) {
            oval = fv;
            int r = fj >> 6;
            int srg = (r == 0) ? slotr0 : (r == 1) ? slotr1 : (r == 2) ? slotr2 : slotr3;
            oslot = __shfl(srg, fj & 63);
          }
        }

        const bool owins = (oval > bval) || (oval == bval && oslot < bslot);
        const int sloti = owins ? oslot : bslot;

        unsigned long long kb0 = __ballot(slotr0 == sloti);
        unsigned long long kb1 = __ballot(slotr1 == sloti);
        unsigned long long kb2 = __ballot(slotr2 == sloti);
        unsigned long long kb3 = __ballot(slotr3 == sloti);
        alive[0] &= ~kb0; alive[1] &= ~kb1; alive[2] &= ~kb2; alive[3] &= ~kb3;
        const int r_new = i >> 6;
        if (lane == (i & 63)) {
          if (r_new == 0) slotr0 = sloti;
          else if (r_new == 1) slotr1 = sloti;
          else if (r_new == 2) slotr2 = sloti;
          else slotr3 = sloti;
        }
        alive[r_new] |= (1ull << (i & 63));
        if (lane == 0) {
          slots_sh[i] = sloti;
          vbm[sloti >> 5] = vbm[sloti >> 5] | (1u << (sloti & 31));
        }
        __builtin_amdgcn_wave_barrier();
      }
      for (int q = lane; q < BATCH; q += 64) slots[q] = slots_sh[q];
    }
    return;
  }

  // ======================= exp-GEMM phase (blocks 1..256) =======================
  unsigned short* sAhi = (unsigned short*)smem;            // 10240 B
  unsigned short* sAlo = (unsigned short*)(smem + 10240);  // 10240 B
  unsigned short* sBhi = (unsigned short*)(smem + 20480);  //  8704 B
  unsigned short* sBlo = (unsigned short*)(smem + 29184);  //  8704 B -> 37888

  const int b  = blockIdx.x - 1;           // 0..255
  const int bx = b >> 7;                   // 0..1   (M tiles)
  const int by = (b >> 5) & 3;             // 0..3   (N tiles)
  const int bz = b & 31;                   // 0..31  (K chunks)
  const int m0 = bx * 128, n0 = by * 128;
  const int kb = bz * KCHUNK;
  const int t = threadIdx.x;
  const int wave = t >> 6, lane = t & 63;
  const int wr = (wave >> 1) * 64, wc = (wave & 1) * 64;
  const int lrow = lane & 15, quad = lane >> 4;
  const int sr = t >> 1;           // A staging row (0..127), 2 threads/row
  const int sc = (t & 1) * 16;     // A staging k-offset
  const int pr = t >> 4;           // B k-pair row (0..15) -> k rows 2pr,2pr+1
  const int nbase = (t & 15) * 8;  // B n-offset (0..120)
  const float mrow = mArr[m0 + sr];

  f32x4 acc[4][4];
  #pragma unroll
  for (int a = 0; a < 4; ++a)
    #pragma unroll
    for (int c = 0; c < 4; ++c)
      acc[a][c] = (f32x4){0.f, 0.f, 0.f, 0.f};

  for (int k0 = kb; k0 < kb + KCHUNK; k0 += 32) {
    // ---- global loads (A rows of S0T, B rows of mem_vals: both coalesced)
    const float* ap = S0T + (size_t)(m0 + sr) * SLOTS + k0 + sc;
    float4 a0 = *(const float4*)(ap);
    float4 a1 = *(const float4*)(ap + 4);
    float4 a2 = *(const float4*)(ap + 8);
    float4 a3 = *(const float4*)(ap + 12);
    const float* bp = B + (size_t)(k0 + 2*pr) * DIM + n0 + nbase;
    float4 q0 = *(const float4*)(bp);
    float4 q1 = *(const float4*)(bp + 4);
    float4 q2 = *(const float4*)(bp + DIM);
    float4 q3 = *(const float4*)(bp + DIM + 4);

    // ---- A: exp (scaled, vs m_base) + fp16 hi/lo split
    float ax[16] = {a0.x,a0.y,a0.z,a0.w, a1.x,a1.y,a1.z,a1.w,
                    a2.x,a2.y,a2.z,a2.w, a3.x,a3.y,a3.z,a3.w};
    unsigned short ah[16], av[16];
    #pragma unroll
    for (int e = 0; e < 16; ++e) {
      float rm; float ee = __expf(ax[e] - mrow) * EXP_SCALE;
      ah[e] = h_split(ee, rm); av[e] = h_rne(rm);
    }
    // ---- B: fp16 hi/lo split + pack k-pairs (2pr, 2pr+1) per n
    float r0[8] = {q0.x,q0.y,q0.z,q0.w, q1.x,q1.y,q1.z,q1.w};
    float r1[8] = {q2.x,q2.y,q2.z,q2.w, q3.x,q3.y,q3.z,q3.w};
    unsigned int pbh[8], pbl[8];
    #pragma unroll
    for (int e = 0; e < 8; ++e) {
      float rm0, rm1;
      unsigned short h0 = h_split(r0[e], rm0);
      unsigned short h1 = h_split(r1[e], rm1);
      pbh[e] = pack2(h0, h1);
      pbl[e] = pack2(h_rne(rm0), h_rne(rm1));
    }

    __syncthreads();
    // A: linear [row][k] (proven layout)
    *(uint4*)&sAhi[sr*LSTR + sc] =
        make_uint4(pack2(ah[0],ah[1]), pack2(ah[2],ah[3]),
                   pack2(ah[4],ah[5]), pack2(ah[6],ah[7]));
    *(uint4*)&sAhi[sr*LSTR + sc + 8] =
        make_uint4(pack2(ah[8],ah[9]), pack2(ah[10],ah[11]),
                   pack2(ah[12],ah[13]), pack2(ah[14],ah[15]));
    *(uint4*)&sAlo[sr*LSTR + sc] =
        make_uint4(pack2(av[0],av[1]), pack2(av[2],av[3]),
                   pack2(av[4],av[5]), pack2(av[6],av[7]));
    *(uint4*)&sAlo[sr*LSTR + sc + 8] =
        make_uint4(pack2(av[8],av[9]), pack2(av[10],av[11]),
                   pack2(av[12],av[13]), pack2(av[14],av[15]));
    // B: transposed [n][k] as u32 pairs; halfword k=2pr at u32 index n*17+pr
    {
      unsigned int* bh32 = (unsigned int*)sBhi;
      unsigned int* bl32 = (unsigned int*)sBlo;
      #pragma unroll
      for (int e = 0; e < 8; ++e) bh32[(nbase + e)*17 + pr] = pbh[e];
      #pragma unroll
      for (int e = 0; e < 8; ++e) bl32[(nbase + e)*17 + pr] = pbl[e];
    }
    __syncthreads();

    half8 afh[4], afl[4], bfh[4], bfl[4];
    #pragma unroll
    for (int mt = 0; mt < 4; ++mt) {
      const int ar = wr + mt*16 + lrow;
      afh[mt] = *(const half8*)&sAhi[ar*LSTR + quad*8];
      afl[mt] = *(const half8*)&sAlo[ar*LSTR + quad*8];
    }
    #pragma unroll
    for (int nt = 0; nt < 4; ++nt) {
      const int br = wc + nt*16 + lrow;
      const unsigned int* ph = (const unsigned int*)sBhi + br*17 + quad*4;
      const unsigned int* pl = (const unsigned int*)sBlo + br*17 + quad*4;
      union FU { unsigned int u[4]; half8 s; };
      FU th, tl;
      th.u[0] = ph[0]; th.u[1] = ph[1]; th.u[2] = ph[2]; th.u[3] = ph[3];
      tl.u[0] = pl[0]; tl.u[1] = pl[1]; tl.u[2] = pl[2]; tl.u[3] = pl[3];
      bfh[nt] = th.s; bfl[nt] = tl.s;
    }
    #pragma unroll
    for (int mt = 0; mt < 4; ++mt)
      #pragma unroll
      for (int nt = 0; nt < 4; ++nt) {
        acc[mt][nt] = __builtin_amdgcn_mfma_f32_16x16x32_f16(afh[mt], bfh[nt], acc[mt][nt], 0, 0, 0);
        acc[mt][nt] = __builtin_amdgcn_mfma_f32_16x16x32_f16(afl[mt], bfh[nt], acc[mt][nt], 0, 0, 0);
        acc[mt][nt] = __builtin_amdgcn_mfma_f32_16x16x32_f16(afh[mt], bfl[nt], acc[mt][nt], 0, 0, 0);
      }
  }
  float* Cz = part + (size_t)bz * BATCH * DIM;
  #pragma unroll
  for (int mt = 0; mt < 4; ++mt)
    #pragma unroll
    for (int nt = 0; nt < 4; ++nt)
      #pragma unroll
      for (int reg = 0; reg < 4; ++reg) {
        const int m = m0 + wr + mt*16 + quad*4 + reg;
        const int n = n0 + wc + nt*16 + lrow;
        Cz[(size_t)m * DIM + n] = acc[mt][nt][reg];
      }
}

// reduce split-K partials; rescale base-max GEMM to the corrected max:
// out = (sum_z part_z) * exp(m_base[row] - mOut[row]) / EXP_SCALE
__global__ __launch_bounds__(256) void ksum(
    const float* __restrict__ part, float* __restrict__ out, int mn, int nz,
    const float* __restrict__ m_base, const float* __restrict__ mOut,
    float inv_scale)
{
  int idx = blockIdx.x * 256 + threadIdx.x;
  if (idx >= mn) return;
  float s = 0.f;
  for (int z = 0; z < nz; ++z) s += part[(size_t)z * mn + idx];
  const int row = idx >> 9;   // DIM = 512
  out[idx] = s * __expf(m_base[row] - mOut[row]) * inv_scale;
}

// ---------------------------------------------------------------------------
// Per-chunk stats: top-16 + max + sumexp of one 8192-elem chunk of a row.
// All per-thread arrays statically indexed (registers). Grid (NCHUNK, BATCH).
// ---------------------------------------------------------------------------
__global__ __launch_bounds__(256) void col_chunk(
    const float* __restrict__ S0T, float* __restrict__ cmax,
    float* __restrict__ cse, float* __restrict__ c16v, int* __restrict__ c16i)
{
  const int ch = blockIdx.x, row = blockIdx.y;
  const int t = threadIdx.x;
  const float* col = S0T + (size_t)row * SLOTS + ch * CHSZ;
  const int base = t * (CHSZ / 256);     // 32 contiguous per thread
  float v[16]; int ix[16];
  #pragma unroll
  for (int q = 0; q < 16; ++q) { v[q] = -1e30f; ix[q] = 0x7fffffff; }
  #pragma unroll
  for (int u = 0; u < 32; u += 4) {
    float4 x4 = *(const float4*)(col + base + u);
    float xs[4] = {x4.x, x4.y, x4.z, x4.w};
    #pragma unroll
    for (int e = 0; e < 4; ++e) {
      float cv = xs[e]; int ci = ch * CHSZ + base + u + e;
      if (cv > v[15] || (cv == v[15] && ci < ix[15])) {
        #pragma unroll
        for (int q = 0; q < 16; ++q) {
          bool better = (cv > v[q]) || (cv == v[q] && ci < ix[q]);
          float tv = better ? v[q] : cv;  // static-index swap (cndmask)
          int   ti = better ? ix[q] : ci;
          v[q]  = better ? cv : v[q];
          ix[q] = better ? ci : ix[q];
          cv = tv; ci = ti;
        }
      }
    }
  }
  __shared__ float redv[4]; __shared__ int redi[4];
  __shared__ float outv[16]; __shared__ int outi[16];
  for (int r = 0; r < 16; ++r) {
    float bv = v[0]; int bi = ix[0];
    #pragma unroll
    for (int off = 32; off; off >>= 1) {
      float ov = __shfl_xor(bv, off); int oi = __shfl_xor(bi, off);
      if (ov > bv || (ov == bv && oi < bi)) { bv = ov; bi = oi; }
    }
    if ((t & 63) == 0) { redv[t >> 6] = bv; redi[t >> 6] = bi; }
    __syncthreads();
    float fv = redv[0]; int fi = redi[0];
    #pragma unroll
    for (int w = 1; w < 4; ++w)
      if (redv[w] > fv || (redv[w] == fv && redi[w] < fi)) { fv = redv[w]; fi = redi[w]; }
    if (t == 0) { outv[r] = fv; outi[r] = fi; }
    // winner advances via constant-indexed shift-down (keeps arrays in VGPRs)
    const bool adv = (v[0] == fv) && (ix[0] == fi);
    #pragma unroll
    for (int q = 0; q < 15; ++q) {
      v[q]  = adv ? v[q+1]  : v[q];
      ix[q] = adv ? ix[q+1] : ix[q];
    }
    v[15]  = adv ? -1e30f     : v[15];
    ix[15] = adv ? 0x7fffffff : ix[15];
    __syncthreads();
  }
  const int cidx = row * NCHUNK + ch;
  if (t < 16) { c16v[cidx*16 + t] = outv[t]; c16i[cidx*16 + t] = outi[t]; }
  const float m = outv[0];
  float s = 0.f;
  #pragma unroll
  for (int u = 0; u < 32; u += 4) {
    float4 x4 = *(const float4*)(col + base + u);
    s += __expf(x4.x - m) + __expf(x4.y - m) + __expf(x4.z - m) + __expf(x4.w - m);
  }
  #pragma unroll
  for (int off = 32; off; off >>= 1) s += __shfl_xor(s, off);
  __shared__ float ws2[4];
  if ((t & 63) == 0) ws2[t >> 6] = s;
  __syncthreads();
  if (t == 0) { cse[cidx] = ws2[0]+ws2[1]+ws2[2]+ws2[3]; cmax[cidx] = m; }
}

// ---------------------------------------------------------------------------
// Combine chunk stats: row max, rescaled sumexp, merged global top-16.
// One wave per row; lane = (chunk<<4) | pos candidate.
// ---------------------------------------------------------------------------
__global__ __launch_bounds__(64) void col_combine(
    const float* __restrict__ cmax, const float* __restrict__ cse,
    const float* __restrict__ c16v, const int* __restrict__ c16i,
    float* __restrict__ m_base, float* __restrict__ se_base,
    float* __restrict__ t16v, int* __restrict__ t16i)
{
  const int i = blockIdx.x, lane = threadIdx.x;
  float v = c16v[(size_t)i * 64 + lane];
  int   id = c16i[(size_t)i * 64 + lane];
  float m0 = cmax[i*4+0], m1 = cmax[i*4+1], m2 = cmax[i*4+2], m3 = cmax[i*4+3];
  const float m = fmaxf(fmaxf(m0, m1), fmaxf(m2, m3));
  const float se = cse[i*4+0]*__expf(m0-m) + cse[i*4+1]*__expf(m1-m)
                 + cse[i*4+2]*__expf(m2-m) + cse[i*4+3]*__expf(m3-m);
  bool dead = false;
  for (int r = 0; r < 16; ++r) {
    float bv = dead ? -1e30f : v;
    int   bi = dead ? 0x7fffffff : id;
    #pragma unroll
    for (int off = 32; off; off >>= 1) {
      float ov = __shfl_xor(bv, off); int oi = __shfl_xor(bi, off);
      if (ov > bv || (ov == bv && oi < bi)) { bv = ov; bi = oi; }
    }
    if (!dead && v == bv && id == bi) dead = true;
    if (lane == 0) { t16v[i*16 + r] = bv; t16i[i*16 + r] = bi; }
  }
  if (lane == 0) { m_base[i] = m; se_base[i] = se; }
}

// ---------------------------------------------------------------------------
// Per-row top-16 of G[i, j<i]. One wave per row.
// ---------------------------------------------------------------------------
__global__ __launch_bounds__(64) void gtop16(
    const float* __restrict__ G, float* __restrict__ gv16, int* __restrict__ gj16)
{
  const int i = blockIdx.x, lane = threadIdx.x;
  __shared__ float vals[BATCH];
  for (int q = lane; q < BATCH; q += 64) vals[q] = (q < i) ? G[(size_t)i*BATCH + q] : -1e30f;
  __syncthreads();
  for (int r = 0; r < 16; ++r) {
    float bv = -1e30f; int bj = 0x7fffffff;
    for (int q = lane; q < BATCH; q += 64) {
      float x = vals[q];
      if (x > bv || (x == bv && q < bj)) { bv = x; bj = q; }
    }
    #pragma unroll
    for (int off = 32; off; off >>= 1) {
      float ov = __shfl_xor(bv, off); int oj = __shfl_xor(bj, off);
      if (ov > bv || (ov == bv && oj < bj)) { bv = ov; bj = oj; }
    }
    if (lane == 0) {
      gv16[i*16 + r] = bv; gj16[i*16 + r] = (bj == 0x7fffffff) ? 0 : bj;
      if (bj != 0x7fffffff) vals[bj] = -1e30f;
    }
    __syncthreads();
  }
}

// ---------------------------------------------------------------------------
__global__ __launch_bounds__(256) void nxt_kernel(
    const int* __restrict__ slots, int* __restrict__ nxt)
{
  __shared__ int sh[BATCH];
  const int j = threadIdx.x;
  sh[j] = slots[j];
  __syncthreads();
  const int sj = sh[j];
  int n = 0x7fffffff;
  for (int k = j + 1; k < BATCH; ++k)
    if (sh[k] == sj) { n = k; break; }
  nxt[j] = n;
}

// ---------------------------------------------------------------------------
__global__ __launch_bounds__(256) void coef_kernel(
    const float* __restrict__ S0T, const float* __restrict__ G,
    const int* __restrict__ slots, const int* __restrict__ nxt,
    const float* __restrict__ m_base, const float* __restrict__ se_base,
    float* __restrict__ mOut, float* __restrict__ Zout,
    float* __restrict__ Cadd, float* __restrict__ Csub)
{
  const int i = blockIdx.x, j = threadIdx.x;
  const bool alive = (j < i) && (nxt[j] >= i);
  const float g = alive ? G[(size_t)i*BATCH + j] : -1e30f;
  float bv = g;
  #pragma unroll
  for (int off = 32; off; off >>= 1) bv = fmaxf(bv, __shfl_xor(bv, off));
  __shared__ float red[4];
  if ((j & 63) == 0) red[j >> 6] = bv;
  __syncthreads();
  const float mb = m_base[i];
  const float mi = fmaxf(fmaxf(fmaxf(red[0], red[1]), fmaxf(red[2], red[3])), mb);
  const float sv = alive ? S0T[(size_t)i*SLOTS + slots[j]] : 0.f;
  const float ca = alive ? __expf(g - mi) : 0.f;
  const float cs = alive ? __expf(sv - mi) : 0.f;
  Cadd[(size_t)i*BATCH + j] = ca;
  Csub[(size_t)i*BATCH + j] = cs;
  float z = ca - cs;
  #pragma unroll
  for (int off = 32; off; off >>= 1) z += __shfl_xor(z, off);
  __syncthreads();
  if ((j & 63) == 0) red[j >> 6] = z;
  __syncthreads();
  if (j == 0) {
    mOut[i] = mi;
    Zout[i] = se_base[i] * __expf(mb - mi) + red[0] + red[1] + red[2] + red[3];
  }
}

// ---------------------------------------------------------------------------
__global__ __launch_bounds__(256) void readval_merge(
    const float* __restrict__ read_num, const float* __restrict__ Cadd,
    const float* __restrict__ Csub, const float* __restrict__ WVp,
    const float* __restrict__ mem_vals, const int* __restrict__ slots,
    const float* __restrict__ Zarr, const float* __restrict__ S_t,
    float* __restrict__ merged)
{
  const int i = blockIdx.x;
  const int t = threadIdx.x;
  merged[(size_t)i*1024 + t]        = S_t[(size_t)i*DIM + t];
  merged[(size_t)i*1024 + 256 + t]  = S_t[(size_t)i*DIM + 256 + t];
  float acc0 = read_num[(size_t)i*DIM + t];
  float acc1 = read_num[(size_t)i*DIM + 256 + t];
  for (int j = 0; j < BATCH; ++j) {
    float caj = Cadd[(size_t)i*BATCH + j];
    float csj = Csub[(size_t)i*BATCH + j];
    if (caj != 0.f || csj != 0.f) {
      int sj = slots[j];
      acc0 += caj * WVp[(size_t)j*DIM + t]       - csj * mem_vals[(size_t)sj*DIM + t];
      acc1 += caj * WVp[(size_t)j*DIM + 256 + t] - csj * mem_vals[(size_t)sj*DIM + 256 + t];
    }
  }
  const float invZ = 1.0f / Zarr[i];
  merged[(size_t)i*1024 + 512 + t] = acc0 * invZ;
  merged[(size_t)i*1024 + 768 + t] = acc1 * invZ;
}

// ---------------------------------------------------------------------------
extern "C" void kernel_launch(void* const* d_in, const int* in_sizes, int n_in,
                              void* d_out, int out_size, void* d_ws, size_t ws_size,
                              hipStream_t stream)
{
  (void)in_sizes; (void)n_in; (void)out_size; (void)ws_size;
  const float* S_t      = (const float*)d_in[0];
  const float* mem_keys = (const float*)d_in[1];
  const float* mem_vals = (const float*)d_in[2];
  const float* Wk       = (const float*)d_in[3];
  const float* bk       = (const float*)d_in[4];
  const float* Wv       = (const float*)d_in[5];
  const float* bv       = (const float*)d_in[6];
  const float* W1       = (const float*)d_in[7];
  const float* b1       = (const float*)d_in[8];
  const float* W2       = (const float*)d_in[9];
  const float* b2       = (const float*)d_in[10];
  float* out = (float*)d_out;

  // Workspace layout — same proven footprint; Khi/Klo tail no longer used.
  float* ws = (float*)d_ws;
  float* Kp       = ws + 0;         // [256,512]
  float* WVp      = ws + 131072;    // [256,512]
  float* G        = ws + 262144;    // [256,256]
  float* S0T      = ws + 327680;    // [256,32768]
  float* m_base   = ws + 8716288;   // [256]
  float* se_base  = ws + 8716544;   // [256]
  float* t16v     = ws + 8716800;   // [256,16]
  int*   t16i     = (int*)(ws + 8720896);
  float* gv16     = ws + 8724992;   // [256,16]
  int*   gj16     = (int*)(ws + 8729088);
  int*   slots    = (int*)(ws + 8733184);
  int*   nxt      = (int*)(ws + 8733440);
  float* mOut     = ws + 8733696;
  float* Zout     = ws + 8733952;
  float* Cadd     = ws + 8734208;   // [256,256]
  float* Csub     = ws + 8799744;   // [256,256]
  float* read_num = ws + 8865280;   // [256,512]
  float* merged   = ws + 8996352;   // [256,1024]
  float* hid      = ws + 9258496;   // [256,2048] ends 9782784
  float* part     = ws + 9782784;   // [32][256,512] ends 13977088
  // col_chunk scratch aliased onto head of part:
  float* cmaxb    = ws + 9782784;   // [256,4]
  float* cseb     = ws + 9783808;   // [256,4]
  float* c16vb    = ws + 9784832;   // [256,4,16]
  int*   c16ib    = (int*)(ws + 9801216);  // [256,4,16] ends 9817600 < 13977088

  // phase 1: projections + gram + base scores — all via fp16-hilo MFMA
  hgemm_bt<<<dim3(2, 4),   dim3(256), 0, stream>>>(S_t, Wk, bk, Kp,  256, 512, 512, 0);
  hgemm_bt<<<dim3(2, 4),   dim3(256), 0, stream>>>(S_t, Wv, bv, WVp, 256, 512, 512, 0);
  hgemm_bt<<<dim3(2, 2),   dim3(256), 0, stream>>>(Kp,  Kp, nullptr, G, 256, 256, 512, 0);
  hgemm_bt<<<dim3(2, 256), dim3(256), 0, stream>>>(Kp, mem_keys, nullptr, S0T,
                                                   256, 32768, 512, 0);

  // phase 2: chunked per-column stats + combine, G top-16
  col_chunk<<<dim3(NCHUNK, 256), dim3(256), 0, stream>>>(S0T, cmaxb, cseb, c16vb, c16ib);
  col_combine<<<dim3(256), dim3(64), 0, stream>>>(cmaxb, cseb, c16vb, c16ib,
                                                  m_base, se_base, t16v, t16i);
  gtop16<<<dim3(256), dim3(64), 0, stream>>>(G, gv16, gj16);

  // phase 2.5: FUSED sequential phase (block 0) + read exp-GEMM (blocks 1..256)
  seq_plus_gemm<<<dim3(257), dim3(256), 0, stream>>>(S0T, G, t16v, t16i, gv16, gj16,
                                                     slots, mem_vals, m_base, part);

  // phase 3: write-interaction coefficients + split-K reduce + merge
  nxt_kernel<<<dim3(1), dim3(256), 0, stream>>>(slots, nxt);
  coef_kernel<<<dim3(256), dim3(256), 0, stream>>>(S0T, G, slots, nxt, m_base, se_base,
                                                   mOut, Zout, Cadd, Csub);
  ksum<<<dim3(512), dim3(256), 0, stream>>>(part, read_num, 131072, 32,
                                            m_base, mOut, 1.0f / EXP_SCALE);
  readval_merge<<<dim3(256), dim3(256), 0, stream>>>(read_num, Cadd, Csub, WVp,
                                                     mem_vals, slots, Zout, S_t, merged);

  // phase 4: MLP via fp16-hilo MFMA
  hgemm_bt<<<dim3(2, 16), dim3(256), 0, stream>>>(merged, W1, b1, hid, 256, 2048, 1024, 1);
  hgemm_bt<<<dim3(2, 4),  dim3(256), 0, stream>>>(hid,    W2, b2, out, 256, 512,  2048, 0);
}

// Round 5
// 793.983 us; speedup vs baseline: 1.0986x; 1.0986x over previous
//
#include <hip/hip_runtime.h>
#include <cstdint>
#include <cstddef>

#define BATCH 256
#define DIM   512
#define HIDN  2048
#define SLOTS 32768
#define NCHUNK 4
#define CHSZ  (SLOTS/NCHUNK)    // 8192

typedef __attribute__((ext_vector_type(8))) short short8;
typedef __attribute__((ext_vector_type(8))) _Float16 half8;
typedef __attribute__((ext_vector_type(4))) float f32x4;

// ---------------------------------------------------------------------------
// bf16 split helpers (RNE) — score GEMM path (proven at K=512)
// ---------------------------------------------------------------------------
__device__ __forceinline__ unsigned short bf_rne(float x) {
  unsigned int u = __float_as_uint(x);
  unsigned int r = (u + 0x7fffu + ((u >> 16) & 1u)) >> 16;
  return (unsigned short)r;
}
__device__ __forceinline__ unsigned short bf_split(float x, float& rem) {
  unsigned short h = bf_rne(x);
  rem = x - __uint_as_float(((unsigned int)h) << 16);
  return h;
}
__device__ __forceinline__ unsigned int pack2(unsigned short a, unsigned short b) {
  return (unsigned int)a | ((unsigned int)b << 16);
}

// ---------------------------------------------------------------------------
// fp16 split helpers (RNE) — read exp-GEMM path (proven at K=32768)
// ---------------------------------------------------------------------------
__device__ __forceinline__ unsigned short h_rne(float x) {
  _Float16 h = (_Float16)x;
  union { _Float16 f; unsigned short u; } cv; cv.f = h;
  return cv.u;
}
__device__ __forceinline__ unsigned short h_split(float x, float& rem) {
  _Float16 h = (_Float16)x;
  rem = x - (float)h;
  union { _Float16 f; unsigned short u; } cv; cv.f = h;
  return cv.u;
}

// ---------------------------------------------------------------------------
// 64x64 fp32 VALU GEMM tile body: C = act(A @ B^T + bias). TK=16.
// (round-3 proven; tile size matches the tiny shapes' need for block count)
// ---------------------------------------------------------------------------
__device__ __forceinline__ void gemm64_body(
    const float* __restrict__ A, const float* __restrict__ B,
    const float* __restrict__ bias, float* __restrict__ C,
    int M, int N, int K, int relu, int bx, int by, int t,
    float (*As)[68], float (*Bs)[68])
{
  const int m0 = bx * 64;
  const int n0 = by * 64;
  const int tx = t & 15, ty = t >> 4;
  const int lr = t >> 2;
  const int lc = (t & 3) * 4;
  float acc[4][4] = {};
  for (int k0 = 0; k0 < K; k0 += 16) {
    float4 a = *(const float4*)(A + (size_t)(m0 + lr) * K + k0 + lc);
    float4 b = *(const float4*)(B + (size_t)(n0 + lr) * K + k0 + lc);
    __syncthreads();
    As[lc+0][lr] = a.x; As[lc+1][lr] = a.y; As[lc+2][lr] = a.z; As[lc+3][lr] = a.w;
    Bs[lc+0][lr] = b.x; Bs[lc+1][lr] = b.y; Bs[lc+2][lr] = b.z; Bs[lc+3][lr] = b.w;
    __syncthreads();
    #pragma unroll
    for (int k = 0; k < 16; ++k) {
      const float4 a4 = *(const float4*)&As[k][ty*4];
      const float4 b4 = *(const float4*)&Bs[k][tx*4];
      const float aa[4] = {a4.x, a4.y, a4.z, a4.w};
      const float bb[4] = {b4.x, b4.y, b4.z, b4.w};
      #pragma unroll
      for (int u = 0; u < 4; ++u)
        #pragma unroll
        for (int v = 0; v < 4; ++v)
          acc[u][v] = fmaf(aa[u], bb[v], acc[u][v]);
    }
  }
  #pragma unroll
  for (int u = 0; u < 4; ++u) {
    const int m = m0 + ty*4 + u;
    float o[4];
    #pragma unroll
    for (int v = 0; v < 4; ++v) {
      float c = acc[u][v];
      if (bias) c += bias[n0 + tx*4 + v];
      if (relu) c = fmaxf(c, 0.0f);
      o[v] = c;
    }
    *(float4*)(C + (size_t)m * N + n0 + tx*4) = make_float4(o[0], o[1], o[2], o[3]);
  }
}

// standalone 64x64 GEMM (MLP W1/W2)
__global__ __launch_bounds__(256) void gemm_bt(
    const float* __restrict__ A, const float* __restrict__ B,
    const float* __restrict__ bias, float* __restrict__ C,
    int M, int N, int K, int relu)
{
  __shared__ __align__(16) float As[16][68];
  __shared__ __align__(16) float Bs[16][68];
  gemm64_body(A, B, bias, C, M, N, K, relu, blockIdx.x, blockIdx.y, threadIdx.x, As, Bs);
}

// FUSED: Wk-projection (blocks 0..31) + Wv-projection (blocks 32..63).
// Independent roles; halves the serial projection time.
__global__ __launch_bounds__(256) void proj2(
    const float* __restrict__ S_t,
    const float* __restrict__ Wk, const float* __restrict__ bk, float* __restrict__ Kp,
    const float* __restrict__ Wv, const float* __restrict__ bv, float* __restrict__ WVp)
{
  __shared__ __align__(16) float As[16][68];
  __shared__ __align__(16) float Bs[16][68];
  int b = blockIdx.x;
  if (b < 32)
    gemm64_body(S_t, Wk, bk, Kp,  256, 512, 512, 0, b & 3, b >> 2, threadIdx.x, As, Bs);
  else {
    b -= 32;
    gemm64_body(S_t, Wv, bv, WVp, 256, 512, 512, 0, b & 3, b >> 2, threadIdx.x, As, Bs);
  }
}

// ---------------------------------------------------------------------------
// fp32 -> bf16 hi/lo split (round-3 proven)
// ---------------------------------------------------------------------------
__global__ __launch_bounds__(256) void convert_hilo(
    const float* __restrict__ x, unsigned short* __restrict__ hi,
    unsigned short* __restrict__ lo, int n)
{
  int idx = (blockIdx.x * 256 + threadIdx.x) * 4;
  if (idx >= n) return;
  float4 v = *(const float4*)(x + idx);
  float r0, r1, r2, r3;
  unsigned short h0 = bf_split(v.x, r0), h1 = bf_split(v.y, r1);
  unsigned short h2 = bf_split(v.z, r2), h3 = bf_split(v.w, r3);
  *(uint2*)(hi + idx) = make_uint2(pack2(h0, h1), pack2(h2, h3));
  *(uint2*)(lo + idx) = make_uint2(pack2(bf_rne(r0), bf_rne(r1)),
                                   pack2(bf_rne(r2), bf_rne(r3)));
}

// ---------------------------------------------------------------------------
// bf16 hi/lo MFMA BT-GEMM body (scores; round-3 proven at K=512)
// ---------------------------------------------------------------------------
#define LSTR 40
__device__ __forceinline__ void mfma_scores_body(
    const unsigned short* __restrict__ Ahi, const unsigned short* __restrict__ Alo,
    const float* __restrict__ B, float* __restrict__ C, int M, int N, int K,
    int bx, int by, int t,
    unsigned short* sAhi, unsigned short* sAlo,
    unsigned short* sBhi, unsigned short* sBlo)
{
  const int m0 = bx * 128, n0 = by * 128;
  const int wave = t >> 6, lane = t & 63;
  const int wr = (wave >> 1) * 64, wc = (wave & 1) * 64;
  const int lrow = lane & 15, quad = lane >> 4;
  const int sr = t >> 1;
  const int sc = (t & 1) * 16;

  f32x4 acc[4][4];
  #pragma unroll
  for (int a = 0; a < 4; ++a)
    #pragma unroll
    for (int b = 0; b < 4; ++b)
      acc[a][b] = (f32x4){0.f, 0.f, 0.f, 0.f};

  for (int k0 = 0; k0 < K; k0 += 32) {
    const size_t aoff = (size_t)(m0 + sr) * K + k0 + sc;
    uint4 ah0 = *(const uint4*)(Ahi + aoff);
    uint4 ah1 = *(const uint4*)(Ahi + aoff + 8);
    uint4 al0 = *(const uint4*)(Alo + aoff);
    uint4 al1 = *(const uint4*)(Alo + aoff + 8);
    const float* bp = B + (size_t)(n0 + sr) * K + k0 + sc;
    float4 b0 = *(const float4*)(bp + 0);
    float4 b1 = *(const float4*)(bp + 4);
    float4 b2 = *(const float4*)(bp + 8);
    float4 b3 = *(const float4*)(bp + 12);
    float bx_[16] = {b0.x,b0.y,b0.z,b0.w, b1.x,b1.y,b1.z,b1.w,
                     b2.x,b2.y,b2.z,b2.w, b3.x,b3.y,b3.z,b3.w};
    unsigned short bh[16], bl[16];
    #pragma unroll
    for (int e = 0; e < 16; ++e) {
      float rem; bh[e] = bf_split(bx_[e], rem); bl[e] = bf_rne(rem);
    }
    __syncthreads();
    *(uint4*)&sAhi[sr*LSTR + sc]     = ah0;
    *(uint4*)&sAhi[sr*LSTR + sc + 8] = ah1;
    *(uint4*)&sAlo[sr*LSTR + sc]     = al0;
    *(uint4*)&sAlo[sr*LSTR + sc + 8] = al1;
    *(uint4*)&sBhi[sr*LSTR + sc] =
        make_uint4(pack2(bh[0],bh[1]), pack2(bh[2],bh[3]),
                   pack2(bh[4],bh[5]), pack2(bh[6],bh[7]));
    *(uint4*)&sBhi[sr*LSTR + sc + 8] =
        make_uint4(pack2(bh[8],bh[9]), pack2(bh[10],bh[11]),
                   pack2(bh[12],bh[13]), pack2(bh[14],bh[15]));
    *(uint4*)&sBlo[sr*LSTR + sc] =
        make_uint4(pack2(bl[0],bl[1]), pack2(bl[2],bl[3]),
                   pack2(bl[4],bl[5]), pack2(bl[6],bl[7]));
    *(uint4*)&sBlo[sr*LSTR + sc + 8] =
        make_uint4(pack2(bl[8],bl[9]), pack2(bl[10],bl[11]),
                   pack2(bl[12],bl[13]), pack2(bl[14],bl[15]));
    __syncthreads();

    short8 afh[4], afl[4], bfh[4], bfl[4];
    #pragma unroll
    for (int mt = 0; mt < 4; ++mt) {
      const int ar = wr + mt*16 + lrow;
      afh[mt] = *(const short8*)&sAhi[ar*LSTR + quad*8];
      afl[mt] = *(const short8*)&sAlo[ar*LSTR + quad*8];
    }
    #pragma unroll
    for (int nt = 0; nt < 4; ++nt) {
      const int br = wc + nt*16 + lrow;
      bfh[nt] = *(const short8*)&sBhi[br*LSTR + quad*8];
      bfl[nt] = *(const short8*)&sBlo[br*LSTR + quad*8];
    }
    #pragma unroll
    for (int mt = 0; mt < 4; ++mt)
      #pragma unroll
      for (int nt = 0; nt < 4; ++nt) {
        acc[mt][nt] = __builtin_amdgcn_mfma_f32_16x16x32_bf16(afh[mt], bfh[nt], acc[mt][nt], 0, 0, 0);
        acc[mt][nt] = __builtin_amdgcn_mfma_f32_16x16x32_bf16(afl[mt], bfh[nt], acc[mt][nt], 0, 0, 0);
        acc[mt][nt] = __builtin_amdgcn_mfma_f32_16x16x32_bf16(afh[mt], bfl[nt], acc[mt][nt], 0, 0, 0);
      }
  }
  #pragma unroll
  for (int mt = 0; mt < 4; ++mt)
    #pragma unroll
    for (int nt = 0; nt < 4; ++nt)
      #pragma unroll
      for (int reg = 0; reg < 4; ++reg) {
        const int m = m0 + wr + mt*16 + quad*4 + reg;
        const int n = n0 + wc + nt*16 + lrow;
        C[(size_t)m * N + n] = acc[mt][nt][reg];
      }
}

// FUSED: gram GEMM (blocks 0..15, fp32 64x64) + score MFMA GEMM (blocks
// 16..527, bf16-hilo 128x128). Both depend only on Kp — independent roles.
__global__ __launch_bounds__(256) void gram_scores(
    const float* __restrict__ Kp, float* __restrict__ G,
    const unsigned short* __restrict__ Khi, const unsigned short* __restrict__ Klo,
    const float* __restrict__ mem_keys, float* __restrict__ S0T)
{
  __shared__ __align__(16) unsigned char arena[40960];
  const int b = blockIdx.x;
  if (b < 16) {
    float (*As)[68] = (float (*)[68])arena;
    float (*Bs)[68] = (float (*)[68])(arena + 4352);
    gemm64_body(Kp, Kp, nullptr, G, 256, 256, 512, 0, b & 3, b >> 2, threadIdx.x, As, Bs);
  } else {
    const int sb = b - 16;
    unsigned short* sAhi = (unsigned short*)arena;
    unsigned short* sAlo = (unsigned short*)(arena + 10240);
    unsigned short* sBhi = (unsigned short*)(arena + 20480);
    unsigned short* sBlo = (unsigned short*)(arena + 30720);
    mfma_scores_body(Khi, Klo, mem_keys, S0T, 256, 32768, 512,
                     sb & 1, sb >> 1, threadIdx.x, sAhi, sAlo, sBhi, sBlo);
  }
}

// ---------------------------------------------------------------------------
// FUSED: col_chunk (blocks 0..1023) + gtop16 (blocks 1024..1279, rewritten
// for 256 uniform threads). Both depend only on S0T / G.
// ---------------------------------------------------------------------------
__global__ __launch_bounds__(256) void colchunk_gtop(
    const float* __restrict__ S0T, float* __restrict__ cmax,
    float* __restrict__ cse, float* __restrict__ c16v, int* __restrict__ c16i,
    const float* __restrict__ G, float* __restrict__ gv16, int* __restrict__ gj16)
{
  __shared__ float redv[4]; __shared__ int redi[4];
  __shared__ float outv[16]; __shared__ int outi[16];
  __shared__ float ws2[4];
  __shared__ float gvals[BATCH];
  const int t = threadIdx.x;

  if (blockIdx.x >= 1024) {
    // ---------------- gtop16 role: per-row top-16 of G[i, j<i] ----------------
    const int i = blockIdx.x - 1024;
    const int lane = t & 63, w = t >> 6;
    gvals[t] = (t < i) ? G[(size_t)i*BATCH + t] : -1e30f;
    __syncthreads();
    for (int r = 0; r < 16; ++r) {
      float bv = gvals[t]; int bj = t;
      #pragma unroll
      for (int off = 32; off; off >>= 1) {
        float ov = __shfl_xor(bv, off); int oj = __shfl_xor(bj, off);
        if (ov > bv || (ov == bv && oj < bj)) { bv = ov; bj = oj; }
      }
      if (lane == 0) { redv[w] = bv; redi[w] = bj; }
      __syncthreads();
      if (t == 0) {
        float fv = redv[0]; int fj = redi[0];
        #pragma unroll
        for (int w2 = 1; w2 < 4; ++w2)
          if (redv[w2] > fv || (redv[w2] == fv && redi[w2] < fj)) { fv = redv[w2]; fj = redi[w2]; }
        gv16[i*16 + r] = fv; gj16[i*16 + r] = fj;
        gvals[fj] = -1e30f;
      }
      __syncthreads();
    }
    return;
  }

  // ---------------- col_chunk role (round-3 proven body) ----------------
  const int ch = blockIdx.x & 3, row = blockIdx.x >> 2;
  const float* col = S0T + (size_t)row * SLOTS + ch * CHSZ;
  const int base = t * (CHSZ / 256);     // 32 contiguous per thread
  float v[16]; int ix[16];
  #pragma unroll
  for (int q = 0; q < 16; ++q) { v[q] = -1e30f; ix[q] = 0x7fffffff; }
  #pragma unroll
  for (int u = 0; u < 32; u += 4) {
    float4 x4 = *(const float4*)(col + base + u);
    float xs[4] = {x4.x, x4.y, x4.z, x4.w};
    #pragma unroll
    for (int e = 0; e < 4; ++e) {
      float cv = xs[e]; int ci = ch * CHSZ + base + u + e;
      if (cv > v[15] || (cv == v[15] && ci < ix[15])) {
        #pragma unroll
        for (int q = 0; q < 16; ++q) {
          bool better = (cv > v[q]) || (cv == v[q] && ci < ix[q]);
          float tv = better ? v[q] : cv;  // static-index swap (cndmask)
          int   ti = better ? ix[q] : ci;
          v[q]  = better ? cv : v[q];
          ix[q] = better ? ci : ix[q];
          cv = tv; ci = ti;
        }
      }
    }
  }
  for (int r = 0; r < 16; ++r) {
    float bv = v[0]; int bi = ix[0];
    #pragma unroll
    for (int off = 32; off; off >>= 1) {
      float ov = __shfl_xor(bv, off); int oi = __shfl_xor(bi, off);
      if (ov > bv || (ov == bv && oi < bi)) { bv = ov; bi = oi; }
    }
    if ((t & 63) == 0) { redv[t >> 6] = bv; redi[t >> 6] = bi; }
    __syncthreads();
    float fv = redv[0]; int fi = redi[0];
    #pragma unroll
    for (int w = 1; w < 4; ++w)
      if (redv[w] > fv || (redv[w] == fv && redi[w] < fi)) { fv = redv[w]; fi = redi[w]; }
    if (t == 0) { outv[r] = fv; outi[r] = fi; }
    const bool adv = (v[0] == fv) && (ix[0] == fi);
    #pragma unroll
    for (int q = 0; q < 15; ++q) {
      v[q]  = adv ? v[q+1]  : v[q];
      ix[q] = adv ? ix[q+1] : ix[q];
    }
    v[15]  = adv ? -1e30f     : v[15];
    ix[15] = adv ? 0x7fffffff : ix[15];
    __syncthreads();
  }
  const int cidx = row * NCHUNK + ch;
  if (t < 16) { c16v[cidx*16 + t] = outv[t]; c16i[cidx*16 + t] = outi[t]; }
  const float m = outv[0];
  float s = 0.f;
  #pragma unroll
  for (int u = 0; u < 32; u += 4) {
    float4 x4 = *(const float4*)(col + base + u);
    s += __expf(x4.x - m) + __expf(x4.y - m) + __expf(x4.z - m) + __expf(x4.w - m);
  }
  #pragma unroll
  for (int off = 32; off; off >>= 1) s += __shfl_xor(s, off);
  if ((t & 63) == 0) ws2[t >> 6] = s;
  __syncthreads();
  if (t == 0) { cse[cidx] = ws2[0]+ws2[1]+ws2[2]+ws2[3]; cmax[cidx] = m; }
}

// ---------------------------------------------------------------------------
// Combine chunk stats (unchanged, round-3 proven)
// ---------------------------------------------------------------------------
__global__ __launch_bounds__(64) void col_combine(
    const float* __restrict__ cmax, const float* __restrict__ cse,
    const float* __restrict__ c16v, const int* __restrict__ c16i,
    float* __restrict__ m_base, float* __restrict__ se_base,
    float* __restrict__ t16v, int* __restrict__ t16i)
{
  const int i = blockIdx.x, lane = threadIdx.x;
  float v = c16v[(size_t)i * 64 + lane];
  int   id = c16i[(size_t)i * 64 + lane];
  float m0 = cmax[i*4+0], m1 = cmax[i*4+1], m2 = cmax[i*4+2], m3 = cmax[i*4+3];
  const float m = fmaxf(fmaxf(m0, m1), fmaxf(m2, m3));
  const float se = cse[i*4+0]*__expf(m0-m) + cse[i*4+1]*__expf(m1-m)
                 + cse[i*4+2]*__expf(m2-m) + cse[i*4+3]*__expf(m3-m);
  bool dead = false;
  for (int r = 0; r < 16; ++r) {
    float bv = dead ? -1e30f : v;
    int   bi = dead ? 0x7fffffff : id;
    #pragma unroll
    for (int off = 32; off; off >>= 1) {
      float ov = __shfl_xor(bv, off); int oi = __shfl_xor(bi, off);
      if (ov > bv || (ov == bv && oi < bi)) { bv = ov; bi = oi; }
    }
    if (!dead && v == bv && id == bi) dead = true;
    if (lane == 0) { t16v[i*16 + r] = bv; t16i[i*16 + r] = bi; }
  }
  if (lane == 0) { m_base[i] = m; se_base[i] = se; }
}

// ---------------------------------------------------------------------------
// FUSED: sequential slot assignment (block 0) + split-K NN exp-GEMM
// (blocks 1..256). Unchanged from round 3 (proven, 163 us).
// ---------------------------------------------------------------------------
#define EXP_SCALE 16384.0f
#define KCHUNK 1024
__global__ __launch_bounds__(256) void seq_plus_gemm(
    const float* __restrict__ S0T, const float* __restrict__ G,
    const float* __restrict__ t16v, const int* __restrict__ t16i,
    const float* __restrict__ gv16, const int* __restrict__ gj16,
    int* __restrict__ slots,
    const float* __restrict__ B, const float* __restrict__ mArr,
    float* __restrict__ part)
{
  __shared__ __align__(16) unsigned char smem[70656];

  if (blockIdx.x == 0) {
    // ======================= sequential phase =======================
    unsigned int* bitmap = (unsigned int*)smem;            //  4096 B
    float* sv       = (float*)(smem + 4096);               // 16384 B
    int*   si       = (int*)  (smem + 20480);              // 16384 B
    float* gv       = (float*)(smem + 36864);              // 16384 B
    int*   gj       = (int*)  (smem + 53248);              // 16384 B
    int*   slots_sh = (int*)  (smem + 69632);              //  1024 B
    volatile unsigned int* vbm = bitmap;
    const int tt = threadIdx.x;
    for (int q = tt; q < SLOTS/32; q += 256) bitmap[q] = 0u;
    for (int q = tt; q < BATCH*16; q += 256) {
      sv[q] = t16v[q]; si[q] = t16i[q]; gv[q] = gv16[q]; gj[q] = gj16[q];
    }
    __syncthreads();
    if (tt < 64) {
      const int lane = tt;
      unsigned long long alive[4] = {0ull,0ull,0ull,0ull};
      int slotr0 = -1, slotr1 = -1, slotr2 = -1, slotr3 = -1;

      for (int i = 0; i < BATCH; ++i) {
        float myv = -1e30f; int myslot = 0; bool bvalid = false;
        if (lane < 16) {
          myv = sv[i*16 + lane]; myslot = si[i*16 + lane];
          bvalid = (((vbm[myslot >> 5] >> (myslot & 31)) & 1u) == 0u);
        }
        unsigned long long bb = __ballot(bvalid);
        float ov = -1e30f; int oj = 0; bool ovalid = false;
        if (lane < 16) {
          ov = gv[i*16 + lane]; oj = gj[i*16 + lane];
          unsigned long long am = (oj < 64) ? alive[0] : (oj < 128) ? alive[1]
                                 : (oj < 192) ? alive[2] : alive[3];
          ovalid = (ov > -1e29f) && (((am >> (oj & 63)) & 1ull) != 0ull);
        }
        unsigned long long ob = __ballot(ovalid);

        float bval; int bslot;
        if (bb != 0ull) {
          int bl = __ffsll((unsigned long long)bb) - 1;
          bval = __shfl(myv, bl); bslot = __shfl(myslot, bl);
        } else {
          float fv = -1e30f; int fi = 0x7fffffff;
          for (int s = lane; s < SLOTS; s += 64) {
            if (((vbm[s >> 5] >> (s & 31)) & 1u) == 0u) {
              float x = S0T[(size_t)i*SLOTS + s];
              if (x > fv || (x == fv && s < fi)) { fv = x; fi = s; }
            }
          }
          #pragma unroll
          for (int off = 32; off; off >>= 1) {
            float ovv = __shfl_xor(fv, off); int oii = __shfl_xor(fi, off);
            if (ovv > fv || (ovv == fv && oii < fi)) { fv = ovv; fi = oii; }
          }
          bval = fv; bslot = fi;
        }

        float oval = -1e30f; int oslot = 0x7fffffff;
        if (ob != 0ull) {
          int ol = __ffsll((unsigned long long)ob) - 1;
          oval = __shfl(ov, ol);
          int ojw = __shfl(oj, ol);
          int r = ojw >> 6;
          int srg = (r == 0) ? slotr0 : (r == 1) ? slotr1 : (r == 2) ? slotr2 : slotr3;
          oslot = __shfl(srg, ojw & 63);
        } else if ((alive[0] | alive[1] | alive[2] | alive[3]) != 0ull) {
          float fv = -1e30f; int fj = 0x7fffffff;
          #pragma unroll
          for (int r = 0; r < 4; ++r) {
            int j = lane + 64*r;
            if (j < i && ((alive[r] >> lane) & 1ull)) {
              float x = G[(size_t)i*BATCH + j];
              if (x > fv || (x == fv && j < fj)) { fv = x; fj = j; }
            }
          }
          #pragma unroll
          for (int off = 32; off; off >>= 1) {
            float ovv = __shfl_xor(fv, off); int ojj = __shfl_xor(fj, off);
            if (ovv > fv || (ovv == fv && ojj < fj)) { fv = ovv; fj = ojj; }
          }
          if (fj != 0x7fffffff) {
            oval = fv;
            int r = fj >> 6;
            int srg = (r == 0) ? slotr0 : (r == 1) ? slotr1 : (r == 2) ? slotr2 : slotr3;
            oslot = __shfl(srg, fj & 63);
          }
        }

        const bool owins = (oval > bval) || (oval == bval && oslot < bslot);
        const int sloti = owins ? oslot : bslot;

        unsigned long long kb0 = __ballot(slotr0 == sloti);
        unsigned long long kb1 = __ballot(slotr1 == sloti);
        unsigned long long kb2 = __ballot(slotr2 == sloti);
        unsigned long long kb3 = __ballot(slotr3 == sloti);
        alive[0] &= ~kb0; alive[1] &= ~kb1; alive[2] &= ~kb2; alive[3] &= ~kb3;
        const int r_new = i >> 6;
        if (lane == (i & 63)) {
          if (r_new == 0) slotr0 = sloti;
          else if (r_new == 1) slotr1 = sloti;
          else if (r_new == 2) slotr2 = sloti;
          else slotr3 = sloti;
        }
        alive[r_new] |= (1ull << (i & 63));
        if (lane == 0) {
          slots_sh[i] = sloti;
          vbm[sloti >> 5] = vbm[sloti >> 5] | (1u << (sloti & 31));
        }
        __builtin_amdgcn_wave_barrier();
      }
      for (int q = lane; q < BATCH; q += 64) slots[q] = slots_sh[q];
    }
    return;
  }

  // ======================= exp-GEMM phase (blocks 1..256) =======================
  unsigned short* sAhi = (unsigned short*)smem;            // 10240 B
  unsigned short* sAlo = (unsigned short*)(smem + 10240);  // 10240 B
  unsigned short* sBhi = (unsigned short*)(smem + 20480);  //  8704 B
  unsigned short* sBlo = (unsigned short*)(smem + 29184);  //  8704 B -> 37888

  const int b  = blockIdx.x - 1;           // 0..255
  const int bx = b >> 7;                   // 0..1   (M tiles)
  const int by = (b >> 5) & 3;             // 0..3   (N tiles)
  const int bz = b & 31;                   // 0..31  (K chunks)
  const int m0 = bx * 128, n0 = by * 128;
  const int kb = bz * KCHUNK;
  const int t = threadIdx.x;
  const int wave = t >> 6, lane = t & 63;
  const int wr = (wave >> 1) * 64, wc = (wave & 1) * 64;
  const int lrow = lane & 15, quad = lane >> 4;
  const int sr = t >> 1;           // A staging row (0..127), 2 threads/row
  const int sc = (t & 1) * 16;     // A staging k-offset
  const int pr = t >> 4;           // B k-pair row (0..15) -> k rows 2pr,2pr+1
  const int nbase = (t & 15) * 8;  // B n-offset (0..120)
  const float mrow = mArr[m0 + sr];

  f32x4 acc[4][4];
  #pragma unroll
  for (int a = 0; a < 4; ++a)
    #pragma unroll
    for (int c = 0; c < 4; ++c)
      acc[a][c] = (f32x4){0.f, 0.f, 0.f, 0.f};

  for (int k0 = kb; k0 < kb + KCHUNK; k0 += 32) {
    const float* ap = S0T + (size_t)(m0 + sr) * SLOTS + k0 + sc;
    float4 a0 = *(const float4*)(ap);
    float4 a1 = *(const float4*)(ap + 4);
    float4 a2 = *(const float4*)(ap + 8);
    float4 a3 = *(const float4*)(ap + 12);
    const float* bp = B + (size_t)(k0 + 2*pr) * DIM + n0 + nbase;
    float4 q0 = *(const float4*)(bp);
    float4 q1 = *(const float4*)(bp + 4);
    float4 q2 = *(const float4*)(bp + DIM);
    float4 q3 = *(const float4*)(bp + DIM + 4);

    float ax[16] = {a0.x,a0.y,a0.z,a0.w, a1.x,a1.y,a1.z,a1.w,
                    a2.x,a2.y,a2.z,a2.w, a3.x,a3.y,a3.z,a3.w};
    unsigned short ah[16], av[16];
    #pragma unroll
    for (int e = 0; e < 16; ++e) {
      float rm; float ee = __expf(ax[e] - mrow) * EXP_SCALE;
      ah[e] = h_split(ee, rm); av[e] = h_rne(rm);
    }
    float r0[8] = {q0.x,q0.y,q0.z,q0.w, q1.x,q1.y,q1.z,q1.w};
    float r1[8] = {q2.x,q2.y,q2.z,q2.w, q3.x,q3.y,q3.z,q3.w};
    unsigned int pbh[8], pbl[8];
    #pragma unroll
    for (int e = 0; e < 8; ++e) {
      float rm0, rm1;
      unsigned short h0 = h_split(r0[e], rm0);
      unsigned short h1 = h_split(r1[e], rm1);
      pbh[e] = pack2(h0, h1);
      pbl[e] = pack2(h_rne(rm0), h_rne(rm1));
    }

    __syncthreads();
    *(uint4*)&sAhi[sr*LSTR + sc] =
        make_uint4(pack2(ah[0],ah[1]), pack2(ah[2],ah[3]),
                   pack2(ah[4],ah[5]), pack2(ah[6],ah[7]));
    *(uint4*)&sAhi[sr*LSTR + sc + 8] =
        make_uint4(pack2(ah[8],ah[9]), pack2(ah[10],ah[11]),
                   pack2(ah[12],ah[13]), pack2(ah[14],ah[15]));
    *(uint4*)&sAlo[sr*LSTR + sc] =
        make_uint4(pack2(av[0],av[1]), pack2(av[2],av[3]),
                   pack2(av[4],av[5]), pack2(av[6],av[7]));
    *(uint4*)&sAlo[sr*LSTR + sc + 8] =
        make_uint4(pack2(av[8],av[9]), pack2(av[10],av[11]),
                   pack2(av[12],av[13]), pack2(av[14],av[15]));
    {
      unsigned int* bh32 = (unsigned int*)sBhi;
      unsigned int* bl32 = (unsigned int*)sBlo;
      #pragma unroll
      for (int e = 0; e < 8; ++e) bh32[(nbase + e)*17 + pr] = pbh[e];
      #pragma unroll
      for (int e = 0; e < 8; ++e) bl32[(nbase + e)*17 + pr] = pbl[e];
    }
    __syncthreads();

    half8 afh[4], afl[4], bfh[4], bfl[4];
    #pragma unroll
    for (int mt = 0; mt < 4; ++mt) {
      const int ar = wr + mt*16 + lrow;
      afh[mt] = *(const half8*)&sAhi[ar*LSTR + quad*8];
      afl[mt] = *(const half8*)&sAlo[ar*LSTR + quad*8];
    }
    #pragma unroll
    for (int nt = 0; nt < 4; ++nt) {
      const int br = wc + nt*16 + lrow;
      const unsigned int* ph = (const unsigned int*)sBhi + br*17 + quad*4;
      const unsigned int* pl = (const unsigned int*)sBlo + br*17 + quad*4;
      union FU { unsigned int u[4]; half8 s; };
      FU th, tl;
      th.u[0] = ph[0]; th.u[1] = ph[1]; th.u[2] = ph[2]; th.u[3] = ph[3];
      tl.u[0] = pl[0]; tl.u[1] = pl[1]; tl.u[2] = pl[2]; tl.u[3] = pl[3];
      bfh[nt] = th.s; bfl[nt] = tl.s;
    }
    #pragma unroll
    for (int mt = 0; mt < 4; ++mt)
      #pragma unroll
      for (int nt = 0; nt < 4; ++nt) {
        acc[mt][nt] = __builtin_amdgcn_mfma_f32_16x16x32_f16(afh[mt], bfh[nt], acc[mt][nt], 0, 0, 0);
        acc[mt][nt] = __builtin_amdgcn_mfma_f32_16x16x32_f16(afl[mt], bfh[nt], acc[mt][nt], 0, 0, 0);
        acc[mt][nt] = __builtin_amdgcn_mfma_f32_16x16x32_f16(afh[mt], bfl[nt], acc[mt][nt], 0, 0, 0);
      }
  }
  float* Cz = part + (size_t)bz * BATCH * DIM;
  #pragma unroll
  for (int mt = 0; mt < 4; ++mt)
    #pragma unroll
    for (int nt = 0; nt < 4; ++nt)
      #pragma unroll
      for (int reg = 0; reg < 4; ++reg) {
        const int m = m0 + wr + mt*16 + quad*4 + reg;
        const int n = n0 + wc + nt*16 + lrow;
        Cz[(size_t)m * DIM + n] = acc[mt][nt][reg];
      }
}

// ---------------------------------------------------------------------------
// coef with INLINED nxt: each block recomputes nxt[j] from slots via an LDS
// scan (~256 iters, trivial) — removes the pathological 1-block nxt_kernel.
// ---------------------------------------------------------------------------
__global__ __launch_bounds__(256) void coef_nxt(
    const float* __restrict__ S0T, const float* __restrict__ G,
    const int* __restrict__ slots,
    const float* __restrict__ m_base, const float* __restrict__ se_base,
    float* __restrict__ mOut, float* __restrict__ Zout,
    float* __restrict__ Cadd, float* __restrict__ Csub)
{
  const int i = blockIdx.x, j = threadIdx.x;
  __shared__ int sh[BATCH];
  sh[j] = slots[j];
  __syncthreads();
  const int sj = sh[j];
  int nj = 0x7fffffff;
  for (int k = j + 1; k < BATCH; ++k)
    if (sh[k] == sj) { nj = k; break; }

  const bool alive = (j < i) && (nj >= i);
  const float g = alive ? G[(size_t)i*BATCH + j] : -1e30f;
  float bv = g;
  #pragma unroll
  for (int off = 32; off; off >>= 1) bv = fmaxf(bv, __shfl_xor(bv, off));
  __shared__ float red[4];
  if ((j & 63) == 0) red[j >> 6] = bv;
  __syncthreads();
  const float mb = m_base[i];
  const float mi = fmaxf(fmaxf(fmaxf(red[0], red[1]), fmaxf(red[2], red[3])), mb);
  const float sv = alive ? S0T[(size_t)i*SLOTS + sj] : 0.f;
  const float ca = alive ? __expf(g - mi) : 0.f;
  const float cs = alive ? __expf(sv - mi) : 0.f;
  Cadd[(size_t)i*BATCH + j] = ca;
  Csub[(size_t)i*BATCH + j] = cs;
  float z = ca - cs;
  #pragma unroll
  for (int off = 32; off; off >>= 1) z += __shfl_xor(z, off);
  __syncthreads();
  if ((j & 63) == 0) red[j >> 6] = z;
  __syncthreads();
  if (j == 0) {
    mOut[i] = mi;
    Zout[i] = se_base[i] * __expf(mb - mi) + red[0] + red[1] + red[2] + red[3];
  }
}

// ---------------------------------------------------------------------------
// readval_merge with INLINED split-K reduction (removes ksum + read_num
// round-trip): acc = (sum_z part_z) * exp(m_base - mOut) / EXP_SCALE, then
// the write-interaction corrections, then /Z and merge.
// ---------------------------------------------------------------------------
__global__ __launch_bounds__(256) void readval_merge_ks(
    const float* __restrict__ part, const float* __restrict__ Cadd,
    const float* __restrict__ Csub, const float* __restrict__ WVp,
    const float* __restrict__ mem_vals, const int* __restrict__ slots,
    const float* __restrict__ Zarr, const float* __restrict__ S_t,
    const float* __restrict__ m_base, const float* __restrict__ mOut,
    float* __restrict__ merged)
{
  const int i = blockIdx.x;
  const int t = threadIdx.x;
  merged[(size_t)i*1024 + t]        = S_t[(size_t)i*DIM + t];
  merged[(size_t)i*1024 + 256 + t]  = S_t[(size_t)i*DIM + 256 + t];
  float acc0 = 0.f, acc1 = 0.f;
  #pragma unroll 4
  for (int z = 0; z < 32; ++z) {
    acc0 += part[(size_t)z * (BATCH*DIM) + (size_t)i*DIM + t];
    acc1 += part[(size_t)z * (BATCH*DIM) + (size_t)i*DIM + 256 + t];
  }
  const float rs = __expf(m_base[i] - mOut[i]) * (1.0f / EXP_SCALE);
  acc0 *= rs; acc1 *= rs;
  for (int j = 0; j < BATCH; ++j) {
    float caj = Cadd[(size_t)i*BATCH + j];
    float csj = Csub[(size_t)i*BATCH + j];
    if (caj != 0.f || csj != 0.f) {
      int sj = slots[j];
      acc0 += caj * WVp[(size_t)j*DIM + t]       - csj * mem_vals[(size_t)sj*DIM + t];
      acc1 += caj * WVp[(size_t)j*DIM + 256 + t] - csj * mem_vals[(size_t)sj*DIM + 256 + t];
    }
  }
  const float invZ = 1.0f / Zarr[i];
  merged[(size_t)i*1024 + 512 + t] = acc0 * invZ;
  merged[(size_t)i*1024 + 768 + t] = acc1 * invZ;
}

// ---------------------------------------------------------------------------
extern "C" void kernel_launch(void* const* d_in, const int* in_sizes, int n_in,
                              void* d_out, int out_size, void* d_ws, size_t ws_size,
                              hipStream_t stream)
{
  (void)in_sizes; (void)n_in; (void)out_size; (void)ws_size;
  const float* S_t      = (const float*)d_in[0];
  const float* mem_keys = (const float*)d_in[1];
  const float* mem_vals = (const float*)d_in[2];
  const float* Wk       = (const float*)d_in[3];
  const float* bk       = (const float*)d_in[4];
  const float* Wv       = (const float*)d_in[5];
  const float* bv       = (const float*)d_in[6];
  const float* W1       = (const float*)d_in[7];
  const float* b1       = (const float*)d_in[8];
  const float* W2       = (const float*)d_in[9];
  const float* b2       = (const float*)d_in[10];
  float* out = (float*)d_out;

  // Workspace layout — round-3-proven footprint (read_num/nxt slots unused).
  float* ws = (float*)d_ws;
  float* Kp       = ws + 0;         // [256,512]
  float* WVp      = ws + 131072;    // [256,512]
  float* G        = ws + 262144;    // [256,256]
  float* S0T      = ws + 327680;    // [256,32768]
  float* m_base   = ws + 8716288;   // [256]
  float* se_base  = ws + 8716544;   // [256]
  float* t16v     = ws + 8716800;   // [256,16]
  int*   t16i     = (int*)(ws + 8720896);
  float* gv16     = ws + 8724992;   // [256,16]
  int*   gj16     = (int*)(ws + 8729088);
  int*   slots    = (int*)(ws + 8733184);
  float* mOut     = ws + 8733696;
  float* Zout     = ws + 8733952;
  float* Cadd     = ws + 8734208;   // [256,256]
  float* Csub     = ws + 8799744;   // [256,256]
  float* merged   = ws + 8996352;   // [256,1024]
  float* hid      = ws + 9258496;   // [256,2048] ends 9782784
  float* part     = ws + 9782784;   // [32][256,512] ends 13977088
  // col_chunk scratch aliased onto head of part:
  float* cmaxb    = ws + 9782784;   // [256,4]
  float* cseb     = ws + 9783808;   // [256,4]
  float* c16vb    = ws + 9784832;   // [256,4,16]
  int*   c16ib    = (int*)(ws + 9801216);  // [256,4,16] ends 9817600 < 13977088
  unsigned short* Khi = (unsigned short*)(ws + 13977088);  // [256,512] bf16
  unsigned short* Klo = (unsigned short*)(ws + 14042624);  // [256,512] bf16, ends 14108160

  // phase 1: Wk/Wv projections fused; then convert; then gram+scores fused
  proj2<<<dim3(64), dim3(256), 0, stream>>>(S_t, Wk, bk, Kp, Wv, bv, WVp);
  convert_hilo<<<dim3(128), dim3(256), 0, stream>>>(Kp, Khi, Klo, 131072);
  gram_scores<<<dim3(528), dim3(256), 0, stream>>>(Kp, G, Khi, Klo, mem_keys, S0T);

  // phase 2: col stats + G top-16 fused; combine
  colchunk_gtop<<<dim3(1280), dim3(256), 0, stream>>>(S0T, cmaxb, cseb, c16vb, c16ib,
                                                      G, gv16, gj16);
  col_combine<<<dim3(256), dim3(64), 0, stream>>>(cmaxb, cseb, c16vb, c16ib,
                                                  m_base, se_base, t16v, t16i);

  // phase 2.5: FUSED sequential phase (block 0) + read exp-GEMM (blocks 1..256)
  seq_plus_gemm<<<dim3(257), dim3(256), 0, stream>>>(S0T, G, t16v, t16i, gv16, gj16,
                                                     slots, mem_vals, m_base, part);

  // phase 3: coefficients (nxt inlined) + merge (ksum inlined)
  coef_nxt<<<dim3(256), dim3(256), 0, stream>>>(S0T, G, slots, m_base, se_base,
                                                mOut, Zout, Cadd, Csub);
  readval_merge_ks<<<dim3(256), dim3(256), 0, stream>>>(part, Cadd, Csub, WVp,
                                                        mem_vals, slots, Zout, S_t,
                                                        m_base, mOut, merged);

  // phase 4: MLP (round-3-proven fp32 64x64 tiles)
  gemm_bt<<<dim3(4, 32), dim3(256), 0, stream>>>(merged, W1, b1, hid, 256, 2048, 1024, 1);
  gemm_bt<<<dim3(4, 8),  dim3(256), 0, stream>>>(hid,    W2, b2, out, 256, 512,  2048, 0);
}

// Round 6
// 755.976 us; speedup vs baseline: 1.1538x; 1.0503x over previous
//
#include <hip/hip_runtime.h>
#include <cstdint>
#include <cstddef>

#define BATCH 256
#define DIM   512
#define HIDN  2048
#define SLOTS 32768
#define NCHUNK 4
#define CHSZ  (SLOTS/NCHUNK)    // 8192

typedef __attribute__((ext_vector_type(8))) short short8;
typedef __attribute__((ext_vector_type(8))) _Float16 half8;
typedef __attribute__((ext_vector_type(4))) float f32x4;

// ---------------------------------------------------------------------------
// bf16 split helpers (RNE) — score GEMM path (proven at K=512)
// ---------------------------------------------------------------------------
__device__ __forceinline__ unsigned short bf_rne(float x) {
  unsigned int u = __float_as_uint(x);
  unsigned int r = (u + 0x7fffu + ((u >> 16) & 1u)) >> 16;
  return (unsigned short)r;
}
__device__ __forceinline__ unsigned short bf_split(float x, float& rem) {
  unsigned short h = bf_rne(x);
  rem = x - __uint_as_float(((unsigned int)h) << 16);
  return h;
}
__device__ __forceinline__ unsigned int pack2(unsigned short a, unsigned short b) {
  return (unsigned int)a | ((unsigned int)b << 16);
}

// ---------------------------------------------------------------------------
// fp16 split helpers (RNE) — read exp-GEMM path (proven at K=32768)
// ---------------------------------------------------------------------------
__device__ __forceinline__ unsigned short h_rne(float x) {
  _Float16 h = (_Float16)x;
  union { _Float16 f; unsigned short u; } cv; cv.f = h;
  return cv.u;
}
__device__ __forceinline__ unsigned short h_split(float x, float& rem) {
  _Float16 h = (_Float16)x;
  rem = x - (float)h;
  union { _Float16 f; unsigned short u; } cv; cv.f = h;
  return cv.u;
}

// ---------------------------------------------------------------------------
// 64x64 fp32 VALU GEMM tile body: C = act(addC?C:0 + A @ B^T + bias). TK=16.
// Generalized with lda/ldb/ldc for strided views (W1 column halves) and an
// optional bf16 hi/lo epilogue (fuses convert_hilo into the Kp projection).
// ---------------------------------------------------------------------------
__device__ __forceinline__ void gemm64_body(
    const float* __restrict__ A, int lda, const float* __restrict__ B, int ldb,
    const float* __restrict__ bias, float* __restrict__ C, int ldc,
    int K, int relu, int addC,
    unsigned short* __restrict__ hi, unsigned short* __restrict__ lo,
    int bx, int by, int t, float (*As)[68], float (*Bs)[68])
{
  const int m0 = bx * 64;
  const int n0 = by * 64;
  const int tx = t & 15, ty = t >> 4;
  const int lr = t >> 2;
  const int lc = (t & 3) * 4;
  float acc[4][4] = {};
  for (int k0 = 0; k0 < K; k0 += 16) {
    float4 a = *(const float4*)(A + (size_t)(m0 + lr) * lda + k0 + lc);
    float4 b = *(const float4*)(B + (size_t)(n0 + lr) * ldb + k0 + lc);
    __syncthreads();
    As[lc+0][lr] = a.x; As[lc+1][lr] = a.y; As[lc+2][lr] = a.z; As[lc+3][lr] = a.w;
    Bs[lc+0][lr] = b.x; Bs[lc+1][lr] = b.y; Bs[lc+2][lr] = b.z; Bs[lc+3][lr] = b.w;
    __syncthreads();
    #pragma unroll
    for (int k = 0; k < 16; ++k) {
      const float4 a4 = *(const float4*)&As[k][ty*4];
      const float4 b4 = *(const float4*)&Bs[k][tx*4];
      const float aa[4] = {a4.x, a4.y, a4.z, a4.w};
      const float bb[4] = {b4.x, b4.y, b4.z, b4.w};
      #pragma unroll
      for (int u = 0; u < 4; ++u)
        #pragma unroll
        for (int v = 0; v < 4; ++v)
          acc[u][v] = fmaf(aa[u], bb[v], acc[u][v]);
    }
  }
  #pragma unroll
  for (int u = 0; u < 4; ++u) {
    const int m = m0 + ty*4 + u;
    float o[4];
    #pragma unroll
    for (int v = 0; v < 4; ++v) {
      float c = acc[u][v];
      if (addC) c += C[(size_t)m * ldc + n0 + tx*4 + v];
      if (bias) c += bias[n0 + tx*4 + v];
      if (relu) c = fmaxf(c, 0.0f);
      o[v] = c;
    }
    *(float4*)(C + (size_t)m * ldc + n0 + tx*4) = make_float4(o[0], o[1], o[2], o[3]);
    if (hi) {
      float r0, r1, r2, r3;
      unsigned short h0 = bf_split(o[0], r0), h1 = bf_split(o[1], r1);
      unsigned short h2 = bf_split(o[2], r2), h3 = bf_split(o[3], r3);
      *(uint2*)(hi + (size_t)m * ldc + n0 + tx*4) =
          make_uint2(pack2(h0, h1), pack2(h2, h3));
      *(uint2*)(lo + (size_t)m * ldc + n0 + tx*4) =
          make_uint2(pack2(bf_rne(r0), bf_rne(r1)), pack2(bf_rne(r2), bf_rne(r3)));
    }
  }
}

// standalone GEMM (MLP W1b/W2)
__global__ __launch_bounds__(256) void gemm_bt(
    const float* __restrict__ A, int lda, const float* __restrict__ B, int ldb,
    const float* __restrict__ bias, float* __restrict__ C, int ldc,
    int K, int relu, int addC)
{
  __shared__ __align__(16) float As[16][68];
  __shared__ __align__(16) float Bs[16][68];
  gemm64_body(A, lda, B, ldb, bias, C, ldc, K, relu, addC, nullptr, nullptr,
              blockIdx.x, blockIdx.y, threadIdx.x, As, Bs);
}

// FUSED: Wk-projection with bf16 hi/lo epilogue (blocks 0..31) +
// Wv-projection (blocks 32..63). Removes the convert_hilo dispatch.
__global__ __launch_bounds__(256) void proj2(
    const float* __restrict__ S_t,
    const float* __restrict__ Wk, const float* __restrict__ bk, float* __restrict__ Kp,
    unsigned short* __restrict__ Khi, unsigned short* __restrict__ Klo,
    const float* __restrict__ Wv, const float* __restrict__ bv, float* __restrict__ WVp)
{
  __shared__ __align__(16) float As[16][68];
  __shared__ __align__(16) float Bs[16][68];
  int b = blockIdx.x;
  if (b < 32)
    gemm64_body(S_t, 512, Wk, 512, bk, Kp, 512, 512, 0, 0, Khi, Klo,
                b & 3, b >> 2, threadIdx.x, As, Bs);
  else {
    b -= 32;
    gemm64_body(S_t, 512, Wv, 512, bv, WVp, 512, 512, 0, 0, nullptr, nullptr,
                b & 3, b >> 2, threadIdx.x, As, Bs);
  }
}

// ---------------------------------------------------------------------------
// bf16 hi/lo MFMA BT-GEMM body (scores; round-3 proven at K=512)
// ---------------------------------------------------------------------------
#define LSTR 40
__device__ __forceinline__ void mfma_scores_body(
    const unsigned short* __restrict__ Ahi, const unsigned short* __restrict__ Alo,
    const float* __restrict__ B, float* __restrict__ C, int M, int N, int K,
    int bx, int by, int t,
    unsigned short* sAhi, unsigned short* sAlo,
    unsigned short* sBhi, unsigned short* sBlo)
{
  const int m0 = bx * 128, n0 = by * 128;
  const int wave = t >> 6, lane = t & 63;
  const int wr = (wave >> 1) * 64, wc = (wave & 1) * 64;
  const int lrow = lane & 15, quad = lane >> 4;
  const int sr = t >> 1;
  const int sc = (t & 1) * 16;

  f32x4 acc[4][4];
  #pragma unroll
  for (int a = 0; a < 4; ++a)
    #pragma unroll
    for (int b = 0; b < 4; ++b)
      acc[a][b] = (f32x4){0.f, 0.f, 0.f, 0.f};

  for (int k0 = 0; k0 < K; k0 += 32) {
    const size_t aoff = (size_t)(m0 + sr) * K + k0 + sc;
    uint4 ah0 = *(const uint4*)(Ahi + aoff);
    uint4 ah1 = *(const uint4*)(Ahi + aoff + 8);
    uint4 al0 = *(const uint4*)(Alo + aoff);
    uint4 al1 = *(const uint4*)(Alo + aoff + 8);
    const float* bp = B + (size_t)(n0 + sr) * K + k0 + sc;
    float4 b0 = *(const float4*)(bp + 0);
    float4 b1 = *(const float4*)(bp + 4);
    float4 b2 = *(const float4*)(bp + 8);
    float4 b3 = *(const float4*)(bp + 12);
    float bx_[16] = {b0.x,b0.y,b0.z,b0.w, b1.x,b1.y,b1.z,b1.w,
                     b2.x,b2.y,b2.z,b2.w, b3.x,b3.y,b3.z,b3.w};
    unsigned short bh[16], bl[16];
    #pragma unroll
    for (int e = 0; e < 16; ++e) {
      float rem; bh[e] = bf_split(bx_[e], rem); bl[e] = bf_rne(rem);
    }
    __syncthreads();
    *(uint4*)&sAhi[sr*LSTR + sc]     = ah0;
    *(uint4*)&sAhi[sr*LSTR + sc + 8] = ah1;
    *(uint4*)&sAlo[sr*LSTR + sc]     = al0;
    *(uint4*)&sAlo[sr*LSTR + sc + 8] = al1;
    *(uint4*)&sBhi[sr*LSTR + sc] =
        make_uint4(pack2(bh[0],bh[1]), pack2(bh[2],bh[3]),
                   pack2(bh[4],bh[5]), pack2(bh[6],bh[7]));
    *(uint4*)&sBhi[sr*LSTR + sc + 8] =
        make_uint4(pack2(bh[8],bh[9]), pack2(bh[10],bh[11]),
                   pack2(bh[12],bh[13]), pack2(bh[14],bh[15]));
    *(uint4*)&sBlo[sr*LSTR + sc] =
        make_uint4(pack2(bl[0],bl[1]), pack2(bl[2],bl[3]),
                   pack2(bl[4],bl[5]), pack2(bl[6],bl[7]));
    *(uint4*)&sBlo[sr*LSTR + sc + 8] =
        make_uint4(pack2(bl[8],bl[9]), pack2(bl[10],bl[11]),
                   pack2(bl[12],bl[13]), pack2(bl[14],bl[15]));
    __syncthreads();

    short8 afh[4], afl[4], bfh[4], bfl[4];
    #pragma unroll
    for (int mt = 0; mt < 4; ++mt) {
      const int ar = wr + mt*16 + lrow;
      afh[mt] = *(const short8*)&sAhi[ar*LSTR + quad*8];
      afl[mt] = *(const short8*)&sAlo[ar*LSTR + quad*8];
    }
    #pragma unroll
    for (int nt = 0; nt < 4; ++nt) {
      const int br = wc + nt*16 + lrow;
      bfh[nt] = *(const short8*)&sBhi[br*LSTR + quad*8];
      bfl[nt] = *(const short8*)&sBlo[br*LSTR + quad*8];
    }
    #pragma unroll
    for (int mt = 0; mt < 4; ++mt)
      #pragma unroll
      for (int nt = 0; nt < 4; ++nt) {
        acc[mt][nt] = __builtin_amdgcn_mfma_f32_16x16x32_bf16(afh[mt], bfh[nt], acc[mt][nt], 0, 0, 0);
        acc[mt][nt] = __builtin_amdgcn_mfma_f32_16x16x32_bf16(afl[mt], bfh[nt], acc[mt][nt], 0, 0, 0);
        acc[mt][nt] = __builtin_amdgcn_mfma_f32_16x16x32_bf16(afh[mt], bfl[nt], acc[mt][nt], 0, 0, 0);
      }
  }
  #pragma unroll
  for (int mt = 0; mt < 4; ++mt)
    #pragma unroll
    for (int nt = 0; nt < 4; ++nt)
      #pragma unroll
      for (int reg = 0; reg < 4; ++reg) {
        const int m = m0 + wr + mt*16 + quad*4 + reg;
        const int n = n0 + wc + nt*16 + lrow;
        C[(size_t)m * N + n] = acc[mt][nt][reg];
      }
}

// FUSED: gram GEMM (blocks 0..15, fp32 64x64) + score MFMA GEMM (blocks
// 16..527, bf16-hilo 128x128). Both depend only on Kp — independent roles.
__global__ __launch_bounds__(256) void gram_scores(
    const float* __restrict__ Kp, float* __restrict__ G,
    const unsigned short* __restrict__ Khi, const unsigned short* __restrict__ Klo,
    const float* __restrict__ mem_keys, float* __restrict__ S0T)
{
  __shared__ __align__(16) unsigned char arena[40960];
  const int b = blockIdx.x;
  if (b < 16) {
    float (*As)[68] = (float (*)[68])arena;
    float (*Bs)[68] = (float (*)[68])(arena + 4352);
    gemm64_body(Kp, 512, Kp, 512, nullptr, G, 256, 512, 0, 0, nullptr, nullptr,
                b & 3, b >> 2, threadIdx.x, As, Bs);
  } else {
    const int sb = b - 16;
    unsigned short* sAhi = (unsigned short*)arena;
    unsigned short* sAlo = (unsigned short*)(arena + 10240);
    unsigned short* sBhi = (unsigned short*)(arena + 20480);
    unsigned short* sBlo = (unsigned short*)(arena + 30720);
    mfma_scores_body(Khi, Klo, mem_keys, S0T, 256, 32768, 512,
                     sb & 1, sb >> 1, threadIdx.x, sAhi, sAlo, sBhi, sBlo);
  }
}

// ---------------------------------------------------------------------------
// FUSED: col_chunk (blocks 0..1023) + gtop16 (blocks 1024..1279).
// ---------------------------------------------------------------------------
__global__ __launch_bounds__(256) void colchunk_gtop(
    const float* __restrict__ S0T, float* __restrict__ cmax,
    float* __restrict__ cse, float* __restrict__ c16v, int* __restrict__ c16i,
    const float* __restrict__ G, float* __restrict__ gv16, int* __restrict__ gj16)
{
  __shared__ float redv[4]; __shared__ int redi[4];
  __shared__ float outv[16]; __shared__ int outi[16];
  __shared__ float ws2[4];
  __shared__ float gvals[BATCH];
  const int t = threadIdx.x;

  if (blockIdx.x >= 1024) {
    const int i = blockIdx.x - 1024;
    const int lane = t & 63, w = t >> 6;
    gvals[t] = (t < i) ? G[(size_t)i*BATCH + t] : -1e30f;
    __syncthreads();
    for (int r = 0; r < 16; ++r) {
      float bv = gvals[t]; int bj = t;
      #pragma unroll
      for (int off = 32; off; off >>= 1) {
        float ov = __shfl_xor(bv, off); int oj = __shfl_xor(bj, off);
        if (ov > bv || (ov == bv && oj < bj)) { bv = ov; bj = oj; }
      }
      if (lane == 0) { redv[w] = bv; redi[w] = bj; }
      __syncthreads();
      if (t == 0) {
        float fv = redv[0]; int fj = redi[0];
        #pragma unroll
        for (int w2 = 1; w2 < 4; ++w2)
          if (redv[w2] > fv || (redv[w2] == fv && redi[w2] < fj)) { fv = redv[w2]; fj = redi[w2]; }
        gv16[i*16 + r] = fv; gj16[i*16 + r] = fj;
        gvals[fj] = -1e30f;
      }
      __syncthreads();
    }
    return;
  }

  const int ch = blockIdx.x & 3, row = blockIdx.x >> 2;
  const float* col = S0T + (size_t)row * SLOTS + ch * CHSZ;
  const int base = t * (CHSZ / 256);     // 32 contiguous per thread
  float v[16]; int ix[16];
  #pragma unroll
  for (int q = 0; q < 16; ++q) { v[q] = -1e30f; ix[q] = 0x7fffffff; }
  #pragma unroll
  for (int u = 0; u < 32; u += 4) {
    float4 x4 = *(const float4*)(col + base + u);
    float xs[4] = {x4.x, x4.y, x4.z, x4.w};
    #pragma unroll
    for (int e = 0; e < 4; ++e) {
      float cv = xs[e]; int ci = ch * CHSZ + base + u + e;
      if (cv > v[15] || (cv == v[15] && ci < ix[15])) {
        #pragma unroll
        for (int q = 0; q < 16; ++q) {
          bool better = (cv > v[q]) || (cv == v[q] && ci < ix[q]);
          float tv = better ? v[q] : cv;  // static-index swap (cndmask)
          int   ti = better ? ix[q] : ci;
          v[q]  = better ? cv : v[q];
          ix[q] = better ? ci : ix[q];
          cv = tv; ci = ti;
        }
      }
    }
  }
  for (int r = 0; r < 16; ++r) {
    float bv = v[0]; int bi = ix[0];
    #pragma unroll
    for (int off = 32; off; off >>= 1) {
      float ov = __shfl_xor(bv, off); int oi = __shfl_xor(bi, off);
      if (ov > bv || (ov == bv && oi < bi)) { bv = ov; bi = oi; }
    }
    if ((t & 63) == 0) { redv[t >> 6] = bv; redi[t >> 6] = bi; }
    __syncthreads();
    float fv = redv[0]; int fi = redi[0];
    #pragma unroll
    for (int w = 1; w < 4; ++w)
      if (redv[w] > fv || (redv[w] == fv && redi[w] < fi)) { fv = redv[w]; fi = redi[w]; }
    if (t == 0) { outv[r] = fv; outi[r] = fi; }
    const bool adv = (v[0] == fv) && (ix[0] == fi);
    #pragma unroll
    for (int q = 0; q < 15; ++q) {
      v[q]  = adv ? v[q+1]  : v[q];
      ix[q] = adv ? ix[q+1] : ix[q];
    }
    v[15]  = adv ? -1e30f     : v[15];
    ix[15] = adv ? 0x7fffffff : ix[15];
    __syncthreads();
  }
  const int cidx = row * NCHUNK + ch;
  if (t < 16) { c16v[cidx*16 + t] = outv[t]; c16i[cidx*16 + t] = outi[t]; }
  const float m = outv[0];
  float s = 0.f;
  #pragma unroll
  for (int u = 0; u < 32; u += 4) {
    float4 x4 = *(const float4*)(col + base + u);
    s += __expf(x4.x - m) + __expf(x4.y - m) + __expf(x4.z - m) + __expf(x4.w - m);
  }
  #pragma unroll
  for (int off = 32; off; off >>= 1) s += __shfl_xor(s, off);
  if ((t & 63) == 0) ws2[t >> 6] = s;
  __syncthreads();
  if (t == 0) { cse[cidx] = ws2[0]+ws2[1]+ws2[2]+ws2[3]; cmax[cidx] = m; }
}

// ---------------------------------------------------------------------------
// Combine chunk stats (unchanged, round-3 proven)
// ---------------------------------------------------------------------------
__global__ __launch_bounds__(64) void col_combine(
    const float* __restrict__ cmax, const float* __restrict__ cse,
    const float* __restrict__ c16v, const int* __restrict__ c16i,
    float* __restrict__ m_base, float* __restrict__ se_base,
    float* __restrict__ t16v, int* __restrict__ t16i)
{
  const int i = blockIdx.x, lane = threadIdx.x;
  float v = c16v[(size_t)i * 64 + lane];
  int   id = c16i[(size_t)i * 64 + lane];
  float m0 = cmax[i*4+0], m1 = cmax[i*4+1], m2 = cmax[i*4+2], m3 = cmax[i*4+3];
  const float m = fmaxf(fmaxf(m0, m1), fmaxf(m2, m3));
  const float se = cse[i*4+0]*__expf(m0-m) + cse[i*4+1]*__expf(m1-m)
                 + cse[i*4+2]*__expf(m2-m) + cse[i*4+3]*__expf(m3-m);
  bool dead = false;
  for (int r = 0; r < 16; ++r) {
    float bv = dead ? -1e30f : v;
    int   bi = dead ? 0x7fffffff : id;
    #pragma unroll
    for (int off = 32; off; off >>= 1) {
      float ov = __shfl_xor(bv, off); int oi = __shfl_xor(bi, off);
      if (ov > bv || (ov == bv && oi < bi)) { bv = ov; bi = oi; }
    }
    if (!dead && v == bv && id == bi) dead = true;
    if (lane == 0) { t16v[i*16 + r] = bv; t16i[i*16 + r] = bi; }
  }
  if (lane == 0) { m_base[i] = m; se_base[i] = se; }
}

// ---------------------------------------------------------------------------
// FUSED: sequential slot assignment (block 0, software-pipelined candidate
// prefetch) + split-K NN exp-GEMM (blocks 1..256) + hidA = S_t @ W1[:,:512]^T
// (blocks 257..384). Seq prefetch is exact: per iteration only bit `sloti`
// is newly set in the bitmap (bb-path picks clear bits; override paths re-set
// existing bits), so next-iteration validity = !prefetched_bit && slot!=prev.
// ---------------------------------------------------------------------------
#define EXP_SCALE 16384.0f
#define KCHUNK 1024
__global__ __launch_bounds__(256) void seq_plus_gemm(
    const float* __restrict__ S0T, const float* __restrict__ G,
    const float* __restrict__ t16v, const int* __restrict__ t16i,
    const float* __restrict__ gv16, const int* __restrict__ gj16,
    int* __restrict__ slots,
    const float* __restrict__ B, const float* __restrict__ mArr,
    float* __restrict__ part,
    const float* __restrict__ S_t, const float* __restrict__ W1,
    float* __restrict__ hid)
{
  __shared__ __align__(16) unsigned char smem[70656];

  if (blockIdx.x == 0) {
    // ======================= sequential phase =======================
    unsigned int* bitmap = (unsigned int*)smem;            //  4096 B
    float* sv       = (float*)(smem + 4096);               // 16384 B
    int*   si       = (int*)  (smem + 20480);              // 16384 B
    float* gv       = (float*)(smem + 36864);              // 16384 B
    int*   gj       = (int*)  (smem + 53248);              // 16384 B
    int*   slots_sh = (int*)  (smem + 69632);              //  1024 B
    volatile unsigned int* vbm = bitmap;
    const int tt = threadIdx.x;
    for (int q = tt; q < SLOTS/32; q += 256) bitmap[q] = 0u;
    for (int q = tt; q < BATCH*16; q += 256) {
      sv[q] = t16v[q]; si[q] = t16i[q]; gv[q] = gv16[q]; gj[q] = gj16[q];
    }
    __syncthreads();
    if (tt < 64) {
      const int lane = tt;
      unsigned long long alive[4] = {0ull,0ull,0ull,0ull};
      int slotr0 = -1, slotr1 = -1, slotr2 = -1, slotr3 = -1;

      // pipelined candidate state for iteration 0
      float myv = -1e30f; int myslot = 0; unsigned int wpref = 0;
      float ovq = -1e30f; int ojq = 0;
      if (lane < 16) {
        myv = sv[lane]; myslot = si[lane];
        wpref = vbm[myslot >> 5];
        ovq = gv[lane]; ojq = gj[lane];
      }
      int prev_slot = -1;

      for (int i = 0; i < BATCH; ++i) {
        bool bvalid = false, ovalid = false;
        if (lane < 16) {
          bvalid = (((wpref >> (myslot & 31)) & 1u) == 0u) && (myslot != prev_slot);
          unsigned long long am = (ojq < 64) ? alive[0] : (ojq < 128) ? alive[1]
                                 : (ojq < 192) ? alive[2] : alive[3];
          ovalid = (ovq > -1e29f) && (((am >> (ojq & 63)) & 1ull) != 0ull);
        }
        unsigned long long bb = __ballot(bvalid);
        unsigned long long ob = __ballot(ovalid);

        // prefetch next iteration's candidates (off the critical chain)
        float myv_n = -1e30f; int myslot_n = 0; unsigned int wpref_n = 0;
        float ovq_n = -1e30f; int ojq_n = 0;
        if (i + 1 < BATCH && lane < 16) {
          myv_n = sv[(i+1)*16 + lane]; myslot_n = si[(i+1)*16 + lane];
          wpref_n = vbm[myslot_n >> 5];
          ovq_n = gv[(i+1)*16 + lane]; ojq_n = gj[(i+1)*16 + lane];
        }

        float bval; int bslot;
        if (bb != 0ull) {
          int bl = __ffsll((unsigned long long)bb) - 1;
          bval = __shfl(myv, bl); bslot = __shfl(myslot, bl);
        } else {
          float fv = -1e30f; int fi = 0x7fffffff;
          for (int s = lane; s < SLOTS; s += 64) {
            if (((vbm[s >> 5] >> (s & 31)) & 1u) == 0u) {
              float x = S0T[(size_t)i*SLOTS + s];
              if (x > fv || (x == fv && s < fi)) { fv = x; fi = s; }
            }
          }
          #pragma unroll
          for (int off = 32; off; off >>= 1) {
            float ovv = __shfl_xor(fv, off); int oii = __shfl_xor(fi, off);
            if (ovv > fv || (ovv == fv && oii < fi)) { fv = ovv; fi = oii; }
          }
          bval = fv; bslot = fi;
        }

        float oval = -1e30f; int oslot = 0x7fffffff;
        if (ob != 0ull) {
          int ol = __ffsll((unsigned long long)ob) - 1;
          oval = __shfl(ovq, ol);
          int ojw = __shfl(ojq, ol);
          int r = ojw >> 6;
          int srg = (r == 0) ? slotr0 : (r == 1) ? slotr1 : (r == 2) ? slotr2 : slotr3;
          oslot = __shfl(srg, ojw & 63);
        } else if ((alive[0] | alive[1] | alive[2] | alive[3]) != 0ull) {
          float fv = -1e30f; int fj = 0x7fffffff;
          #pragma unroll
          for (int r = 0; r < 4; ++r) {
            int j = lane + 64*r;
            if (j < i && ((alive[r] >> lane) & 1ull)) {
              float x = G[(size_t)i*BATCH + j];
              if (x > fv || (x == fv && j < fj)) { fv = x; fj = j; }
            }
          }
          #pragma unroll
          for (int off = 32; off; off >>= 1) {
            float ovv = __shfl_xor(fv, off); int ojj = __shfl_xor(fj, off);
            if (ovv > fv || (ovv == fv && ojj < fj)) { fv = ovv; fj = ojj; }
          }
          if (fj != 0x7fffffff) {
            oval = fv;
            int r = fj >> 6;
            int srg = (r == 0) ? slotr0 : (r == 1) ? slotr1 : (r == 2) ? slotr2 : slotr3;
            oslot = __shfl(srg, fj & 63);
          }
        }

        const bool owins = (oval > bval) || (oval == bval && oslot < bslot);
        const int sloti = owins ? oslot : bslot;

        unsigned long long kb0 = __ballot(slotr0 == sloti);
        unsigned long long kb1 = __ballot(slotr1 == sloti);
        unsigned long long kb2 = __ballot(slotr2 == sloti);
        unsigned long long kb3 = __ballot(slotr3 == sloti);
        alive[0] &= ~kb0; alive[1] &= ~kb1; alive[2] &= ~kb2; alive[3] &= ~kb3;
        const int r_new = i >> 6;
        if (lane == (i & 63)) {
          if (r_new == 0) slotr0 = sloti;
          else if (r_new == 1) slotr1 = sloti;
          else if (r_new == 2) slotr2 = sloti;
          else slotr3 = sloti;
        }
        alive[r_new] |= (1ull << (i & 63));
        if (lane == 0) {
          slots_sh[i] = sloti;
          vbm[sloti >> 5] = vbm[sloti >> 5] | (1u << (sloti & 31));
        }
        prev_slot = sloti;
        myv = myv_n; myslot = myslot_n; wpref = wpref_n; ovq = ovq_n; ojq = ojq_n;
        __builtin_amdgcn_wave_barrier();
      }
      for (int q = lane; q < BATCH; q += 64) slots[q] = slots_sh[q];
    }
    return;
  }

  if (blockIdx.x >= 257) {
    // =================== hidA = S_t @ W1[:, :512]^T (blocks 257..384) ===================
    float (*As)[68] = (float (*)[68])smem;
    float (*Bs)[68] = (float (*)[68])(smem + 4352);
    const int b2 = blockIdx.x - 257;     // 0..127 -> 4 x 32 tiles
    gemm64_body(S_t, 512, W1, 1024, nullptr, hid, 2048, 512, 0, 0, nullptr, nullptr,
                b2 & 3, b2 >> 2, threadIdx.x, As, Bs);
    return;
  }

  // ======================= exp-GEMM phase (blocks 1..256) =======================
  unsigned short* sAhi = (unsigned short*)smem;            // 10240 B
  unsigned short* sAlo = (unsigned short*)(smem + 10240);  // 10240 B
  unsigned short* sBhi = (unsigned short*)(smem + 20480);  //  8704 B
  unsigned short* sBlo = (unsigned short*)(smem + 29184);  //  8704 B -> 37888

  const int b  = blockIdx.x - 1;           // 0..255
  const int bx = b >> 7;                   // 0..1   (M tiles)
  const int by = (b >> 5) & 3;             // 0..3   (N tiles)
  const int bz = b & 31;                   // 0..31  (K chunks)
  const int m0 = bx * 128, n0 = by * 128;
  const int kb = bz * KCHUNK;
  const int t = threadIdx.x;
  const int wave = t >> 6, lane = t & 63;
  const int wr = (wave >> 1) * 64, wc = (wave & 1) * 64;
  const int lrow = lane & 15, quad = lane >> 4;
  const int sr = t >> 1;           // A staging row (0..127), 2 threads/row
  const int sc = (t & 1) * 16;     // A staging k-offset
  const int pr = t >> 4;           // B k-pair row (0..15) -> k rows 2pr,2pr+1
  const int nbase = (t & 15) * 8;  // B n-offset (0..120)
  const float mrow = mArr[m0 + sr];

  f32x4 acc[4][4];
  #pragma unroll
  for (int a = 0; a < 4; ++a)
    #pragma unroll
    for (int c = 0; c < 4; ++c)
      acc[a][c] = (f32x4){0.f, 0.f, 0.f, 0.f};

  for (int k0 = kb; k0 < kb + KCHUNK; k0 += 32) {
    const float* ap = S0T + (size_t)(m0 + sr) * SLOTS + k0 + sc;
    float4 a0 = *(const float4*)(ap);
    float4 a1 = *(const float4*)(ap + 4);
    float4 a2 = *(const float4*)(ap + 8);
    float4 a3 = *(const float4*)(ap + 12);
    const float* bp = B + (size_t)(k0 + 2*pr) * DIM + n0 + nbase;
    float4 q0 = *(const float4*)(bp);
    float4 q1 = *(const float4*)(bp + 4);
    float4 q2 = *(const float4*)(bp + DIM);
    float4 q3 = *(const float4*)(bp + DIM + 4);

    float ax[16] = {a0.x,a0.y,a0.z,a0.w, a1.x,a1.y,a1.z,a1.w,
                    a2.x,a2.y,a2.z,a2.w, a3.x,a3.y,a3.z,a3.w};
    unsigned short ah[16], av[16];
    #pragma unroll
    for (int e = 0; e < 16; ++e) {
      float rm; float ee = __expf(ax[e] - mrow) * EXP_SCALE;
      ah[e] = h_split(ee, rm); av[e] = h_rne(rm);
    }
    float r0[8] = {q0.x,q0.y,q0.z,q0.w, q1.x,q1.y,q1.z,q1.w};
    float r1[8] = {q2.x,q2.y,q2.z,q2.w, q3.x,q3.y,q3.z,q3.w};
    unsigned int pbh[8], pbl[8];
    #pragma unroll
    for (int e = 0; e < 8; ++e) {
      float rm0, rm1;
      unsigned short h0 = h_split(r0[e], rm0);
      unsigned short h1 = h_split(r1[e], rm1);
      pbh[e] = pack2(h0, h1);
      pbl[e] = pack2(h_rne(rm0), h_rne(rm1));
    }

    __syncthreads();
    *(uint4*)&sAhi[sr*LSTR + sc] =
        make_uint4(pack2(ah[0],ah[1]), pack2(ah[2],ah[3]),
                   pack2(ah[4],ah[5]), pack2(ah[6],ah[7]));
    *(uint4*)&sAhi[sr*LSTR + sc + 8] =
        make_uint4(pack2(ah[8],ah[9]), pack2(ah[10],ah[11]),
                   pack2(ah[12],ah[13]), pack2(ah[14],ah[15]));
    *(uint4*)&sAlo[sr*LSTR + sc] =
        make_uint4(pack2(av[0],av[1]), pack2(av[2],av[3]),
                   pack2(av[4],av[5]), pack2(av[6],av[7]));
    *(uint4*)&sAlo[sr*LSTR + sc + 8] =
        make_uint4(pack2(av[8],av[9]), pack2(av[10],av[11]),
                   pack2(av[12],av[13]), pack2(av[14],av[15]));
    {
      unsigned int* bh32 = (unsigned int*)sBhi;
      unsigned int* bl32 = (unsigned int*)sBlo;
      #pragma unroll
      for (int e = 0; e < 8; ++e) bh32[(nbase + e)*17 + pr] = pbh[e];
      #pragma unroll
      for (int e = 0; e < 8; ++e) bl32[(nbase + e)*17 + pr] = pbl[e];
    }
    __syncthreads();

    half8 afh[4], afl[4], bfh[4], bfl[4];
    #pragma unroll
    for (int mt = 0; mt < 4; ++mt) {
      const int ar = wr + mt*16 + lrow;
      afh[mt] = *(const half8*)&sAhi[ar*LSTR + quad*8];
      afl[mt] = *(const half8*)&sAlo[ar*LSTR + quad*8];
    }
    #pragma unroll
    for (int nt = 0; nt < 4; ++nt) {
      const int br = wc + nt*16 + lrow;
      const unsigned int* ph = (const unsigned int*)sBhi + br*17 + quad*4;
      const unsigned int* pl = (const unsigned int*)sBlo + br*17 + quad*4;
      union FU { unsigned int u[4]; half8 s; };
      FU th, tl;
      th.u[0] = ph[0]; th.u[1] = ph[1]; th.u[2] = ph[2]; th.u[3] = ph[3];
      tl.u[0] = pl[0]; tl.u[1] = pl[1]; tl.u[2] = pl[2]; tl.u[3] = pl[3];
      bfh[nt] = th.s; bfl[nt] = tl.s;
    }
    #pragma unroll
    for (int mt = 0; mt < 4; ++mt)
      #pragma unroll
      for (int nt = 0; nt < 4; ++nt) {
        acc[mt][nt] = __builtin_amdgcn_mfma_f32_16x16x32_f16(afh[mt], bfh[nt], acc[mt][nt], 0, 0, 0);
        acc[mt][nt] = __builtin_amdgcn_mfma_f32_16x16x32_f16(afl[mt], bfh[nt], acc[mt][nt], 0, 0, 0);
        acc[mt][nt] = __builtin_amdgcn_mfma_f32_16x16x32_f16(afh[mt], bfl[nt], acc[mt][nt], 0, 0, 0);
      }
  }
  float* Cz = part + (size_t)bz * BATCH * DIM;
  #pragma unroll
  for (int mt = 0; mt < 4; ++mt)
    #pragma unroll
    for (int nt = 0; nt < 4; ++nt)
      #pragma unroll
      for (int reg = 0; reg < 4; ++reg) {
        const int m = m0 + wr + mt*16 + quad*4 + reg;
        const int n = n0 + wc + nt*16 + lrow;
        Cz[(size_t)m * DIM + n] = acc[mt][nt][reg];
      }
}

// ---------------------------------------------------------------------------
// FUSED coef + readval_merge: block i computes nxt (LDS scan), the write-
// interaction coefficients ca/cs into LDS, then consumes them directly in the
// merge phase. Cadd/Csub/mOut/Zout never touch global memory.
// ---------------------------------------------------------------------------
__global__ __launch_bounds__(256) void coef_readval(
    const float* __restrict__ S0T, const float* __restrict__ G,
    const int* __restrict__ slots,
    const float* __restrict__ m_base, const float* __restrict__ se_base,
    const float* __restrict__ WVp, const float* __restrict__ mem_vals,
    const float* __restrict__ S_t, const float* __restrict__ part,
    float* __restrict__ merged)
{
  const int i = blockIdx.x, j = threadIdx.x;
  __shared__ int sh[BATCH];
  __shared__ float sca[BATCH], scs[BATCH];
  __shared__ float red[4];
  __shared__ float sh_invZ, sh_rs;
  sh[j] = slots[j];
  __syncthreads();
  const int sj = sh[j];
  int nj = 0x7fffffff;
  for (int k = j + 1; k < BATCH; ++k)
    if (sh[k] == sj) { nj = k; break; }

  const bool alive = (j < i) && (nj >= i);
  const float g = alive ? G[(size_t)i*BATCH + j] : -1e30f;
  float bv = g;
  #pragma unroll
  for (int off = 32; off; off >>= 1) bv = fmaxf(bv, __shfl_xor(bv, off));
  if ((j & 63) == 0) red[j >> 6] = bv;
  __syncthreads();
  const float mb = m_base[i];
  const float mi = fmaxf(fmaxf(fmaxf(red[0], red[1]), fmaxf(red[2], red[3])), mb);
  const float sv_ = alive ? S0T[(size_t)i*SLOTS + sj] : 0.f;
  const float ca = alive ? __expf(g - mi) : 0.f;
  const float cs = alive ? __expf(sv_ - mi) : 0.f;
  sca[j] = ca; scs[j] = cs;
  float z = ca - cs;
  #pragma unroll
  for (int off = 32; off; off >>= 1) z += __shfl_xor(z, off);
  __syncthreads();
  if ((j & 63) == 0) red[j >> 6] = z;
  __syncthreads();
  if (j == 0) {
    const float Z = se_base[i] * __expf(mb - mi) + red[0] + red[1] + red[2] + red[3];
    sh_invZ = 1.0f / Z;
    sh_rs = __expf(mb - mi) * (1.0f / EXP_SCALE);
  }
  __syncthreads();

  // ---- merge phase (j now indexes output columns) ----
  merged[(size_t)i*1024 + j]        = S_t[(size_t)i*DIM + j];
  merged[(size_t)i*1024 + 256 + j]  = S_t[(size_t)i*DIM + 256 + j];
  float acc0 = 0.f, acc1 = 0.f;
  #pragma unroll 4
  for (int zz = 0; zz < 32; ++zz) {
    acc0 += part[(size_t)zz * (BATCH*DIM) + (size_t)i*DIM + j];
    acc1 += part[(size_t)zz * (BATCH*DIM) + (size_t)i*DIM + 256 + j];
  }
  acc0 *= sh_rs; acc1 *= sh_rs;
  for (int jj = 0; jj < BATCH; ++jj) {
    float caj = sca[jj];
    float csj = scs[jj];
    if (caj != 0.f || csj != 0.f) {
      int sjj = sh[jj];
      acc0 += caj * WVp[(size_t)jj*DIM + j]       - csj * mem_vals[(size_t)sjj*DIM + j];
      acc1 += caj * WVp[(size_t)jj*DIM + 256 + j] - csj * mem_vals[(size_t)sjj*DIM + 256 + j];
    }
  }
  merged[(size_t)i*1024 + 512 + j] = acc0 * sh_invZ;
  merged[(size_t)i*1024 + 768 + j] = acc1 * sh_invZ;
}

// ---------------------------------------------------------------------------
extern "C" void kernel_launch(void* const* d_in, const int* in_sizes, int n_in,
                              void* d_out, int out_size, void* d_ws, size_t ws_size,
                              hipStream_t stream)
{
  (void)in_sizes; (void)n_in; (void)out_size; (void)ws_size;
  const float* S_t      = (const float*)d_in[0];
  const float* mem_keys = (const float*)d_in[1];
  const float* mem_vals = (const float*)d_in[2];
  const float* Wk       = (const float*)d_in[3];
  const float* bk       = (const float*)d_in[4];
  const float* Wv       = (const float*)d_in[5];
  const float* bv       = (const float*)d_in[6];
  const float* W1       = (const float*)d_in[7];
  const float* b1       = (const float*)d_in[8];
  const float* W2       = (const float*)d_in[9];
  const float* b2       = (const float*)d_in[10];
  float* out = (float*)d_out;

  // Workspace layout — round-3-proven footprint.
  float* ws = (float*)d_ws;
  float* Kp       = ws + 0;         // [256,512]
  float* WVp      = ws + 131072;    // [256,512]
  float* G        = ws + 262144;    // [256,256]
  float* S0T      = ws + 327680;    // [256,32768]
  float* m_base   = ws + 8716288;   // [256]
  float* se_base  = ws + 8716544;   // [256]
  float* t16v     = ws + 8716800;   // [256,16]
  int*   t16i     = (int*)(ws + 8720896);
  float* gv16     = ws + 8724992;   // [256,16]
  int*   gj16     = (int*)(ws + 8729088);
  int*   slots    = (int*)(ws + 8733184);
  float* merged   = ws + 8996352;   // [256,1024]
  float* hid      = ws + 9258496;   // [256,2048] ends 9782784
  float* part     = ws + 9782784;   // [32][256,512] ends 13977088
  // col_chunk scratch aliased onto head of part:
  float* cmaxb    = ws + 9782784;   // [256,4]
  float* cseb     = ws + 9783808;   // [256,4]
  float* c16vb    = ws + 9784832;   // [256,4,16]
  int*   c16ib    = (int*)(ws + 9801216);  // [256,4,16] ends 9817600 < 13977088
  unsigned short* Khi = (unsigned short*)(ws + 13977088);  // [256,512] bf16
  unsigned short* Klo = (unsigned short*)(ws + 14042624);  // [256,512] bf16, ends 14108160

  // phase 1: Wk-proj (+hi/lo epilogue) & Wv-proj fused; then gram+scores fused
  proj2<<<dim3(64), dim3(256), 0, stream>>>(S_t, Wk, bk, Kp, Khi, Klo, Wv, bv, WVp);
  gram_scores<<<dim3(528), dim3(256), 0, stream>>>(Kp, G, Khi, Klo, mem_keys, S0T);

  // phase 2: col stats + G top-16 fused; combine
  colchunk_gtop<<<dim3(1280), dim3(256), 0, stream>>>(S0T, cmaxb, cseb, c16vb, c16ib,
                                                      G, gv16, gj16);
  col_combine<<<dim3(256), dim3(64), 0, stream>>>(cmaxb, cseb, c16vb, c16ib,
                                                  m_base, se_base, t16v, t16i);

  // phase 2.5: FUSED pipelined sequential (block 0) + read exp-GEMM (1..256)
  //            + hidA = S_t @ W1[:, :512]^T (257..384)
  seq_plus_gemm<<<dim3(385), dim3(256), 0, stream>>>(S0T, G, t16v, t16i, gv16, gj16,
                                                     slots, mem_vals, m_base, part,
                                                     S_t, W1, hid);

  // phase 3: coefficients + split-K reduce + merge, fully fused
  coef_readval<<<dim3(256), dim3(256), 0, stream>>>(S0T, G, slots, m_base, se_base,
                                                    WVp, mem_vals, S_t, part, merged);

  // phase 4: MLP — W1b half (K=512, accumulate onto hidA) then W2
  gemm_bt<<<dim3(4, 32), dim3(256), 0, stream>>>(merged + 512, 1024, W1 + 512, 1024,
                                                 b1, hid, 2048, 512, 1, 1);
  gemm_bt<<<dim3(4, 8),  dim3(256), 0, stream>>>(hid, 2048, W2, 2048,
                                                 b2, out, 512, 2048, 0, 0);
}

// Round 8
// 644.409 us; speedup vs baseline: 1.3536x; 1.1731x over previous
//
#include <hip/hip_runtime.h>
#include <cstdint>
#include <cstddef>

#define BATCH 256
#define DIM   512
#define HIDN  2048
#define SLOTS 32768
#define NCHUNK 4
#define CHSZ  (SLOTS/NCHUNK)    // 8192

typedef __attribute__((ext_vector_type(8))) short short8;
typedef __attribute__((ext_vector_type(8))) _Float16 half8;
typedef __attribute__((ext_vector_type(4))) float f32x4;

// ---------------------------------------------------------------------------
// bf16 split helpers (RNE) — score GEMM path (proven at K=512)
// ---------------------------------------------------------------------------
__device__ __forceinline__ unsigned short bf_rne(float x) {
  unsigned int u = __float_as_uint(x);
  unsigned int r = (u + 0x7fffu + ((u >> 16) & 1u)) >> 16;
  return (unsigned short)r;
}
__device__ __forceinline__ unsigned short bf_split(float x, float& rem) {
  unsigned short h = bf_rne(x);
  rem = x - __uint_as_float(((unsigned int)h) << 16);
  return h;
}
__device__ __forceinline__ unsigned int pack2(unsigned short a, unsigned short b) {
  return (unsigned int)a | ((unsigned int)b << 16);
}

// ---------------------------------------------------------------------------
// fp16 split helpers (RNE) — read exp-GEMM path (proven at K=32768)
// ---------------------------------------------------------------------------
__device__ __forceinline__ unsigned short h_rne(float x) {
  _Float16 h = (_Float16)x;
  union { _Float16 f; unsigned short u; } cv; cv.f = h;
  return cv.u;
}
__device__ __forceinline__ unsigned short h_split(float x, float& rem) {
  _Float16 h = (_Float16)x;
  rem = x - (float)h;
  union { _Float16 f; unsigned short u; } cv; cv.f = h;
  return cv.u;
}

// ---------------------------------------------------------------------------
// 64x64 fp32 VALU GEMM tile body: C = act(addC?C:0 + A @ B^T + bias).
// TK=16, k range [kb,ke). atomic=1 -> atomicAdd epilogue (split-K), C must
// be pre-initialized (we pre-fill with bias). Optional bf16 hi/lo epilogue.
// ---------------------------------------------------------------------------
__device__ __forceinline__ void gemm64_body(
    const float* __restrict__ A, int lda, const float* __restrict__ B, int ldb,
    const float* __restrict__ bias, float* __restrict__ C, int ldc,
    int kb, int ke, int relu, int addC, int atomic,
    unsigned short* __restrict__ hi, unsigned short* __restrict__ lo,
    int bx, int by, int t, float (*As)[68], float (*Bs)[68])
{
  const int m0 = bx * 64;
  const int n0 = by * 64;
  const int tx = t & 15, ty = t >> 4;
  const int lr = t >> 2;
  const int lc = (t & 3) * 4;
  float acc[4][4] = {};
  for (int k0 = kb; k0 < ke; k0 += 16) {
    float4 a = *(const float4*)(A + (size_t)(m0 + lr) * lda + k0 + lc);
    float4 b = *(const float4*)(B + (size_t)(n0 + lr) * ldb + k0 + lc);
    __syncthreads();
    As[lc+0][lr] = a.x; As[lc+1][lr] = a.y; As[lc+2][lr] = a.z; As[lc+3][lr] = a.w;
    Bs[lc+0][lr] = b.x; Bs[lc+1][lr] = b.y; Bs[lc+2][lr] = b.z; Bs[lc+3][lr] = b.w;
    __syncthreads();
    #pragma unroll
    for (int k = 0; k < 16; ++k) {
      const float4 a4 = *(const float4*)&As[k][ty*4];
      const float4 b4 = *(const float4*)&Bs[k][tx*4];
      const float aa[4] = {a4.x, a4.y, a4.z, a4.w};
      const float bb[4] = {b4.x, b4.y, b4.z, b4.w};
      #pragma unroll
      for (int u = 0; u < 4; ++u)
        #pragma unroll
        for (int v = 0; v < 4; ++v)
          acc[u][v] = fmaf(aa[u], bb[v], acc[u][v]);
    }
  }
  #pragma unroll
  for (int u = 0; u < 4; ++u) {
    const int m = m0 + ty*4 + u;
    if (atomic) {
      #pragma unroll
      for (int v = 0; v < 4; ++v)
        atomicAdd(&C[(size_t)m * ldc + n0 + tx*4 + v], acc[u][v]);
    } else {
      float o[4];
      #pragma unroll
      for (int v = 0; v < 4; ++v) {
        float c = acc[u][v];
        if (addC) c += C[(size_t)m * ldc + n0 + tx*4 + v];
        if (bias) c += bias[n0 + tx*4 + v];
        if (relu) c = fmaxf(c, 0.0f);
        o[v] = c;
      }
      *(float4*)(C + (size_t)m * ldc + n0 + tx*4) = make_float4(o[0], o[1], o[2], o[3]);
      if (hi) {
        float r0, r1, r2, r3;
        unsigned short h0 = bf_split(o[0], r0), h1 = bf_split(o[1], r1);
        unsigned short h2 = bf_split(o[2], r2), h3 = bf_split(o[3], r3);
        *(uint2*)(hi + (size_t)m * ldc + n0 + tx*4) =
            make_uint2(pack2(h0, h1), pack2(h2, h3));
        *(uint2*)(lo + (size_t)m * ldc + n0 + tx*4) =
            make_uint2(pack2(bf_rne(r0), bf_rne(r1)), pack2(bf_rne(r2), bf_rne(r3)));
      }
    }
  }
}

// standalone GEMM (MLP W1b)
__global__ __launch_bounds__(256) void gemm_bt(
    const float* __restrict__ A, int lda, const float* __restrict__ B, int ldb,
    const float* __restrict__ bias, float* __restrict__ C, int ldc,
    int K, int relu, int addC)
{
  __shared__ __align__(16) float As[16][68];
  __shared__ __align__(16) float Bs[16][68];
  gemm64_body(A, lda, B, ldb, bias, C, ldc, 0, K, relu, addC, 0, nullptr, nullptr,
              blockIdx.x, blockIdx.y, threadIdx.x, As, Bs);
}

// split-K GEMM with atomicAdd epilogue (W2; out pre-filled with bias)
__global__ __launch_bounds__(256) void gemm_bt_sk(
    const float* __restrict__ A, int lda, const float* __restrict__ B, int ldb,
    float* __restrict__ C, int ldc, int kchunk)
{
  __shared__ __align__(16) float As[16][68];
  __shared__ __align__(16) float Bs[16][68];
  const int kb = blockIdx.z * kchunk;
  gemm64_body(A, lda, B, ldb, nullptr, C, ldc, kb, kb + kchunk, 0, 0, 1,
              nullptr, nullptr, blockIdx.x, blockIdx.y, threadIdx.x, As, Bs);
}

// FUSED: Wk-projection with bf16 hi/lo epilogue (blocks 0..31) +
// Wv-projection (blocks 32..63).
__global__ __launch_bounds__(256) void proj2(
    const float* __restrict__ S_t,
    const float* __restrict__ Wk, const float* __restrict__ bk, float* __restrict__ Kp,
    unsigned short* __restrict__ Khi, unsigned short* __restrict__ Klo,
    const float* __restrict__ Wv, const float* __restrict__ bv, float* __restrict__ WVp)
{
  __shared__ __align__(16) float As[16][68];
  __shared__ __align__(16) float Bs[16][68];
  int b = blockIdx.x;
  if (b < 32)
    gemm64_body(S_t, 512, Wk, 512, bk, Kp, 512, 0, 512, 0, 0, 0, Khi, Klo,
                b & 3, b >> 2, threadIdx.x, As, Bs);
  else {
    b -= 32;
    gemm64_body(S_t, 512, Wv, 512, bv, WVp, 512, 0, 512, 0, 0, 0, nullptr, nullptr,
                b & 3, b >> 2, threadIdx.x, As, Bs);
  }
}

// ---------------------------------------------------------------------------
// bf16 hi/lo MFMA BT-GEMM body (scores; round-3 proven at K=512)
// ---------------------------------------------------------------------------
#define LSTR 40
__device__ __forceinline__ void mfma_scores_body(
    const unsigned short* __restrict__ Ahi, const unsigned short* __restrict__ Alo,
    const float* __restrict__ B, float* __restrict__ C, int M, int N, int K,
    int bx, int by, int t,
    unsigned short* sAhi, unsigned short* sAlo,
    unsigned short* sBhi, unsigned short* sBlo)
{
  const int m0 = bx * 128, n0 = by * 128;
  const int wave = t >> 6, lane = t & 63;
  const int wr = (wave >> 1) * 64, wc = (wave & 1) * 64;
  const int lrow = lane & 15, quad = lane >> 4;
  const int sr = t >> 1;
  const int sc = (t & 1) * 16;

  f32x4 acc[4][4];
  #pragma unroll
  for (int a = 0; a < 4; ++a)
    #pragma unroll
    for (int b = 0; b < 4; ++b)
      acc[a][b] = (f32x4){0.f, 0.f, 0.f, 0.f};

  for (int k0 = 0; k0 < K; k0 += 32) {
    const size_t aoff = (size_t)(m0 + sr) * K + k0 + sc;
    uint4 ah0 = *(const uint4*)(Ahi + aoff);
    uint4 ah1 = *(const uint4*)(Ahi + aoff + 8);
    uint4 al0 = *(const uint4*)(Alo + aoff);
    uint4 al1 = *(const uint4*)(Alo + aoff + 8);
    const float* bp = B + (size_t)(n0 + sr) * K + k0 + sc;
    float4 b0 = *(const float4*)(bp + 0);
    float4 b1 = *(const float4*)(bp + 4);
    float4 b2 = *(const float4*)(bp + 8);
    float4 b3 = *(const float4*)(bp + 12);
    float bx_[16] = {b0.x,b0.y,b0.z,b0.w, b1.x,b1.y,b1.z,b1.w,
                     b2.x,b2.y,b2.z,b2.w, b3.x,b3.y,b3.z,b3.w};
    unsigned short bh[16], bl[16];
    #pragma unroll
    for (int e = 0; e < 16; ++e) {
      float rem; bh[e] = bf_split(bx_[e], rem); bl[e] = bf_rne(rem);
    }
    __syncthreads();
    *(uint4*)&sAhi[sr*LSTR + sc]     = ah0;
    *(uint4*)&sAhi[sr*LSTR + sc + 8] = ah1;
    *(uint4*)&sAlo[sr*LSTR + sc]     = al0;
    *(uint4*)&sAlo[sr*LSTR + sc + 8] = al1;
    *(uint4*)&sBhi[sr*LSTR + sc] =
        make_uint4(pack2(bh[0],bh[1]), pack2(bh[2],bh[3]),
                   pack2(bh[4],bh[5]), pack2(bh[6],bh[7]));
    *(uint4*)&sBhi[sr*LSTR + sc + 8] =
        make_uint4(pack2(bh[8],bh[9]), pack2(bh[10],bh[11]),
                   pack2(bh[12],bh[13]), pack2(bh[14],bh[15]));
    *(uint4*)&sBlo[sr*LSTR + sc] =
        make_uint4(pack2(bl[0],bl[1]), pack2(bl[2],bl[3]),
                   pack2(bl[4],bl[5]), pack2(bl[6],bl[7]));
    *(uint4*)&sBlo[sr*LSTR + sc + 8] =
        make_uint4(pack2(bl[8],bl[9]), pack2(bl[10],bl[11]),
                   pack2(bl[12],bl[13]), pack2(bl[14],bl[15]));
    __syncthreads();

    short8 afh[4], afl[4], bfh[4], bfl[4];
    #pragma unroll
    for (int mt = 0; mt < 4; ++mt) {
      const int ar = wr + mt*16 + lrow;
      afh[mt] = *(const short8*)&sAhi[ar*LSTR + quad*8];
      afl[mt] = *(const short8*)&sAlo[ar*LSTR + quad*8];
    }
    #pragma unroll
    for (int nt = 0; nt < 4; ++nt) {
      const int br = wc + nt*16 + lrow;
      bfh[nt] = *(const short8*)&sBhi[br*LSTR + quad*8];
      bfl[nt] = *(const short8*)&sBlo[br*LSTR + quad*8];
    }
    #pragma unroll
    for (int mt = 0; mt < 4; ++mt)
      #pragma unroll
      for (int nt = 0; nt < 4; ++nt) {
        acc[mt][nt] = __builtin_amdgcn_mfma_f32_16x16x32_bf16(afh[mt], bfh[nt], acc[mt][nt], 0, 0, 0);
        acc[mt][nt] = __builtin_amdgcn_mfma_f32_16x16x32_bf16(afl[mt], bfh[nt], acc[mt][nt], 0, 0, 0);
        acc[mt][nt] = __builtin_amdgcn_mfma_f32_16x16x32_bf16(afh[mt], bfl[nt], acc[mt][nt], 0, 0, 0);
      }
  }
  #pragma unroll
  for (int mt = 0; mt < 4; ++mt)
    #pragma unroll
    for (int nt = 0; nt < 4; ++nt)
      #pragma unroll
      for (int reg = 0; reg < 4; ++reg) {
        const int m = m0 + wr + mt*16 + quad*4 + reg;
        const int n = n0 + wc + nt*16 + lrow;
        C[(size_t)m * N + n] = acc[mt][nt][reg];
      }
}

// FUSED: gram GEMM (blocks 0..15) + score MFMA GEMM (blocks 16..527).
__global__ __launch_bounds__(256) void gram_scores(
    const float* __restrict__ Kp, float* __restrict__ G,
    const unsigned short* __restrict__ Khi, const unsigned short* __restrict__ Klo,
    const float* __restrict__ mem_keys, float* __restrict__ S0T)
{
  __shared__ __align__(16) unsigned char arena[40960];
  const int b = blockIdx.x;
  if (b < 16) {
    float (*As)[68] = (float (*)[68])arena;
    float (*Bs)[68] = (float (*)[68])(arena + 4352);
    gemm64_body(Kp, 512, Kp, 512, nullptr, G, 256, 0, 512, 0, 0, 0, nullptr, nullptr,
                b & 3, b >> 2, threadIdx.x, As, Bs);
  } else {
    const int sb = b - 16;
    unsigned short* sAhi = (unsigned short*)arena;
    unsigned short* sAlo = (unsigned short*)(arena + 10240);
    unsigned short* sBhi = (unsigned short*)(arena + 20480);
    unsigned short* sBlo = (unsigned short*)(arena + 30720);
    mfma_scores_body(Khi, Klo, mem_keys, S0T, 256, 32768, 512,
                     sb & 1, sb >> 1, threadIdx.x, sAhi, sAlo, sBhi, sBlo);
  }
}

// ---------------------------------------------------------------------------
// FUSED: col_chunk (blocks 0..1023, column data kept in registers for the
// sumexp pass — removes the 32-KB re-read) + gtop16 (blocks 1024..1279).
// ---------------------------------------------------------------------------
__global__ __launch_bounds__(256) void colchunk_gtop(
    const float* __restrict__ S0T, float* __restrict__ cmax,
    float* __restrict__ cse, float* __restrict__ c16v, int* __restrict__ c16i,
    const float* __restrict__ G, float* __restrict__ gv16, int* __restrict__ gj16)
{
  __shared__ float redv[4]; __shared__ int redi[4];
  __shared__ float outv[16]; __shared__ int outi[16];
  __shared__ float ws2[4];
  __shared__ float gvals[BATCH];
  const int t = threadIdx.x;

  if (blockIdx.x >= 1024) {
    const int i = blockIdx.x - 1024;
    const int lane = t & 63, w = t >> 6;
    gvals[t] = (t < i) ? G[(size_t)i*BATCH + t] : -1e30f;
    __syncthreads();
    for (int r = 0; r < 16; ++r) {
      float bv = gvals[t]; int bj = t;
      #pragma unroll
      for (int off = 32; off; off >>= 1) {
        float ov = __shfl_xor(bv, off); int oj = __shfl_xor(bj, off);
        if (ov > bv || (ov == bv && oj < bj)) { bv = ov; bj = oj; }
      }
      if (lane == 0) { redv[w] = bv; redi[w] = bj; }
      __syncthreads();
      if (t == 0) {
        float fv = redv[0]; int fj = redi[0];
        #pragma unroll
        for (int w2 = 1; w2 < 4; ++w2)
          if (redv[w2] > fv || (redv[w2] == fv && redi[w2] < fj)) { fv = redv[w2]; fj = redi[w2]; }
        gv16[i*16 + r] = fv; gj16[i*16 + r] = fj;
        gvals[fj] = -1e30f;
      }
      __syncthreads();
    }
    return;
  }

  const int ch = blockIdx.x & 3, row = blockIdx.x >> 2;
  const float* col = S0T + (size_t)row * SLOTS + ch * CHSZ;
  const int base = t * (CHSZ / 256);     // 32 contiguous per thread
  float4 xa[8];
  #pragma unroll
  for (int u = 0; u < 8; ++u) xa[u] = *(const float4*)(col + base + u*4);
  float v[16]; int ix[16];
  #pragma unroll
  for (int q = 0; q < 16; ++q) { v[q] = -1e30f; ix[q] = 0x7fffffff; }
  #pragma unroll
  for (int u = 0; u < 8; ++u) {
    float xs[4] = {xa[u].x, xa[u].y, xa[u].z, xa[u].w};
    #pragma unroll
    for (int e = 0; e < 4; ++e) {
      float cv = xs[e]; int ci = ch * CHSZ + base + u*4 + e;
      if (cv > v[15] || (cv == v[15] && ci < ix[15])) {
        #pragma unroll
        for (int q = 0; q < 16; ++q) {
          bool better = (cv > v[q]) || (cv == v[q] && ci < ix[q]);
          float tv = better ? v[q] : cv;  // static-index swap (cndmask)
          int   ti = better ? ix[q] : ci;
          v[q]  = better ? cv : v[q];
          ix[q] = better ? ci : ix[q];
          cv = tv; ci = ti;
        }
      }
    }
  }
  for (int r = 0; r < 16; ++r) {
    float bv = v[0]; int bi = ix[0];
    #pragma unroll
    for (int off = 32; off; off >>= 1) {
      float ov = __shfl_xor(bv, off); int oi = __shfl_xor(bi, off);
      if (ov > bv || (ov == bv && oi < bi)) { bv = ov; bi = oi; }
    }
    if ((t & 63) == 0) { redv[t >> 6] = bv; redi[t >> 6] = bi; }
    __syncthreads();
    float fv = redv[0]; int fi = redi[0];
    #pragma unroll
    for (int w = 1; w < 4; ++w)
      if (redv[w] > fv || (redv[w] == fv && redi[w] < fi)) { fv = redv[w]; fi = redi[w]; }
    if (t == 0) { outv[r] = fv; outi[r] = fi; }
    const bool adv = (v[0] == fv) && (ix[0] == fi);
    #pragma unroll
    for (int q = 0; q < 15; ++q) {
      v[q]  = adv ? v[q+1]  : v[q];
      ix[q] = adv ? ix[q+1] : ix[q];
    }
    v[15]  = adv ? -1e30f     : v[15];
    ix[15] = adv ? 0x7fffffff : ix[15];
    __syncthreads();
  }
  const int cidx = row * NCHUNK + ch;
  if (t < 16) { c16v[cidx*16 + t] = outv[t]; c16i[cidx*16 + t] = outi[t]; }
  const float m = outv[0];
  float s = 0.f;
  #pragma unroll
  for (int u = 0; u < 8; ++u) {
    s += __expf(xa[u].x - m) + __expf(xa[u].y - m)
       + __expf(xa[u].z - m) + __expf(xa[u].w - m);
  }
  #pragma unroll
  for (int off = 32; off; off >>= 1) s += __shfl_xor(s, off);
  if ((t & 63) == 0) ws2[t >> 6] = s;
  __syncthreads();
  if (t == 0) { cse[cidx] = ws2[0]+ws2[1]+ws2[2]+ws2[3]; cmax[cidx] = m; }
}

// ---------------------------------------------------------------------------
// Combine chunk stats (unchanged, round-3 proven)
// ---------------------------------------------------------------------------
__global__ __launch_bounds__(64) void col_combine(
    const float* __restrict__ cmax, const float* __restrict__ cse,
    const float* __restrict__ c16v, const int* __restrict__ c16i,
    float* __restrict__ m_base, float* __restrict__ se_base,
    float* __restrict__ t16v, int* __restrict__ t16i)
{
  const int i = blockIdx.x, lane = threadIdx.x;
  float v = c16v[(size_t)i * 64 + lane];
  int   id = c16i[(size_t)i * 64 + lane];
  float m0 = cmax[i*4+0], m1 = cmax[i*4+1], m2 = cmax[i*4+2], m3 = cmax[i*4+3];
  const float m = fmaxf(fmaxf(m0, m1), fmaxf(m2, m3));
  const float se = cse[i*4+0]*__expf(m0-m) + cse[i*4+1]*__expf(m1-m)
                 + cse[i*4+2]*__expf(m2-m) + cse[i*4+3]*__expf(m3-m);
  bool dead = false;
  for (int r = 0; r < 16; ++r) {
    float bv = dead ? -1e30f : v;
    int   bi = dead ? 0x7fffffff : id;
    #pragma unroll
    for (int off = 32; off; off >>= 1) {
      float ov = __shfl_xor(bv, off); int oi = __shfl_xor(bi, off);
      if (ov > bv || (ov == bv && oi < bi)) { bv = ov; bi = oi; }
    }
    if (!dead && v == bv && id == bi) dead = true;
    if (lane == 0) { t16v[i*16 + r] = bv; t16i[i*16 + r] = bi; }
  }
  if (lane == 0) { m_base[i] = m; se_base[i] = se; }
}

// ---------------------------------------------------------------------------
// FUSED: pipelined sequential slot assignment (block 0; candidate + bitmap +
// G-row all prefetched into registers one iteration ahead) + split-K NN
// exp-GEMM (blocks 1..256) + hidA = S_t @ W1[:,:512]^T (blocks 257..384).
// ---------------------------------------------------------------------------
#define EXP_SCALE 16384.0f
#define KCHUNK 1024
__global__ __launch_bounds__(256) void seq_plus_gemm(
    const float* __restrict__ S0T, const float* __restrict__ G,
    const float* __restrict__ t16v, const int* __restrict__ t16i,
    const float* __restrict__ gv16, const int* __restrict__ gj16,
    int* __restrict__ slots,
    const float* __restrict__ B, const float* __restrict__ mArr,
    float* __restrict__ part,
    const float* __restrict__ S_t, const float* __restrict__ W1,
    float* __restrict__ hid)
{
  __shared__ __align__(16) unsigned char smem[70656];

  if (blockIdx.x == 0) {
    // ======================= sequential phase =======================
    unsigned int* bitmap = (unsigned int*)smem;            //  4096 B
    float* sv       = (float*)(smem + 4096);               // 16384 B
    int*   si       = (int*)  (smem + 20480);              // 16384 B
    float* gv       = (float*)(smem + 36864);              // 16384 B
    int*   gj       = (int*)  (smem + 53248);              // 16384 B
    int*   slots_sh = (int*)  (smem + 69632);              //  1024 B
    volatile unsigned int* vbm = bitmap;
    const int tt = threadIdx.x;
    for (int q = tt; q < SLOTS/32; q += 256) bitmap[q] = 0u;
    for (int q = tt; q < BATCH*16; q += 256) {
      sv[q] = t16v[q]; si[q] = t16i[q]; gv[q] = gv16[q]; gj[q] = gj16[q];
    }
    __syncthreads();
    if (tt < 64) {
      const int lane = tt;
      unsigned long long alive[4] = {0ull,0ull,0ull,0ull};
      int slotr0 = -1, slotr1 = -1, slotr2 = -1, slotr3 = -1;

      // pipelined candidate state for iteration 0
      float myv = -1e30f; int myslot = 0; unsigned int wpref = 0;
      float ovq = -1e30f; int ojq = 0;
      if (lane < 16) {
        myv = sv[lane]; myslot = si[lane];
        wpref = vbm[myslot >> 5];
        ovq = gv[lane]; ojq = gj[lane];
      }
      int prev_slot = -1;
      // G-row register prefetch (row 0 unused; fallback can't fire at i=0)
      float grow[4];
      #pragma unroll
      for (int r = 0; r < 4; ++r) grow[r] = G[(size_t)0 * BATCH + lane + 64*r];

      for (int i = 0; i < BATCH; ++i) {
        bool bvalid = false, ovalid = false;
        if (lane < 16) {
          bvalid = (((wpref >> (myslot & 31)) & 1u) == 0u) && (myslot != prev_slot);
          unsigned long long am = (ojq < 64) ? alive[0] : (ojq < 128) ? alive[1]
                                 : (ojq < 192) ? alive[2] : alive[3];
          ovalid = (ovq > -1e29f) && (((am >> (ojq & 63)) & 1ull) != 0ull);
        }
        unsigned long long bb = __ballot(bvalid);
        unsigned long long ob = __ballot(ovalid);

        // prefetch next iteration's candidates + G row (off the critical chain)
        float myv_n = -1e30f; int myslot_n = 0; unsigned int wpref_n = 0;
        float ovq_n = -1e30f; int ojq_n = 0;
        if (i + 1 < BATCH && lane < 16) {
          myv_n = sv[(i+1)*16 + lane]; myslot_n = si[(i+1)*16 + lane];
          wpref_n = vbm[myslot_n >> 5];
          ovq_n = gv[(i+1)*16 + lane]; ojq_n = gj[(i+1)*16 + lane];
        }
        float grow_n[4];
        {
          const int nrow = (i + 1 < BATCH) ? (i + 1) : i;
          #pragma unroll
          for (int r = 0; r < 4; ++r) grow_n[r] = G[(size_t)nrow * BATCH + lane + 64*r];
        }

        float bval; int bslot;
        if (bb != 0ull) {
          int bl = __ffsll((unsigned long long)bb) - 1;
          bval = __shfl(myv, bl); bslot = __shfl(myslot, bl);
        } else {
          float fv = -1e30f; int fi = 0x7fffffff;
          for (int s = lane; s < SLOTS; s += 64) {
            if (((vbm[s >> 5] >> (s & 31)) & 1u) == 0u) {
              float x = S0T[(size_t)i*SLOTS + s];
              if (x > fv || (x == fv && s < fi)) { fv = x; fi = s; }
            }
          }
          #pragma unroll
          for (int off = 32; off; off >>= 1) {
            float ovv = __shfl_xor(fv, off); int oii = __shfl_xor(fi, off);
            if (ovv > fv || (ovv == fv && oii < fi)) { fv = ovv; fi = oii; }
          }
          bval = fv; bslot = fi;
        }

        float oval = -1e30f; int oslot = 0x7fffffff;
        if (ob != 0ull) {
          int ol = __ffsll((unsigned long long)ob) - 1;
          oval = __shfl(ovq, ol);
          int ojw = __shfl(ojq, ol);
          int r = ojw >> 6;
          int srg = (r == 0) ? slotr0 : (r == 1) ? slotr1 : (r == 2) ? slotr2 : slotr3;
          oslot = __shfl(srg, ojw & 63);
        } else if ((alive[0] | alive[1] | alive[2] | alive[3]) != 0ull) {
          float fv = -1e30f; int fj = 0x7fffffff;
          #pragma unroll
          for (int r = 0; r < 4; ++r) {
            int j = lane + 64*r;
            if (j < i && ((alive[r] >> lane) & 1ull)) {
              float x = grow[r];          // register-prefetched G[i][j]
              if (x > fv || (x == fv && j < fj)) { fv = x; fj = j; }
            }
          }
          #pragma unroll
          for (int off = 32; off; off >>= 1) {
            float ovv = __shfl_xor(fv, off); int ojj = __shfl_xor(fj, off);
            if (ovv > fv || (ovv == fv && ojj < fj)) { fv = ovv; fj = ojj; }
          }
          if (fj != 0x7fffffff) {
            oval = fv;
            int r = fj >> 6;
            int srg = (r == 0) ? slotr0 : (r == 1) ? slotr1 : (r == 2) ? slotr2 : slotr3;
            oslot = __shfl(srg, fj & 63);
          }
        }

        const bool owins = (oval > bval) || (oval == bval && oslot < bslot);
        const int sloti = owins ? oslot : bslot;

        unsigned long long kb0 = __ballot(slotr0 == sloti);
        unsigned long long kb1 = __ballot(slotr1 == sloti);
        unsigned long long kb2 = __ballot(slotr2 == sloti);
        unsigned long long kb3 = __ballot(slotr3 == sloti);
        alive[0] &= ~kb0; alive[1] &= ~kb1; alive[2] &= ~kb2; alive[3] &= ~kb3;
        const int r_new = i >> 6;
        if (lane == (i & 63)) {
          if (r_new == 0) slotr0 = sloti;
          else if (r_new == 1) slotr1 = sloti;
          else if (r_new == 2) slotr2 = sloti;
          else slotr3 = sloti;
        }
        alive[r_new] |= (1ull << (i & 63));
        if (lane == 0) {
          slots_sh[i] = sloti;
          vbm[sloti >> 5] = vbm[sloti >> 5] | (1u << (sloti & 31));
        }
        prev_slot = sloti;
        myv = myv_n; myslot = myslot_n; wpref = wpref_n; ovq = ovq_n; ojq = ojq_n;
        #pragma unroll
        for (int r = 0; r < 4; ++r) grow[r] = grow_n[r];
        __builtin_amdgcn_wave_barrier();
      }
      for (int q = lane; q < BATCH; q += 64) slots[q] = slots_sh[q];
    }
    return;
  }

  if (blockIdx.x >= 257) {
    // =================== hidA = S_t @ W1[:, :512]^T (blocks 257..384) ===================
    float (*As)[68] = (float (*)[68])smem;
    float (*Bs)[68] = (float (*)[68])(smem + 4352);
    const int b2 = blockIdx.x - 257;     // 0..127 -> 4 x 32 tiles
    gemm64_body(S_t, 512, W1, 1024, nullptr, hid, 2048, 0, 512, 0, 0, 0,
                nullptr, nullptr, b2 & 3, b2 >> 2, threadIdx.x, As, Bs);
    return;
  }

  // ======================= exp-GEMM phase (blocks 1..256) =======================
  unsigned short* sAhi = (unsigned short*)smem;            // 10240 B
  unsigned short* sAlo = (unsigned short*)(smem + 10240);  // 10240 B
  unsigned short* sBhi = (unsigned short*)(smem + 20480);  //  8704 B
  unsigned short* sBlo = (unsigned short*)(smem + 29184);  //  8704 B -> 37888

  const int b  = blockIdx.x - 1;           // 0..255
  const int bx = b >> 7;                   // 0..1   (M tiles)
  const int by = (b >> 5) & 3;             // 0..3   (N tiles)
  const int bz = b & 31;                   // 0..31  (K chunks)
  const int m0 = bx * 128, n0 = by * 128;
  const int kb = bz * KCHUNK;
  const int t = threadIdx.x;
  const int wave = t >> 6, lane = t & 63;
  const int wr = (wave >> 1) * 64, wc = (wave & 1) * 64;
  const int lrow = lane & 15, quad = lane >> 4;
  const int sr = t >> 1;           // A staging row (0..127), 2 threads/row
  const int sc = (t & 1) * 16;     // A staging k-offset
  const int pr = t >> 4;           // B k-pair row (0..15) -> k rows 2pr,2pr+1
  const int nbase = (t & 15) * 8;  // B n-offset (0..120)
  const float mrow = mArr[m0 + sr];

  f32x4 acc[4][4];
  #pragma unroll
  for (int a = 0; a < 4; ++a)
    #pragma unroll
    for (int c = 0; c < 4; ++c)
      acc[a][c] = (f32x4){0.f, 0.f, 0.f, 0.f};

  for (int k0 = kb; k0 < kb + KCHUNK; k0 += 32) {
    const float* ap = S0T + (size_t)(m0 + sr) * SLOTS + k0 + sc;
    float4 a0 = *(const float4*)(ap);
    float4 a1 = *(const float4*)(ap + 4);
    float4 a2 = *(const float4*)(ap + 8);
    float4 a3 = *(const float4*)(ap + 12);
    const float* bp = B + (size_t)(k0 + 2*pr) * DIM + n0 + nbase;
    float4 q0 = *(const float4*)(bp);
    float4 q1 = *(const float4*)(bp + 4);
    float4 q2 = *(const float4*)(bp + DIM);
    float4 q3 = *(const float4*)(bp + DIM + 4);

    float ax[16] = {a0.x,a0.y,a0.z,a0.w, a1.x,a1.y,a1.z,a1.w,
                    a2.x,a2.y,a2.z,a2.w, a3.x,a3.y,a3.z,a3.w};
    unsigned short ah[16], av[16];
    #pragma unroll
    for (int e = 0; e < 16; ++e) {
      float rm; float ee = __expf(ax[e] - mrow) * EXP_SCALE;
      ah[e] = h_split(ee, rm); av[e] = h_rne(rm);
    }
    float r0[8] = {q0.x,q0.y,q0.z,q0.w, q1.x,q1.y,q1.z,q1.w};
    float r1[8] = {q2.x,q2.y,q2.z,q2.w, q3.x,q3.y,q3.z,q3.w};
    unsigned int pbh[8], pbl[8];
    #pragma unroll
    for (int e = 0; e < 8; ++e) {
      float rm0, rm1;
      unsigned short h0 = h_split(r0[e], rm0);
      unsigned short h1 = h_split(r1[e], rm1);
      pbh[e] = pack2(h0, h1);
      pbl[e] = pack2(h_rne(rm0), h_rne(rm1));
    }

    __syncthreads();
    *(uint4*)&sAhi[sr*LSTR + sc] =
        make_uint4(pack2(ah[0],ah[1]), pack2(ah[2],ah[3]),
                   pack2(ah[4],ah[5]), pack2(ah[6],ah[7]));
    *(uint4*)&sAhi[sr*LSTR + sc + 8] =
        make_uint4(pack2(ah[8],ah[9]), pack2(ah[10],ah[11]),
                   pack2(ah[12],ah[13]), pack2(ah[14],ah[15]));
    *(uint4*)&sAlo[sr*LSTR + sc] =
        make_uint4(pack2(av[0],av[1]), pack2(av[2],av[3]),
                   pack2(av[4],av[5]), pack2(av[6],av[7]));
    *(uint4*)&sAlo[sr*LSTR + sc + 8] =
        make_uint4(pack2(av[8],av[9]), pack2(av[10],av[11]),
                   pack2(av[12],av[13]), pack2(av[14],av[15]));
    {
      unsigned int* bh32 = (unsigned int*)sBhi;
      unsigned int* bl32 = (unsigned int*)sBlo;
      #pragma unroll
      for (int e = 0; e < 8; ++e) bh32[(nbase + e)*17 + pr] = pbh[e];
      #pragma unroll
      for (int e = 0; e < 8; ++e) bl32[(nbase + e)*17 + pr] = pbl[e];
    }
    __syncthreads();

    half8 afh[4], afl[4], bfh[4], bfl[4];
    #pragma unroll
    for (int mt = 0; mt < 4; ++mt) {
      const int ar = wr + mt*16 + lrow;
      afh[mt] = *(const half8*)&sAhi[ar*LSTR + quad*8];
      afl[mt] = *(const half8*)&sAlo[ar*LSTR + quad*8];
    }
    #pragma unroll
    for (int nt = 0; nt < 4; ++nt) {
      const int br = wc + nt*16 + lrow;
      const unsigned int* ph = (const unsigned int*)sBhi + br*17 + quad*4;
      const unsigned int* pl = (const unsigned int*)sBlo + br*17 + quad*4;
      union FU { unsigned int u[4]; half8 s; };
      FU th, tl;
      th.u[0] = ph[0]; th.u[1] = ph[1]; th.u[2] = ph[2]; th.u[3] = ph[3];
      tl.u[0] = pl[0]; tl.u[1] = pl[1]; tl.u[2] = pl[2]; tl.u[3] = pl[3];
      bfh[nt] = th.s; bfl[nt] = tl.s;
    }
    #pragma unroll
    for (int mt = 0; mt < 4; ++mt)
      #pragma unroll
      for (int nt = 0; nt < 4; ++nt) {
        acc[mt][nt] = __builtin_amdgcn_mfma_f32_16x16x32_f16(afh[mt], bfh[nt], acc[mt][nt], 0, 0, 0);
        acc[mt][nt] = __builtin_amdgcn_mfma_f32_16x16x32_f16(afl[mt], bfh[nt], acc[mt][nt], 0, 0, 0);
        acc[mt][nt] = __builtin_amdgcn_mfma_f32_16x16x32_f16(afh[mt], bfl[nt], acc[mt][nt], 0, 0, 0);
      }
  }
  float* Cz = part + (size_t)bz * BATCH * DIM;
  #pragma unroll
  for (int mt = 0; mt < 4; ++mt)
    #pragma unroll
    for (int nt = 0; nt < 4; ++nt)
      #pragma unroll
      for (int reg = 0; reg < 4; ++reg) {
        const int m = m0 + wr + mt*16 + quad*4 + reg;
        const int n = n0 + wc + nt*16 + lrow;
        Cz[(size_t)m * DIM + n] = acc[mt][nt][reg];
      }
}

// ---------------------------------------------------------------------------
// FUSED coef + readval_merge (blocks 0..255) + out-bias-init (blocks 256..263,
// pre-fills `out` with b2 so the W2 split-K kernel can atomicAdd into it).
// jj-loop is branchless over jj<i (ca/cs are exactly 0 for dead j) so the
// two gather loads software-pipeline instead of latency-chaining.
// ---------------------------------------------------------------------------
__global__ __launch_bounds__(256) void coef_readval(
    const float* __restrict__ S0T, const float* __restrict__ G,
    const int* __restrict__ slots,
    const float* __restrict__ m_base, const float* __restrict__ se_base,
    const float* __restrict__ WVp, const float* __restrict__ mem_vals,
    const float* __restrict__ S_t, const float* __restrict__ part,
    float* __restrict__ merged,
    const float* __restrict__ bias2, float* __restrict__ outp)
{
  const int j = threadIdx.x;
  if (blockIdx.x >= BATCH) {
    const int b2 = blockIdx.x - BATCH;   // 0..7 -> 32 rows each
    const float z0 = bias2[j], z1 = bias2[256 + j];
    for (int r = 0; r < 32; ++r) {
      const int m = b2 * 32 + r;
      outp[(size_t)m * DIM + j] = z0;
      outp[(size_t)m * DIM + 256 + j] = z1;
    }
    return;
  }
  const int i = blockIdx.x;
  __shared__ int sh[BATCH];
  __shared__ float sca[BATCH], scs[BATCH];
  __shared__ float red[4];
  __shared__ float sh_invZ, sh_rs;
  sh[j] = slots[j];
  __syncthreads();
  const int sj = sh[j];
  int nj = 0x7fffffff;
  for (int k = j + 1; k < BATCH; ++k)
    if (sh[k] == sj) { nj = k; break; }

  const bool alive = (j < i) && (nj >= i);
  const float g = alive ? G[(size_t)i*BATCH + j] : -1e30f;
  float bv = g;
  #pragma unroll
  for (int off = 32; off; off >>= 1) bv = fmaxf(bv, __shfl_xor(bv, off));
  if ((j & 63) == 0) red[j >> 6] = bv;
  __syncthreads();
  const float mb = m_base[i];
  const float mi = fmaxf(fmaxf(fmaxf(red[0], red[1]), fmaxf(red[2], red[3])), mb);
  const float sv_ = alive ? S0T[(size_t)i*SLOTS + sj] : 0.f;
  const float ca = alive ? __expf(g - mi) : 0.f;
  const float cs = alive ? __expf(sv_ - mi) : 0.f;
  sca[j] = ca; scs[j] = cs;
  float z = ca - cs;
  #pragma unroll
  for (int off = 32; off; off >>= 1) z += __shfl_xor(z, off);
  __syncthreads();
  if ((j & 63) == 0) red[j >> 6] = z;
  __syncthreads();
  if (j == 0) {
    const float Z = se_base[i] * __expf(mb - mi) + red[0] + red[1] + red[2] + red[3];
    sh_invZ = 1.0f / Z;
    sh_rs = __expf(mb - mi) * (1.0f / EXP_SCALE);
  }
  __syncthreads();

  // ---- merge phase (j now indexes output columns) ----
  merged[(size_t)i*1024 + j]        = S_t[(size_t)i*DIM + j];
  merged[(size_t)i*1024 + 256 + j]  = S_t[(size_t)i*DIM + 256 + j];
  float acc0 = 0.f, acc1 = 0.f;
  #pragma unroll 4
  for (int zz = 0; zz < 32; ++zz) {
    acc0 += part[(size_t)zz * (BATCH*DIM) + (size_t)i*DIM + j];
    acc1 += part[(size_t)zz * (BATCH*DIM) + (size_t)i*DIM + 256 + j];
  }
  acc0 *= sh_rs; acc1 *= sh_rs;
  #pragma unroll 4
  for (int jj = 0; jj < i; ++jj) {      // ca/cs are zero for dead j: branchless
    const float caj = sca[jj];
    const float csj = scs[jj];
    const int sjj = sh[jj];
    acc0 += caj * WVp[(size_t)jj*DIM + j]       - csj * mem_vals[(size_t)sjj*DIM + j];
    acc1 += caj * WVp[(size_t)jj*DIM + 256 + j] - csj * mem_vals[(size_t)sjj*DIM + 256 + j];
  }
  merged[(size_t)i*1024 + 512 + j] = acc0 * sh_invZ;
  merged[(size_t)i*1024 + 768 + j] = acc1 * sh_invZ;
}

// ---------------------------------------------------------------------------
extern "C" void kernel_launch(void* const* d_in, const int* in_sizes, int n_in,
                              void* d_out, int out_size, void* d_ws, size_t ws_size,
                              hipStream_t stream)
{
  (void)in_sizes; (void)n_in; (void)out_size; (void)ws_size;
  const float* S_t      = (const float*)d_in[0];
  const float* mem_keys = (const float*)d_in[1];
  const float* mem_vals = (const float*)d_in[2];
  const float* Wk       = (const float*)d_in[3];
  const float* bk       = (const float*)d_in[4];
  const float* Wv       = (const float*)d_in[5];
  const float* bv       = (const float*)d_in[6];
  const float* W1       = (const float*)d_in[7];
  const float* b1       = (const float*)d_in[8];
  const float* W2       = (const float*)d_in[9];
  const float* b2       = (const float*)d_in[10];
  float* out = (float*)d_out;

  // Workspace layout — round-3-proven footprint.
  float* ws = (float*)d_ws;
  float* Kp       = ws + 0;         // [256,512]
  float* WVp      = ws + 131072;    // [256,512]
  float* G        = ws + 262144;    // [256,256]
  float* S0T      = ws + 327680;    // [256,32768]
  float* m_base   = ws + 8716288;   // [256]
  float* se_base  = ws + 8716544;   // [256]
  float* t16v     = ws + 8716800;   // [256,16]
  int*   t16i     = (int*)(ws + 8720896);
  float* gv16     = ws + 8724992;   // [256,16]
  int*   gj16     = (int*)(ws + 8729088);
  int*   slots    = (int*)(ws + 8733184);
  float* merged   = ws + 8996352;   // [256,1024]
  float* hid      = ws + 9258496;   // [256,2048] ends 9782784
  float* part     = ws + 9782784;   // [32][256,512] ends 13977088
  // col_chunk scratch aliased onto head of part:
  float* cmaxb    = ws + 9782784;   // [256,4]
  float* cseb     = ws + 9783808;   // [256,4]
  float* c16vb    = ws + 9784832;   // [256,4,16]
  int*   c16ib    = (int*)(ws + 9801216);  // [256,4,16] ends 9817600 < 13977088
  unsigned short* Khi = (unsigned short*)(ws + 13977088);  // [256,512] bf16
  unsigned short* Klo = (unsigned short*)(ws + 14042624);  // [256,512] bf16, ends 14108160

  // phase 1: Wk-proj (+hi/lo epilogue) & Wv-proj fused; then gram+scores fused
  proj2<<<dim3(64), dim3(256), 0, stream>>>(S_t, Wk, bk, Kp, Khi, Klo, Wv, bv, WVp);
  gram_scores<<<dim3(528), dim3(256), 0, stream>>>(Kp, G, Khi, Klo, mem_keys, S0T);

  // phase 2: col stats + G top-16 fused; combine
  colchunk_gtop<<<dim3(1280), dim3(256), 0, stream>>>(S0T, cmaxb, cseb, c16vb, c16ib,
                                                      G, gv16, gj16);
  col_combine<<<dim3(256), dim3(64), 0, stream>>>(cmaxb, cseb, c16vb, c16ib,
                                                  m_base, se_base, t16v, t16i);

  // phase 2.5: FUSED pipelined sequential (block 0) + read exp-GEMM (1..256)
  //            + hidA = S_t @ W1[:, :512]^T (257..384)
  seq_plus_gemm<<<dim3(385), dim3(256), 0, stream>>>(S0T, G, t16v, t16i, gv16, gj16,
                                                     slots, mem_vals, m_base, part,
                                                     S_t, W1, hid);

  // phase 3: coefficients + split-K reduce + merge + out-bias-init, fused
  coef_readval<<<dim3(264), dim3(256), 0, stream>>>(S0T, G, slots, m_base, se_base,
                                                    WVp, mem_vals, S_t, part, merged,
                                                    b2, out);

  // phase 4: MLP — W1b half (K=512, accumulate onto hidA) then W2 split-K x4
  gemm_bt<<<dim3(4, 32), dim3(256), 0, stream>>>(merged + 512, 1024, W1 + 512, 1024,
                                                 b1, hid, 2048, 512, 1, 1);
  gemm_bt_sk<<<dim3(4, 8, 4), dim3(256), 0, stream>>>(hid, 2048, W2, 2048,
                                                      out, 512, 512);
}

// Round 9
// 611.614 us; speedup vs baseline: 1.4262x; 1.0536x over previous
//
#include <hip/hip_runtime.h>
#include <cstdint>
#include <cstddef>

#define BATCH 256
#define DIM   512
#define HIDN  2048
#define SLOTS 32768
#define NCHUNK 4
#define CHSZ  (SLOTS/NCHUNK)    // 8192

typedef __attribute__((ext_vector_type(8))) short short8;
typedef __attribute__((ext_vector_type(8))) _Float16 half8;
typedef __attribute__((ext_vector_type(4))) float f32x4;

// ---------------------------------------------------------------------------
// bf16 split helpers (RNE) — score GEMM path (proven at K=512)
// ---------------------------------------------------------------------------
__device__ __forceinline__ unsigned short bf_rne(float x) {
  unsigned int u = __float_as_uint(x);
  unsigned int r = (u + 0x7fffu + ((u >> 16) & 1u)) >> 16;
  return (unsigned short)r;
}
__device__ __forceinline__ unsigned short bf_split(float x, float& rem) {
  unsigned short h = bf_rne(x);
  rem = x - __uint_as_float(((unsigned int)h) << 16);
  return h;
}
__device__ __forceinline__ unsigned int pack2(unsigned short a, unsigned short b) {
  return (unsigned int)a | ((unsigned int)b << 16);
}

// ---------------------------------------------------------------------------
// fp16 split helpers (RNE) — read exp-GEMM path (proven at K=32768)
// ---------------------------------------------------------------------------
__device__ __forceinline__ unsigned short h_rne(float x) {
  _Float16 h = (_Float16)x;
  union { _Float16 f; unsigned short u; } cv; cv.f = h;
  return cv.u;
}
__device__ __forceinline__ unsigned short h_split(float x, float& rem) {
  _Float16 h = (_Float16)x;
  rem = x - (float)h;
  union { _Float16 f; unsigned short u; } cv; cv.f = h;
  return cv.u;
}

// ---------------------------------------------------------------------------
// readlane helpers — uniform-index lane extraction via v_readlane_b32
// (VALU-class, ~10 cy) instead of __shfl's ds_bpermute (LDS-class, ~120 cy).
// Index MUST be wave-uniform (here: derived from ballot/converged reduce).
// ---------------------------------------------------------------------------
__device__ __forceinline__ int rdl(int v, int l) {
  return __builtin_amdgcn_readlane(v, l);
}
__device__ __forceinline__ float rdlf(float v, int l) {
  return __int_as_float(__builtin_amdgcn_readlane(__float_as_int(v), l));
}

// ---------------------------------------------------------------------------
// 64x64 fp32 VALU GEMM tile body: C = act(addC?C:0 + A @ B^T + bias).
// TK=16, k range [kb,ke). atomic=1 -> atomicAdd epilogue (split-K), C must
// be pre-initialized (we pre-fill with bias). Optional bf16 hi/lo epilogue.
// ---------------------------------------------------------------------------
__device__ __forceinline__ void gemm64_body(
    const float* __restrict__ A, int lda, const float* __restrict__ B, int ldb,
    const float* __restrict__ bias, float* __restrict__ C, int ldc,
    int kb, int ke, int relu, int addC, int atomic,
    unsigned short* __restrict__ hi, unsigned short* __restrict__ lo,
    int bx, int by, int t, float (*As)[68], float (*Bs)[68])
{
  const int m0 = bx * 64;
  const int n0 = by * 64;
  const int tx = t & 15, ty = t >> 4;
  const int lr = t >> 2;
  const int lc = (t & 3) * 4;
  float acc[4][4] = {};
  for (int k0 = kb; k0 < ke; k0 += 16) {
    float4 a = *(const float4*)(A + (size_t)(m0 + lr) * lda + k0 + lc);
    float4 b = *(const float4*)(B + (size_t)(n0 + lr) * ldb + k0 + lc);
    __syncthreads();
    As[lc+0][lr] = a.x; As[lc+1][lr] = a.y; As[lc+2][lr] = a.z; As[lc+3][lr] = a.w;
    Bs[lc+0][lr] = b.x; Bs[lc+1][lr] = b.y; Bs[lc+2][lr] = b.z; Bs[lc+3][lr] = b.w;
    __syncthreads();
    #pragma unroll
    for (int k = 0; k < 16; ++k) {
      const float4 a4 = *(const float4*)&As[k][ty*4];
      const float4 b4 = *(const float4*)&Bs[k][tx*4];
      const float aa[4] = {a4.x, a4.y, a4.z, a4.w};
      const float bb[4] = {b4.x, b4.y, b4.z, b4.w};
      #pragma unroll
      for (int u = 0; u < 4; ++u)
        #pragma unroll
        for (int v = 0; v < 4; ++v)
          acc[u][v] = fmaf(aa[u], bb[v], acc[u][v]);
    }
  }
  #pragma unroll
  for (int u = 0; u < 4; ++u) {
    const int m = m0 + ty*4 + u;
    if (atomic) {
      #pragma unroll
      for (int v = 0; v < 4; ++v)
        atomicAdd(&C[(size_t)m * ldc + n0 + tx*4 + v], acc[u][v]);
    } else {
      float o[4];
      #pragma unroll
      for (int v = 0; v < 4; ++v) {
        float c = acc[u][v];
        if (addC) c += C[(size_t)m * ldc + n0 + tx*4 + v];
        if (bias) c += bias[n0 + tx*4 + v];
        if (relu) c = fmaxf(c, 0.0f);
        o[v] = c;
      }
      *(float4*)(C + (size_t)m * ldc + n0 + tx*4) = make_float4(o[0], o[1], o[2], o[3]);
      if (hi) {
        float r0, r1, r2, r3;
        unsigned short h0 = bf_split(o[0], r0), h1 = bf_split(o[1], r1);
        unsigned short h2 = bf_split(o[2], r2), h3 = bf_split(o[3], r3);
        *(uint2*)(hi + (size_t)m * ldc + n0 + tx*4) =
            make_uint2(pack2(h0, h1), pack2(h2, h3));
        *(uint2*)(lo + (size_t)m * ldc + n0 + tx*4) =
            make_uint2(pack2(bf_rne(r0), bf_rne(r1)), pack2(bf_rne(r2), bf_rne(r3)));
      }
    }
  }
}

// standalone GEMM (MLP W1b)
__global__ __launch_bounds__(256) void gemm_bt(
    const float* __restrict__ A, int lda, const float* __restrict__ B, int ldb,
    const float* __restrict__ bias, float* __restrict__ C, int ldc,
    int K, int relu, int addC)
{
  __shared__ __align__(16) float As[16][68];
  __shared__ __align__(16) float Bs[16][68];
  gemm64_body(A, lda, B, ldb, bias, C, ldc, 0, K, relu, addC, 0, nullptr, nullptr,
              blockIdx.x, blockIdx.y, threadIdx.x, As, Bs);
}

// split-K GEMM with atomicAdd epilogue (W2; out pre-filled with bias)
__global__ __launch_bounds__(256) void gemm_bt_sk(
    const float* __restrict__ A, int lda, const float* __restrict__ B, int ldb,
    float* __restrict__ C, int ldc, int kchunk)
{
  __shared__ __align__(16) float As[16][68];
  __shared__ __align__(16) float Bs[16][68];
  const int kb = blockIdx.z * kchunk;
  gemm64_body(A, lda, B, ldb, nullptr, C, ldc, kb, kb + kchunk, 0, 0, 1,
              nullptr, nullptr, blockIdx.x, blockIdx.y, threadIdx.x, As, Bs);
}

// FUSED: Wk-projection with bf16 hi/lo epilogue (blocks 0..31) +
// Wv-projection (blocks 32..63).
__global__ __launch_bounds__(256) void proj2(
    const float* __restrict__ S_t,
    const float* __restrict__ Wk, const float* __restrict__ bk, float* __restrict__ Kp,
    unsigned short* __restrict__ Khi, unsigned short* __restrict__ Klo,
    const float* __restrict__ Wv, const float* __restrict__ bv, float* __restrict__ WVp)
{
  __shared__ __align__(16) float As[16][68];
  __shared__ __align__(16) float Bs[16][68];
  int b = blockIdx.x;
  if (b < 32)
    gemm64_body(S_t, 512, Wk, 512, bk, Kp, 512, 0, 512, 0, 0, 0, Khi, Klo,
                b & 3, b >> 2, threadIdx.x, As, Bs);
  else {
    b -= 32;
    gemm64_body(S_t, 512, Wv, 512, bv, WVp, 512, 0, 512, 0, 0, 0, nullptr, nullptr,
                b & 3, b >> 2, threadIdx.x, As, Bs);
  }
}

// ---------------------------------------------------------------------------
// bf16 hi/lo MFMA BT-GEMM body (scores; round-3 proven at K=512)
// ---------------------------------------------------------------------------
#define LSTR 40
__device__ __forceinline__ void mfma_scores_body(
    const unsigned short* __restrict__ Ahi, const unsigned short* __restrict__ Alo,
    const float* __restrict__ B, float* __restrict__ C, int M, int N, int K,
    int bx, int by, int t,
    unsigned short* sAhi, unsigned short* sAlo,
    unsigned short* sBhi, unsigned short* sBlo)
{
  const int m0 = bx * 128, n0 = by * 128;
  const int wave = t >> 6, lane = t & 63;
  const int wr = (wave >> 1) * 64, wc = (wave & 1) * 64;
  const int lrow = lane & 15, quad = lane >> 4;
  const int sr = t >> 1;
  const int sc = (t & 1) * 16;

  f32x4 acc[4][4];
  #pragma unroll
  for (int a = 0; a < 4; ++a)
    #pragma unroll
    for (int b = 0; b < 4; ++b)
      acc[a][b] = (f32x4){0.f, 0.f, 0.f, 0.f};

  for (int k0 = 0; k0 < K; k0 += 32) {
    const size_t aoff = (size_t)(m0 + sr) * K + k0 + sc;
    uint4 ah0 = *(const uint4*)(Ahi + aoff);
    uint4 ah1 = *(const uint4*)(Ahi + aoff + 8);
    uint4 al0 = *(const uint4*)(Alo + aoff);
    uint4 al1 = *(const uint4*)(Alo + aoff + 8);
    const float* bp = B + (size_t)(n0 + sr) * K + k0 + sc;
    float4 b0 = *(const float4*)(bp + 0);
    float4 b1 = *(const float4*)(bp + 4);
    float4 b2 = *(const float4*)(bp + 8);
    float4 b3 = *(const float4*)(bp + 12);
    float bx_[16] = {b0.x,b0.y,b0.z,b0.w, b1.x,b1.y,b1.z,b1.w,
                     b2.x,b2.y,b2.z,b2.w, b3.x,b3.y,b3.z,b3.w};
    unsigned short bh[16], bl[16];
    #pragma unroll
    for (int e = 0; e < 16; ++e) {
      float rem; bh[e] = bf_split(bx_[e], rem); bl[e] = bf_rne(rem);
    }
    __syncthreads();
    *(uint4*)&sAhi[sr*LSTR + sc]     = ah0;
    *(uint4*)&sAhi[sr*LSTR + sc + 8] = ah1;
    *(uint4*)&sAlo[sr*LSTR + sc]     = al0;
    *(uint4*)&sAlo[sr*LSTR + sc + 8] = al1;
    *(uint4*)&sBhi[sr*LSTR + sc] =
        make_uint4(pack2(bh[0],bh[1]), pack2(bh[2],bh[3]),
                   pack2(bh[4],bh[5]), pack2(bh[6],bh[7]));
    *(uint4*)&sBhi[sr*LSTR + sc + 8] =
        make_uint4(pack2(bh[8],bh[9]), pack2(bh[10],bh[11]),
                   pack2(bh[12],bh[13]), pack2(bh[14],bh[15]));
    *(uint4*)&sBlo[sr*LSTR + sc] =
        make_uint4(pack2(bl[0],bl[1]), pack2(bl[2],bl[3]),
                   pack2(bl[4],bl[5]), pack2(bl[6],bl[7]));
    *(uint4*)&sBlo[sr*LSTR + sc + 8] =
        make_uint4(pack2(bl[8],bl[9]), pack2(bl[10],bl[11]),
                   pack2(bl[12],bl[13]), pack2(bl[14],bl[15]));
    __syncthreads();

    short8 afh[4], afl[4], bfh[4], bfl[4];
    #pragma unroll
    for (int mt = 0; mt < 4; ++mt) {
      const int ar = wr + mt*16 + lrow;
      afh[mt] = *(const short8*)&sAhi[ar*LSTR + quad*8];
      afl[mt] = *(const short8*)&sAlo[ar*LSTR + quad*8];
    }
    #pragma unroll
    for (int nt = 0; nt < 4; ++nt) {
      const int br = wc + nt*16 + lrow;
      bfh[nt] = *(const short8*)&sBhi[br*LSTR + quad*8];
      bfl[nt] = *(const short8*)&sBlo[br*LSTR + quad*8];
    }
    #pragma unroll
    for (int mt = 0; mt < 4; ++mt)
      #pragma unroll
      for (int nt = 0; nt < 4; ++nt) {
        acc[mt][nt] = __builtin_amdgcn_mfma_f32_16x16x32_bf16(afh[mt], bfh[nt], acc[mt][nt], 0, 0, 0);
        acc[mt][nt] = __builtin_amdgcn_mfma_f32_16x16x32_bf16(afl[mt], bfh[nt], acc[mt][nt], 0, 0, 0);
        acc[mt][nt] = __builtin_amdgcn_mfma_f32_16x16x32_bf16(afh[mt], bfl[nt], acc[mt][nt], 0, 0, 0);
      }
  }
  #pragma unroll
  for (int mt = 0; mt < 4; ++mt)
    #pragma unroll
    for (int nt = 0; nt < 4; ++nt)
      #pragma unroll
      for (int reg = 0; reg < 4; ++reg) {
        const int m = m0 + wr + mt*16 + quad*4 + reg;
        const int n = n0 + wc + nt*16 + lrow;
        C[(size_t)m * N + n] = acc[mt][nt][reg];
      }
}

// FUSED: gram GEMM (blocks 0..15) + score MFMA GEMM (blocks 16..527).
__global__ __launch_bounds__(256) void gram_scores(
    const float* __restrict__ Kp, float* __restrict__ G,
    const unsigned short* __restrict__ Khi, const unsigned short* __restrict__ Klo,
    const float* __restrict__ mem_keys, float* __restrict__ S0T)
{
  __shared__ __align__(16) unsigned char arena[40960];
  const int b = blockIdx.x;
  if (b < 16) {
    float (*As)[68] = (float (*)[68])arena;
    float (*Bs)[68] = (float (*)[68])(arena + 4352);
    gemm64_body(Kp, 512, Kp, 512, nullptr, G, 256, 0, 512, 0, 0, 0, nullptr, nullptr,
                b & 3, b >> 2, threadIdx.x, As, Bs);
  } else {
    const int sb = b - 16;
    unsigned short* sAhi = (unsigned short*)arena;
    unsigned short* sAlo = (unsigned short*)(arena + 10240);
    unsigned short* sBhi = (unsigned short*)(arena + 20480);
    unsigned short* sBlo = (unsigned short*)(arena + 30720);
    mfma_scores_body(Khi, Klo, mem_keys, S0T, 256, 32768, 512,
                     sb & 1, sb >> 1, threadIdx.x, sAhi, sAlo, sBhi, sBlo);
  }
}

// ---------------------------------------------------------------------------
// FUSED: col_chunk (blocks 0..1023, column data kept in registers for the
// sumexp pass) + gtop16 (blocks 1024..1279).
// ---------------------------------------------------------------------------
__global__ __launch_bounds__(256) void colchunk_gtop(
    const float* __restrict__ S0T, float* __restrict__ cmax,
    float* __restrict__ cse, float* __restrict__ c16v, int* __restrict__ c16i,
    const float* __restrict__ G, float* __restrict__ gv16, int* __restrict__ gj16)
{
  __shared__ float redv[4]; __shared__ int redi[4];
  __shared__ float outv[16]; __shared__ int outi[16];
  __shared__ float ws2[4];
  __shared__ float gvals[BATCH];
  const int t = threadIdx.x;

  if (blockIdx.x >= 1024) {
    const int i = blockIdx.x - 1024;
    const int lane = t & 63, w = t >> 6;
    gvals[t] = (t < i) ? G[(size_t)i*BATCH + t] : -1e30f;
    __syncthreads();
    for (int r = 0; r < 16; ++r) {
      float bv = gvals[t]; int bj = t;
      #pragma unroll
      for (int off = 32; off; off >>= 1) {
        float ov = __shfl_xor(bv, off); int oj = __shfl_xor(bj, off);
        if (ov > bv || (ov == bv && oj < bj)) { bv = ov; bj = oj; }
      }
      if (lane == 0) { redv[w] = bv; redi[w] = bj; }
      __syncthreads();
      if (t == 0) {
        float fv = redv[0]; int fj = redi[0];
        #pragma unroll
        for (int w2 = 1; w2 < 4; ++w2)
          if (redv[w2] > fv || (redv[w2] == fv && redi[w2] < fj)) { fv = redv[w2]; fj = redi[w2]; }
        gv16[i*16 + r] = fv; gj16[i*16 + r] = fj;
        gvals[fj] = -1e30f;
      }
      __syncthreads();
    }
    return;
  }

  const int ch = blockIdx.x & 3, row = blockIdx.x >> 2;
  const float* col = S0T + (size_t)row * SLOTS + ch * CHSZ;
  const int base = t * (CHSZ / 256);     // 32 contiguous per thread
  float4 xa[8];
  #pragma unroll
  for (int u = 0; u < 8; ++u) xa[u] = *(const float4*)(col + base + u*4);
  float v[16]; int ix[16];
  #pragma unroll
  for (int q = 0; q < 16; ++q) { v[q] = -1e30f; ix[q] = 0x7fffffff; }
  #pragma unroll
  for (int u = 0; u < 8; ++u) {
    float xs[4] = {xa[u].x, xa[u].y, xa[u].z, xa[u].w};
    #pragma unroll
    for (int e = 0; e < 4; ++e) {
      float cv = xs[e]; int ci = ch * CHSZ + base + u*4 + e;
      if (cv > v[15] || (cv == v[15] && ci < ix[15])) {
        #pragma unroll
        for (int q = 0; q < 16; ++q) {
          bool better = (cv > v[q]) || (cv == v[q] && ci < ix[q]);
          float tv = better ? v[q] : cv;  // static-index swap (cndmask)
          int   ti = better ? ix[q] : ci;
          v[q]  = better ? cv : v[q];
          ix[q] = better ? ci : ix[q];
          cv = tv; ci = ti;
        }
      }
    }
  }
  for (int r = 0; r < 16; ++r) {
    float bv = v[0]; int bi = ix[0];
    #pragma unroll
    for (int off = 32; off; off >>= 1) {
      float ov = __shfl_xor(bv, off); int oi = __shfl_xor(bi, off);
      if (ov > bv || (ov == bv && oi < bi)) { bv = ov; bi = oi; }
    }
    if ((t & 63) == 0) { redv[t >> 6] = bv; redi[t >> 6] = bi; }
    __syncthreads();
    float fv = redv[0]; int fi = redi[0];
    #pragma unroll
    for (int w = 1; w < 4; ++w)
      if (redv[w] > fv || (redv[w] == fv && redi[w] < fi)) { fv = redv[w]; fi = redi[w]; }
    if (t == 0) { outv[r] = fv; outi[r] = fi; }
    const bool adv = (v[0] == fv) && (ix[0] == fi);
    #pragma unroll
    for (int q = 0; q < 15; ++q) {
      v[q]  = adv ? v[q+1]  : v[q];
      ix[q] = adv ? ix[q+1] : ix[q];
    }
    v[15]  = adv ? -1e30f     : v[15];
    ix[15] = adv ? 0x7fffffff : ix[15];
    __syncthreads();
  }
  const int cidx = row * NCHUNK + ch;
  if (t < 16) { c16v[cidx*16 + t] = outv[t]; c16i[cidx*16 + t] = outi[t]; }
  const float m = outv[0];
  float s = 0.f;
  #pragma unroll
  for (int u = 0; u < 8; ++u) {
    s += __expf(xa[u].x - m) + __expf(xa[u].y - m)
       + __expf(xa[u].z - m) + __expf(xa[u].w - m);
  }
  #pragma unroll
  for (int off = 32; off; off >>= 1) s += __shfl_xor(s, off);
  if ((t & 63) == 0) ws2[t >> 6] = s;
  __syncthreads();
  if (t == 0) { cse[cidx] = ws2[0]+ws2[1]+ws2[2]+ws2[3]; cmax[cidx] = m; }
}

// ---------------------------------------------------------------------------
// Combine chunk stats (unchanged, round-3 proven)
// ---------------------------------------------------------------------------
__global__ __launch_bounds__(64) void col_combine(
    const float* __restrict__ cmax, const float* __restrict__ cse,
    const float* __restrict__ c16v, const int* __restrict__ c16i,
    float* __restrict__ m_base, float* __restrict__ se_base,
    float* __restrict__ t16v, int* __restrict__ t16i)
{
  const int i = blockIdx.x, lane = threadIdx.x;
  float v = c16v[(size_t)i * 64 + lane];
  int   id = c16i[(size_t)i * 64 + lane];
  float m0 = cmax[i*4+0], m1 = cmax[i*4+1], m2 = cmax[i*4+2], m3 = cmax[i*4+3];
  const float m = fmaxf(fmaxf(m0, m1), fmaxf(m2, m3));
  const float se = cse[i*4+0]*__expf(m0-m) + cse[i*4+1]*__expf(m1-m)
                 + cse[i*4+2]*__expf(m2-m) + cse[i*4+3]*__expf(m3-m);
  bool dead = false;
  for (int r = 0; r < 16; ++r) {
    float bv = dead ? -1e30f : v;
    int   bi = dead ? 0x7fffffff : id;
    #pragma unroll
    for (int off = 32; off; off >>= 1) {
      float ov = __shfl_xor(bv, off); int oi = __shfl_xor(bi, off);
      if (ov > bv || (ov == bv && oi < bi)) { bv = ov; bi = oi; }
    }
    if (!dead && v == bv && id == bi) dead = true;
    if (lane == 0) { t16v[i*16 + r] = bv; t16i[i*16 + r] = bi; }
  }
  if (lane == 0) { m_base[i] = m; se_base[i] = se; }
}

// ---------------------------------------------------------------------------
// FUSED: pipelined sequential slot assignment (block 0; candidate + bitmap
// prefetched; winner extraction via v_readlane [uniform index, VALU-class]
// instead of __shfl [ds_bpermute, LDS-class ~120cy] — the chain was
// shfl-latency-bound) + split-K NN exp-GEMM (blocks 1..256) +
// hidA = S_t @ W1[:,:512]^T (blocks 257..384).
// NOTE: G-row register prefetch REMOVED (R8 post-mortem: unconditional copy
// at loop tail put a vmcnt(0) wait on the chain every iteration, +25 us).
// ---------------------------------------------------------------------------
#define EXP_SCALE 16384.0f
#define KCHUNK 1024
__global__ __launch_bounds__(256) void seq_plus_gemm(
    const float* __restrict__ S0T, const float* __restrict__ G,
    const float* __restrict__ t16v, const int* __restrict__ t16i,
    const float* __restrict__ gv16, const int* __restrict__ gj16,
    int* __restrict__ slots,
    const float* __restrict__ B, const float* __restrict__ mArr,
    float* __restrict__ part,
    const float* __restrict__ S_t, const float* __restrict__ W1,
    float* __restrict__ hid)
{
  __shared__ __align__(16) unsigned char smem[70656];

  if (blockIdx.x == 0) {
    // ======================= sequential phase =======================
    unsigned int* bitmap = (unsigned int*)smem;            //  4096 B
    float* sv       = (float*)(smem + 4096);               // 16384 B
    int*   si       = (int*)  (smem + 20480);              // 16384 B
    float* gv       = (float*)(smem + 36864);              // 16384 B
    int*   gj       = (int*)  (smem + 53248);              // 16384 B
    int*   slots_sh = (int*)  (smem + 69632);              //  1024 B
    volatile unsigned int* vbm = bitmap;
    const int tt = threadIdx.x;
    for (int q = tt; q < SLOTS/32; q += 256) bitmap[q] = 0u;
    for (int q = tt; q < BATCH*16; q += 256) {
      sv[q] = t16v[q]; si[q] = t16i[q]; gv[q] = gv16[q]; gj[q] = gj16[q];
    }
    __syncthreads();
    if (tt < 64) {
      const int lane = tt;
      unsigned long long alive[4] = {0ull,0ull,0ull,0ull};
      int slotr0 = -1, slotr1 = -1, slotr2 = -1, slotr3 = -1;

      // pipelined candidate state for iteration 0
      float myv = -1e30f; int myslot = 0; unsigned int wpref = 0;
      float ovq = -1e30f; int ojq = 0;
      if (lane < 16) {
        myv = sv[lane]; myslot = si[lane];
        wpref = vbm[myslot >> 5];
        ovq = gv[lane]; ojq = gj[lane];
      }
      int prev_slot = -1;

      for (int i = 0; i < BATCH; ++i) {
        bool bvalid = false, ovalid = false;
        if (lane < 16) {
          bvalid = (((wpref >> (myslot & 31)) & 1u) == 0u) && (myslot != prev_slot);
          unsigned long long am = (ojq < 64) ? alive[0] : (ojq < 128) ? alive[1]
                                 : (ojq < 192) ? alive[2] : alive[3];
          ovalid = (ovq > -1e29f) && (((am >> (ojq & 63)) & 1ull) != 0ull);
        }
        unsigned long long bb = __ballot(bvalid);
        unsigned long long ob = __ballot(ovalid);

        // prefetch next iteration's candidates (off the critical chain)
        float myv_n = -1e30f; int myslot_n = 0; unsigned int wpref_n = 0;
        float ovq_n = -1e30f; int ojq_n = 0;
        if (i + 1 < BATCH && lane < 16) {
          myv_n = sv[(i+1)*16 + lane]; myslot_n = si[(i+1)*16 + lane];
          wpref_n = vbm[myslot_n >> 5];
          ovq_n = gv[(i+1)*16 + lane]; ojq_n = gj[(i+1)*16 + lane];
        }

        float bval; int bslot;
        if (bb != 0ull) {
          int bl = __ffsll((unsigned long long)bb) - 1;
          bval = rdlf(myv, bl); bslot = rdl(myslot, bl);
        } else {
          float fv = -1e30f; int fi = 0x7fffffff;
          for (int s = lane; s < SLOTS; s += 64) {
            if (((vbm[s >> 5] >> (s & 31)) & 1u) == 0u) {
              float x = S0T[(size_t)i*SLOTS + s];
              if (x > fv || (x == fv && s < fi)) { fv = x; fi = s; }
            }
          }
          #pragma unroll
          for (int off = 32; off; off >>= 1) {
            float ovv = __shfl_xor(fv, off); int oii = __shfl_xor(fi, off);
            if (ovv > fv || (ovv == fv && oii < fi)) { fv = ovv; fi = oii; }
          }
          bval = fv; bslot = fi;
        }

        float oval = -1e30f; int oslot = 0x7fffffff;
        if (ob != 0ull) {
          int ol = __ffsll((unsigned long long)ob) - 1;
          oval = rdlf(ovq, ol);
          int ojw = rdl(ojq, ol);
          int r = ojw >> 6;
          int srg = (r == 0) ? slotr0 : (r == 1) ? slotr1 : (r == 2) ? slotr2 : slotr3;
          oslot = rdl(srg, ojw & 63);
        } else if ((alive[0] | alive[1] | alive[2] | alive[3]) != 0ull) {
          float fv = -1e30f; int fj = 0x7fffffff;
          #pragma unroll
          for (int r = 0; r < 4; ++r) {
            int j = lane + 64*r;
            if (j < i && ((alive[r] >> lane) & 1ull)) {
              float x = G[(size_t)i*BATCH + j];
              if (x > fv || (x == fv && j < fj)) { fv = x; fj = j; }
            }
          }
          #pragma unroll
          for (int off = 32; off; off >>= 1) {
            float ovv = __shfl_xor(fv, off); int ojj = __shfl_xor(fj, off);
            if (ovv > fv || (ovv == fv && ojj < fj)) { fv = ovv; fj = ojj; }
          }
          if (fj != 0x7fffffff) {
            oval = fv;
            int r = fj >> 6;
            int srg = (r == 0) ? slotr0 : (r == 1) ? slotr1 : (r == 2) ? slotr2 : slotr3;
            oslot = rdl(srg, fj & 63);   // fj converged: uniform
          }
        }

        const bool owins = (oval > bval) || (oval == bval && oslot < bslot);
        const int sloti = owins ? oslot : bslot;

        unsigned long long kb0 = __ballot(slotr0 == sloti);
        unsigned long long kb1 = __ballot(slotr1 == sloti);
        unsigned long long kb2 = __ballot(slotr2 == sloti);
        unsigned long long kb3 = __ballot(slotr3 == sloti);
        alive[0] &= ~kb0; alive[1] &= ~kb1; alive[2] &= ~kb2; alive[3] &= ~kb3;
        const int r_new = i >> 6;
        if (lane == (i & 63)) {
          if (r_new == 0) slotr0 = sloti;
          else if (r_new == 1) slotr1 = sloti;
          else if (r_new == 2) slotr2 = sloti;
          else slotr3 = sloti;
        }
        alive[r_new] |= (1ull << (i & 63));
        if (lane == 0) {
          slots_sh[i] = sloti;
          vbm[sloti >> 5] = vbm[sloti >> 5] | (1u << (sloti & 31));
        }
        prev_slot = sloti;
        myv = myv_n; myslot = myslot_n; wpref = wpref_n; ovq = ovq_n; ojq = ojq_n;
        __builtin_amdgcn_wave_barrier();
      }
      for (int q = lane; q < BATCH; q += 64) slots[q] = slots_sh[q];
    }
    return;
  }

  if (blockIdx.x >= 257) {
    // =================== hidA = S_t @ W1[:, :512]^T (blocks 257..384) ===================
    float (*As)[68] = (float (*)[68])smem;
    float (*Bs)[68] = (float (*)[68])(smem + 4352);
    const int b2 = blockIdx.x - 257;     // 0..127 -> 4 x 32 tiles
    gemm64_body(S_t, 512, W1, 1024, nullptr, hid, 2048, 0, 512, 0, 0, 0,
                nullptr, nullptr, b2 & 3, b2 >> 2, threadIdx.x, As, Bs);
    return;
  }

  // ======================= exp-GEMM phase (blocks 1..256) =======================
  unsigned short* sAhi = (unsigned short*)smem;            // 10240 B
  unsigned short* sAlo = (unsigned short*)(smem + 10240);  // 10240 B
  unsigned short* sBhi = (unsigned short*)(smem + 20480);  //  8704 B
  unsigned short* sBlo = (unsigned short*)(smem + 29184);  //  8704 B -> 37888

  const int b  = blockIdx.x - 1;           // 0..255
  const int bx = b >> 7;                   // 0..1   (M tiles)
  const int by = (b >> 5) & 3;             // 0..3   (N tiles)
  const int bz = b & 31;                   // 0..31  (K chunks)
  const int m0 = bx * 128, n0 = by * 128;
  const int kb = bz * KCHUNK;
  const int t = threadIdx.x;
  const int wave = t >> 6, lane = t & 63;
  const int wr = (wave >> 1) * 64, wc = (wave & 1) * 64;
  const int lrow = lane & 15, quad = lane >> 4;
  const int sr = t >> 1;           // A staging row (0..127), 2 threads/row
  const int sc = (t & 1) * 16;     // A staging k-offset
  const int pr = t >> 4;           // B k-pair row (0..15) -> k rows 2pr,2pr+1
  const int nbase = (t & 15) * 8;  // B n-offset (0..120)
  const float mrow = mArr[m0 + sr];

  f32x4 acc[4][4];
  #pragma unroll
  for (int a = 0; a < 4; ++a)
    #pragma unroll
    for (int c = 0; c < 4; ++c)
      acc[a][c] = (f32x4){0.f, 0.f, 0.f, 0.f};

  for (int k0 = kb; k0 < kb + KCHUNK; k0 += 32) {
    const float* ap = S0T + (size_t)(m0 + sr) * SLOTS + k0 + sc;
    float4 a0 = *(const float4*)(ap);
    float4 a1 = *(const float4*)(ap + 4);
    float4 a2 = *(const float4*)(ap + 8);
    float4 a3 = *(const float4*)(ap + 12);
    const float* bp = B + (size_t)(k0 + 2*pr) * DIM + n0 + nbase;
    float4 q0 = *(const float4*)(bp);
    float4 q1 = *(const float4*)(bp + 4);
    float4 q2 = *(const float4*)(bp + DIM);
    float4 q3 = *(const float4*)(bp + DIM + 4);

    float ax[16] = {a0.x,a0.y,a0.z,a0.w, a1.x,a1.y,a1.z,a1.w,
                    a2.x,a2.y,a2.z,a2.w, a3.x,a3.y,a3.z,a3.w};
    unsigned short ah[16], av[16];
    #pragma unroll
    for (int e = 0; e < 16; ++e) {
      float rm; float ee = __expf(ax[e] - mrow) * EXP_SCALE;
      ah[e] = h_split(ee, rm); av[e] = h_rne(rm);
    }
    float r0[8] = {q0.x,q0.y,q0.z,q0.w, q1.x,q1.y,q1.z,q1.w};
    float r1[8] = {q2.x,q2.y,q2.z,q2.w, q3.x,q3.y,q3.z,q3.w};
    unsigned int pbh[8], pbl[8];
    #pragma unroll
    for (int e = 0; e < 8; ++e) {
      float rm0, rm1;
      unsigned short h0 = h_split(r0[e], rm0);
      unsigned short h1 = h_split(r1[e], rm1);
      pbh[e] = pack2(h0, h1);
      pbl[e] = pack2(h_rne(rm0), h_rne(rm1));
    }

    __syncthreads();
    *(uint4*)&sAhi[sr*LSTR + sc] =
        make_uint4(pack2(ah[0],ah[1]), pack2(ah[2],ah[3]),
                   pack2(ah[4],ah[5]), pack2(ah[6],ah[7]));
    *(uint4*)&sAhi[sr*LSTR + sc + 8] =
        make_uint4(pack2(ah[8],ah[9]), pack2(ah[10],ah[11]),
                   pack2(ah[12],ah[13]), pack2(ah[14],ah[15]));
    *(uint4*)&sAlo[sr*LSTR + sc] =
        make_uint4(pack2(av[0],av[1]), pack2(av[2],av[3]),
                   pack2(av[4],av[5]), pack2(av[6],av[7]));
    *(uint4*)&sAlo[sr*LSTR + sc + 8] =
        make_uint4(pack2(av[8],av[9]), pack2(av[10],av[11]),
                   pack2(av[12],av[13]), pack2(av[14],av[15]));
    {
      unsigned int* bh32 = (unsigned int*)sBhi;
      unsigned int* bl32 = (unsigned int*)sBlo;
      #pragma unroll
      for (int e = 0; e < 8; ++e) bh32[(nbase + e)*17 + pr] = pbh[e];
      #pragma unroll
      for (int e = 0; e < 8; ++e) bl32[(nbase + e)*17 + pr] = pbl[e];
    }
    __syncthreads();

    half8 afh[4], afl[4], bfh[4], bfl[4];
    #pragma unroll
    for (int mt = 0; mt < 4; ++mt) {
      const int ar = wr + mt*16 + lrow;
      afh[mt] = *(const half8*)&sAhi[ar*LSTR + quad*8];
      afl[mt] = *(const half8*)&sAlo[ar*LSTR + quad*8];
    }
    #pragma unroll
    for (int nt = 0; nt < 4; ++nt) {
      const int br = wc + nt*16 + lrow;
      const unsigned int* ph = (const unsigned int*)sBhi + br*17 + quad*4;
      const unsigned int* pl = (const unsigned int*)sBlo + br*17 + quad*4;
      union FU { unsigned int u[4]; half8 s; };
      FU th, tl;
      th.u[0] = ph[0]; th.u[1] = ph[1]; th.u[2] = ph[2]; th.u[3] = ph[3];
      tl.u[0] = pl[0]; tl.u[1] = pl[1]; tl.u[2] = pl[2]; tl.u[3] = pl[3];
      bfh[nt] = th.s; bfl[nt] = tl.s;
    }
    #pragma unroll
    for (int mt = 0; mt < 4; ++mt)
      #pragma unroll
      for (int nt = 0; nt < 4; ++nt) {
        acc[mt][nt] = __builtin_amdgcn_mfma_f32_16x16x32_f16(afh[mt], bfh[nt], acc[mt][nt], 0, 0, 0);
        acc[mt][nt] = __builtin_amdgcn_mfma_f32_16x16x32_f16(afl[mt], bfh[nt], acc[mt][nt], 0, 0, 0);
        acc[mt][nt] = __builtin_amdgcn_mfma_f32_16x16x32_f16(afh[mt], bfl[nt], acc[mt][nt], 0, 0, 0);
      }
  }
  float* Cz = part + (size_t)bz * BATCH * DIM;
  #pragma unroll
  for (int mt = 0; mt < 4; ++mt)
    #pragma unroll
    for (int nt = 0; nt < 4; ++nt)
      #pragma unroll
      for (int reg = 0; reg < 4; ++reg) {
        const int m = m0 + wr + mt*16 + quad*4 + reg;
        const int n = n0 + wc + nt*16 + lrow;
        Cz[(size_t)m * DIM + n] = acc[mt][nt][reg];
      }
}

// ---------------------------------------------------------------------------
// FUSED coef + readval_merge (blocks 0..255) + out-bias-init (blocks 256..263).
// ---------------------------------------------------------------------------
__global__ __launch_bounds__(256) void coef_readval(
    const float* __restrict__ S0T, const float* __restrict__ G,
    const int* __restrict__ slots,
    const float* __restrict__ m_base, const float* __restrict__ se_base,
    const float* __restrict__ WVp, const float* __restrict__ mem_vals,
    const float* __restrict__ S_t, const float* __restrict__ part,
    float* __restrict__ merged,
    const float* __restrict__ bias2, float* __restrict__ outp)
{
  const int j = threadIdx.x;
  if (blockIdx.x >= BATCH) {
    const int b2 = blockIdx.x - BATCH;   // 0..7 -> 32 rows each
    const float z0 = bias2[j], z1 = bias2[256 + j];
    for (int r = 0; r < 32; ++r) {
      const int m = b2 * 32 + r;
      outp[(size_t)m * DIM + j] = z0;
      outp[(size_t)m * DIM + 256 + j] = z1;
    }
    return;
  }
  const int i = blockIdx.x;
  __shared__ int sh[BATCH];
  __shared__ float sca[BATCH], scs[BATCH];
  __shared__ float red[4];
  __shared__ float sh_invZ, sh_rs;
  sh[j] = slots[j];
  __syncthreads();
  const int sj = sh[j];
  int nj = 0x7fffffff;
  for (int k = j + 1; k < BATCH; ++k)
    if (sh[k] == sj) { nj = k; break; }

  const bool alive = (j < i) && (nj >= i);
  const float g = alive ? G[(size_t)i*BATCH + j] : -1e30f;
  float bv = g;
  #pragma unroll
  for (int off = 32; off; off >>= 1) bv = fmaxf(bv, __shfl_xor(bv, off));
  if ((j & 63) == 0) red[j >> 6] = bv;
  __syncthreads();
  const float mb = m_base[i];
  const float mi = fmaxf(fmaxf(fmaxf(red[0], red[1]), fmaxf(red[2], red[3])), mb);
  const float sv_ = alive ? S0T[(size_t)i*SLOTS + sj] : 0.f;
  const float ca = alive ? __expf(g - mi) : 0.f;
  const float cs = alive ? __expf(sv_ - mi) : 0.f;
  sca[j] = ca; scs[j] = cs;
  float z = ca - cs;
  #pragma unroll
  for (int off = 32; off; off >>= 1) z += __shfl_xor(z, off);
  __syncthreads();
  if ((j & 63) == 0) red[j >> 6] = z;
  __syncthreads();
  if (j == 0) {
    const float Z = se_base[i] * __expf(mb - mi) + red[0] + red[1] + red[2] + red[3];
    sh_invZ = 1.0f / Z;
    sh_rs = __expf(mb - mi) * (1.0f / EXP_SCALE);
  }
  __syncthreads();

  // ---- merge phase (j now indexes output columns) ----
  merged[(size_t)i*1024 + j]        = S_t[(size_t)i*DIM + j];
  merged[(size_t)i*1024 + 256 + j]  = S_t[(size_t)i*DIM + 256 + j];
  float acc0 = 0.f, acc1 = 0.f;
  #pragma unroll 4
  for (int zz = 0; zz < 32; ++zz) {
    acc0 += part[(size_t)zz * (BATCH*DIM) + (size_t)i*DIM + j];
    acc1 += part[(size_t)zz * (BATCH*DIM) + (size_t)i*DIM + 256 + j];
  }
  acc0 *= sh_rs; acc1 *= sh_rs;
  #pragma unroll 4
  for (int jj = 0; jj < i; ++jj) {      // ca/cs are zero for dead j: branchless
    const float caj = sca[jj];
    const float csj = scs[jj];
    const int sjj = sh[jj];
    acc0 += caj * WVp[(size_t)jj*DIM + j]       - csj * mem_vals[(size_t)sjj*DIM + j];
    acc1 += caj * WVp[(size_t)jj*DIM + 256 + j] - csj * mem_vals[(size_t)sjj*DIM + 256 + j];
  }
  merged[(size_t)i*1024 + 512 + j] = acc0 * sh_invZ;
  merged[(size_t)i*1024 + 768 + j] = acc1 * sh_invZ;
}

// ---------------------------------------------------------------------------
extern "C" void kernel_launch(void* const* d_in, const int* in_sizes, int n_in,
                              void* d_out, int out_size, void* d_ws, size_t ws_size,
                              hipStream_t stream)
{
  (void)in_sizes; (void)n_in; (void)out_size; (void)ws_size;
  const float* S_t      = (const float*)d_in[0];
  const float* mem_keys = (const float*)d_in[1];
  const float* mem_vals = (const float*)d_in[2];
  const float* Wk       = (const float*)d_in[3];
  const float* bk       = (const float*)d_in[4];
  const float* Wv       = (const float*)d_in[5];
  const float* bv       = (const float*)d_in[6];
  const float* W1       = (const float*)d_in[7];
  const float* b1       = (const float*)d_in[8];
  const float* W2       = (const float*)d_in[9];
  const float* b2       = (const float*)d_in[10];
  float* out = (float*)d_out;

  // Workspace layout — round-3-proven footprint.
  float* ws = (float*)d_ws;
  float* Kp       = ws + 0;         // [256,512]
  float* WVp      = ws + 131072;    // [256,512]
  float* G        = ws + 262144;    // [256,256]
  float* S0T      = ws + 327680;    // [256,32768]
  float* m_base   = ws + 8716288;   // [256]
  float* se_base  = ws + 8716544;   // [256]
  float* t16v     = ws + 8716800;   // [256,16]
  int*   t16i     = (int*)(ws + 8720896);
  float* gv16     = ws + 8724992;   // [256,16]
  int*   gj16     = (int*)(ws + 8729088);
  int*   slots    = (int*)(ws + 8733184);
  float* merged   = ws + 8996352;   // [256,1024]
  float* hid      = ws + 9258496;   // [256,2048] ends 9782784
  float* part     = ws + 9782784;   // [32][256,512] ends 13977088
  // col_chunk scratch aliased onto head of part:
  float* cmaxb    = ws + 9782784;   // [256,4]
  float* cseb     = ws + 9783808;   // [256,4]
  float* c16vb    = ws + 9784832;   // [256,4,16]
  int*   c16ib    = (int*)(ws + 9801216);  // [256,4,16] ends 9817600 < 13977088
  unsigned short* Khi = (unsigned short*)(ws + 13977088);  // [256,512] bf16
  unsigned short* Klo = (unsigned short*)(ws + 14042624);  // [256,512] bf16, ends 14108160

  // phase 1: Wk-proj (+hi/lo epilogue) & Wv-proj fused; then gram+scores fused
  proj2<<<dim3(64), dim3(256), 0, stream>>>(S_t, Wk, bk, Kp, Khi, Klo, Wv, bv, WVp);
  gram_scores<<<dim3(528), dim3(256), 0, stream>>>(Kp, G, Khi, Klo, mem_keys, S0T);

  // phase 2: col stats + G top-16 fused; combine
  colchunk_gtop<<<dim3(1280), dim3(256), 0, stream>>>(S0T, cmaxb, cseb, c16vb, c16ib,
                                                      G, gv16, gj16);
  col_combine<<<dim3(256), dim3(64), 0, stream>>>(cmaxb, cseb, c16vb, c16ib,
                                                  m_base, se_base, t16v, t16i);

  // phase 2.5: FUSED pipelined sequential (block 0) + read exp-GEMM (1..256)
  //            + hidA = S_t @ W1[:, :512]^T (257..384)
  seq_plus_gemm<<<dim3(385), dim3(256), 0, stream>>>(S0T, G, t16v, t16i, gv16, gj16,
                                                     slots, mem_vals, m_base, part,
                                                     S_t, W1, hid);

  // phase 3: coefficients + split-K reduce + merge + out-bias-init, fused
  coef_readval<<<dim3(264), dim3(256), 0, stream>>>(S0T, G, slots, m_base, se_base,
                                                    WVp, mem_vals, S_t, part, merged,
                                                    b2, out);

  // phase 4: MLP — W1b half (K=512, accumulate onto hidA) then W2 split-K x4
  gemm_bt<<<dim3(4, 32), dim3(256), 0, stream>>>(merged + 512, 1024, W1 + 512, 1024,
                                                 b1, hid, 2048, 512, 1, 1);
  gemm_bt_sk<<<dim3(4, 8, 4), dim3(256), 0, stream>>>(hid, 2048, W2, 2048,
                                                      out, 512, 512);
}